// Round 4
// baseline (1771.426 us; speedup 1.0000x reference)
//
#include <hip/hip_runtime.h>

// GCN: 3 layers GraphConv (norm='both'), N=50000, E=800000, D=128.
// Round 3: hierarchical scan (was 128us single-block), 4x4 register-blocked
// GEMM, unroll-2 gather.

#define NN 50000
#define NE 800000
#define DM 128
#define NB 196   // ceil(NN/256) scan blocks

__global__ void k_count(const int* __restrict__ src, const int* __restrict__ dst,
                        int* __restrict__ co, int* __restrict__ ci) {
  int e = blockIdx.x * blockDim.x + threadIdx.x;
  if (e < NE) {
    atomicAdd(&co[src[e]], 1);
    atomicAdd(&ci[dst[e]], 1);
  }
}

__global__ void k_norms(const int* __restrict__ co, const int* __restrict__ ci,
                        float* __restrict__ onorm, float* __restrict__ inorm) {
  int i = blockIdx.x * blockDim.x + threadIdx.x;
  if (i < NN) {
    onorm[i] = rsqrtf(fmaxf((float)co[i], 1.0f));
    inorm[i] = rsqrtf(fmaxf((float)ci[i], 1.0f));
  }
}

// ---- hierarchical exclusive scan of ci -> rowptr, cursor ----
__global__ void k_scan_part(const int* __restrict__ ci, int* __restrict__ bsum) {
  __shared__ int s[256];
  int i = blockIdx.x * 256 + threadIdx.x;
  s[threadIdx.x] = (i < NN) ? ci[i] : 0;
  __syncthreads();
  for (int off = 128; off > 0; off >>= 1) {
    if (threadIdx.x < off) s[threadIdx.x] += s[threadIdx.x + off];
    __syncthreads();
  }
  if (threadIdx.x == 0) bsum[blockIdx.x] = s[0];
}

__global__ void k_scan_mid(const int* __restrict__ bsum, int* __restrict__ boff,
                           int* __restrict__ rowptr) {
  __shared__ int s[256];
  int t = threadIdx.x;
  int v = (t < NB) ? bsum[t] : 0;
  s[t] = v;
  __syncthreads();
  for (int off = 1; off < 256; off <<= 1) {
    int u = (t >= off) ? s[t - off] : 0;
    __syncthreads();
    s[t] += u;
    __syncthreads();
  }
  if (t < NB) boff[t] = s[t] - v;  // exclusive
  if (t == 0) rowptr[NN] = NE;
}

__global__ void k_scan_out(const int* __restrict__ ci, const int* __restrict__ boff,
                           int* __restrict__ rowptr, int* __restrict__ cursor) {
  __shared__ int s[256];
  int t = threadIdx.x;
  int i = blockIdx.x * 256 + t;
  int v = (i < NN) ? ci[i] : 0;
  s[t] = v;
  __syncthreads();
  for (int off = 1; off < 256; off <<= 1) {
    int u = (t >= off) ? s[t - off] : 0;
    __syncthreads();
    s[t] += u;
    __syncthreads();
  }
  if (i < NN) {
    int ex = boff[blockIdx.x] + s[t] - v;
    rowptr[i] = ex;
    cursor[i] = ex;
  }
}

__global__ void k_fill(const int* __restrict__ src, const int* __restrict__ dst,
                       int* __restrict__ cursor, int* __restrict__ col) {
  int e = blockIdx.x * blockDim.x + threadIdx.x;
  if (e < NE) {
    int p = atomicAdd(&cursor[dst[e]], 1);
    col[p] = src[e];
  }
}

// 32 lanes per destination node, float4 per lane; unroll 2 edges for MLP.
__global__ void k_gather(const float* __restrict__ h, const int* __restrict__ rowptr,
                         const int* __restrict__ col, const float* __restrict__ onorm,
                         const float* __restrict__ inorm, float* __restrict__ agg) {
  int tid = blockIdx.x * blockDim.x + threadIdx.x;
  int n = tid >> 5;
  if (n >= NN) return;
  int lane = tid & 31;
  int beg = rowptr[n];
  int end = rowptr[n + 1];
  const float4* h4 = reinterpret_cast<const float4*>(h);
  float4 a0 = make_float4(0.f, 0.f, 0.f, 0.f);
  float4 a1 = make_float4(0.f, 0.f, 0.f, 0.f);
  int e = beg;
  for (; e + 2 <= end; e += 2) {
    int s0 = col[e], s1 = col[e + 1];
    float n0 = onorm[s0], n1 = onorm[s1];
    float4 v0 = h4[s0 * 32 + lane];
    float4 v1 = h4[s1 * 32 + lane];
    a0.x += v0.x * n0; a0.y += v0.y * n0; a0.z += v0.z * n0; a0.w += v0.w * n0;
    a1.x += v1.x * n1; a1.y += v1.y * n1; a1.z += v1.z * n1; a1.w += v1.w * n1;
  }
  if (e < end) {
    int s0 = col[e];
    float n0 = onorm[s0];
    float4 v0 = h4[s0 * 32 + lane];
    a0.x += v0.x * n0; a0.y += v0.y * n0; a0.z += v0.z * n0; a0.w += v0.w * n0;
  }
  float sc = inorm[n];
  float4 o = make_float4((a0.x + a1.x) * sc, (a0.y + a1.y) * sc,
                         (a0.z + a1.z) * sc, (a0.w + a1.w) * sc);
  reinterpret_cast<float4*>(agg)[n * 32 + lane] = o;
}

// In-place row GEMM, 4 rows x 4 cols per thread. Block 256 = 8 slots x 32
// lanes; 32 rows per block-pass; grid 782 x 2 passes covers 50048 (guarded).
__launch_bounds__(256, 2)
__global__ void k_gemm(float* __restrict__ x, const float* __restrict__ W,
                       const float* __restrict__ bias) {
  __shared__ float Wl[DM * DM];   // 64 KB
  __shared__ float xs[32][DM];    // 16 KB

  for (int i = threadIdx.x; i < DM * DM / 4; i += 256)
    reinterpret_cast<float4*>(Wl)[i] = reinterpret_cast<const float4*>(W)[i];

  int slot = threadIdx.x >> 5;
  int lane = threadIdx.x & 31;
  int c4 = lane * 4;
  int r0 = slot * 4;
  float4 bj = *reinterpret_cast<const float4*>(bias + c4);

  for (int p = 0; p < 2; ++p) {
    int rbase = (blockIdx.x * 2 + p) * 32;
    __syncthreads();  // Wl ready (p=0) / xs consumed (p=1)
    const float4* xg = reinterpret_cast<const float4*>(x) + (size_t)rbase * 32;
    int lim = (NN - rbase) * 32;  // float4 count remaining (may be <=0)
    for (int i = threadIdx.x; i < 32 * DM / 4; i += 256) {
      float4 v = (i < lim) ? xg[i] : make_float4(0.f, 0.f, 0.f, 0.f);
      reinterpret_cast<float4*>(xs)[i] = v;
    }
    __syncthreads();

    float4 a0 = bj, a1 = bj, a2 = bj, a3 = bj;
#pragma unroll
    for (int kk = 0; kk < DM; kk += 4) {
      float4 xv0 = *reinterpret_cast<const float4*>(&xs[r0 + 0][kk]);
      float4 xv1 = *reinterpret_cast<const float4*>(&xs[r0 + 1][kk]);
      float4 xv2 = *reinterpret_cast<const float4*>(&xs[r0 + 2][kk]);
      float4 xv3 = *reinterpret_cast<const float4*>(&xs[r0 + 3][kk]);
      float xa0[4] = {xv0.x, xv0.y, xv0.z, xv0.w};
      float xa1[4] = {xv1.x, xv1.y, xv1.z, xv1.w};
      float xa2[4] = {xv2.x, xv2.y, xv2.z, xv2.w};
      float xa3[4] = {xv3.x, xv3.y, xv3.z, xv3.w};
#pragma unroll
      for (int j = 0; j < 4; ++j) {
        float4 w = *reinterpret_cast<const float4*>(&Wl[(kk + j) * DM + c4]);
        a0.x += xa0[j] * w.x; a0.y += xa0[j] * w.y; a0.z += xa0[j] * w.z; a0.w += xa0[j] * w.w;
        a1.x += xa1[j] * w.x; a1.y += xa1[j] * w.y; a1.z += xa1[j] * w.z; a1.w += xa1[j] * w.w;
        a2.x += xa2[j] * w.x; a2.y += xa2[j] * w.y; a2.z += xa2[j] * w.z; a2.w += xa2[j] * w.w;
        a3.x += xa3[j] * w.x; a3.y += xa3[j] * w.y; a3.z += xa3[j] * w.z; a3.w += xa3[j] * w.w;
      }
    }

    float* xo = x + (size_t)(rbase + r0) * DM + c4;
    if (rbase + r0 + 3 < NN) {
      *reinterpret_cast<float4*>(xo)          = a0;
      *reinterpret_cast<float4*>(xo + DM)     = a1;
      *reinterpret_cast<float4*>(xo + 2 * DM) = a2;
      *reinterpret_cast<float4*>(xo + 3 * DM) = a3;
    } else {
      if (rbase + r0 + 0 < NN) *reinterpret_cast<float4*>(xo)          = a0;
      if (rbase + r0 + 1 < NN) *reinterpret_cast<float4*>(xo + DM)     = a1;
      if (rbase + r0 + 2 < NN) *reinterpret_cast<float4*>(xo + 2 * DM) = a2;
    }
  }
}

extern "C" void kernel_launch(void* const* d_in, const int* in_sizes, int n_in,
                              void* d_out, int out_size, void* d_ws, size_t ws_size,
                              hipStream_t stream) {
  const float* in_feat = (const float*)d_in[0];
  const int*   ei      = (const int*)d_in[1];
  const float* Ws      = (const float*)d_in[2];
  const float* bs      = (const float*)d_in[3];
  float* out = (float*)d_out;

  const int* src = ei;
  const int* dst = ei + NE;

  char* w = (char*)d_ws;
  int* co     = (int*)w;            w += NN * sizeof(int);
  int* ci     = (int*)w;            w += NN * sizeof(int);
  int* rowptr = (int*)w;            w += (NN + 1) * sizeof(int);
  int* cursor = (int*)w;            w += NN * sizeof(int);
  int* bsum   = (int*)w;            w += NB * sizeof(int);
  int* boff   = (int*)w;            w += NB * sizeof(int);
  int* col    = (int*)w;            w += NE * sizeof(int);
  float* onorm = (float*)w;         w += NN * sizeof(float);
  float* inorm = (float*)w;         w += NN * sizeof(float);
  float* bufA  = (float*)w;         w += (size_t)NN * DM * sizeof(float);
  float* bufB  = (float*)w;

  hipMemsetAsync(co, 0, 2 * NN * sizeof(int), stream);  // co+ci contiguous
  k_count<<<(NE + 255) / 256, 256, 0, stream>>>(src, dst, co, ci);
  k_norms<<<(NN + 255) / 256, 256, 0, stream>>>(co, ci, onorm, inorm);
  k_scan_part<<<NB, 256, 0, stream>>>(ci, bsum);
  k_scan_mid<<<1, 256, 0, stream>>>(bsum, boff, rowptr);
  k_scan_out<<<NB, 256, 0, stream>>>(ci, boff, rowptr, cursor);
  k_fill<<<(NE + 255) / 256, 256, 0, stream>>>(src, dst, cursor, col);

  const float* hin[3]  = {in_feat, bufA, bufB};
  float*       hout[3] = {bufA, bufB, out};

  for (int i = 0; i < 3; ++i) {
    k_gather<<<(NN * 32 + 255) / 256, 256, 0, stream>>>(hin[i], rowptr, col, onorm,
                                                        inorm, hout[i]);
    k_gemm<<<782, 256, 0, stream>>>(hout[i], Ws + (size_t)i * DM * DM, bs + (size_t)i * DM);
  }
}

// Round 5
// 552.245 us; speedup vs baseline: 3.2077x; 3.2077x over previous
//
#include <hip/hip_runtime.h>

// GCN: 3 layers GraphConv (norm='both'), N=50000, E=800000, D=128.
// Round 4: REVERT gemm to round-1 form (round-3's 4x4 unrolled gemm spilled
// to scratch: 1.67GB HBM traffic/dispatch). Keep hierarchical scan + unroll-2
// gather.

#define NN 50000
#define NE 800000
#define DM 128
#define NB 196   // ceil(NN/256) scan blocks

__global__ void k_count(const int* __restrict__ src, const int* __restrict__ dst,
                        int* __restrict__ co, int* __restrict__ ci) {
  int e = blockIdx.x * blockDim.x + threadIdx.x;
  if (e < NE) {
    atomicAdd(&co[src[e]], 1);
    atomicAdd(&ci[dst[e]], 1);
  }
}

__global__ void k_norms(const int* __restrict__ co, const int* __restrict__ ci,
                        float* __restrict__ onorm, float* __restrict__ inorm) {
  int i = blockIdx.x * blockDim.x + threadIdx.x;
  if (i < NN) {
    onorm[i] = rsqrtf(fmaxf((float)co[i], 1.0f));
    inorm[i] = rsqrtf(fmaxf((float)ci[i], 1.0f));
  }
}

// ---- hierarchical exclusive scan of ci -> rowptr, cursor ----
__global__ void k_scan_part(const int* __restrict__ ci, int* __restrict__ bsum) {
  __shared__ int s[256];
  int i = blockIdx.x * 256 + threadIdx.x;
  s[threadIdx.x] = (i < NN) ? ci[i] : 0;
  __syncthreads();
  for (int off = 128; off > 0; off >>= 1) {
    if (threadIdx.x < off) s[threadIdx.x] += s[threadIdx.x + off];
    __syncthreads();
  }
  if (threadIdx.x == 0) bsum[blockIdx.x] = s[0];
}

__global__ void k_scan_mid(const int* __restrict__ bsum, int* __restrict__ boff,
                           int* __restrict__ rowptr) {
  __shared__ int s[256];
  int t = threadIdx.x;
  int v = (t < NB) ? bsum[t] : 0;
  s[t] = v;
  __syncthreads();
  for (int off = 1; off < 256; off <<= 1) {
    int u = (t >= off) ? s[t - off] : 0;
    __syncthreads();
    s[t] += u;
    __syncthreads();
  }
  if (t < NB) boff[t] = s[t] - v;  // exclusive
  if (t == 0) rowptr[NN] = NE;
}

__global__ void k_scan_out(const int* __restrict__ ci, const int* __restrict__ boff,
                           int* __restrict__ rowptr, int* __restrict__ cursor) {
  __shared__ int s[256];
  int t = threadIdx.x;
  int i = blockIdx.x * 256 + t;
  int v = (i < NN) ? ci[i] : 0;
  s[t] = v;
  __syncthreads();
  for (int off = 1; off < 256; off <<= 1) {
    int u = (t >= off) ? s[t - off] : 0;
    __syncthreads();
    s[t] += u;
    __syncthreads();
  }
  if (i < NN) {
    int ex = boff[blockIdx.x] + s[t] - v;
    rowptr[i] = ex;
    cursor[i] = ex;
  }
}

__global__ void k_fill(const int* __restrict__ src, const int* __restrict__ dst,
                       int* __restrict__ cursor, int* __restrict__ col) {
  int e = blockIdx.x * blockDim.x + threadIdx.x;
  if (e < NE) {
    int p = atomicAdd(&cursor[dst[e]], 1);
    col[p] = src[e];
  }
}

// 32 lanes per destination node, float4 per lane; unroll 2 edges for MLP.
__global__ void k_gather(const float* __restrict__ h, const int* __restrict__ rowptr,
                         const int* __restrict__ col, const float* __restrict__ onorm,
                         const float* __restrict__ inorm, float* __restrict__ agg) {
  int tid = blockIdx.x * blockDim.x + threadIdx.x;
  int n = tid >> 5;
  if (n >= NN) return;
  int lane = tid & 31;
  int beg = rowptr[n];
  int end = rowptr[n + 1];
  const float4* h4 = reinterpret_cast<const float4*>(h);
  float4 a0 = make_float4(0.f, 0.f, 0.f, 0.f);
  float4 a1 = make_float4(0.f, 0.f, 0.f, 0.f);
  int e = beg;
  for (; e + 2 <= end; e += 2) {
    int s0 = col[e], s1 = col[e + 1];
    float n0 = onorm[s0], n1 = onorm[s1];
    float4 v0 = h4[s0 * 32 + lane];
    float4 v1 = h4[s1 * 32 + lane];
    a0.x += v0.x * n0; a0.y += v0.y * n0; a0.z += v0.z * n0; a0.w += v0.w * n0;
    a1.x += v1.x * n1; a1.y += v1.y * n1; a1.z += v1.z * n1; a1.w += v1.w * n1;
  }
  if (e < end) {
    int s0 = col[e];
    float n0 = onorm[s0];
    float4 v0 = h4[s0 * 32 + lane];
    a0.x += v0.x * n0; a0.y += v0.y * n0; a0.z += v0.z * n0; a0.w += v0.w * n0;
  }
  float sc = inorm[n];
  float4 o = make_float4((a0.x + a1.x) * sc, (a0.y + a1.y) * sc,
                         (a0.z + a1.z) * sc, (a0.w + a1.w) * sc);
  reinterpret_cast<float4*>(agg)[n * 32 + lane] = o;
}

// In-place row GEMM (round-1 form, known good). Block = 256 threads = 4
// row-slots x 64 threads; each thread computes 2 consecutive outputs.
// Grid=1250, 10 passes over rows: rows = p*5000 + blockIdx.x*4 + sub.
__launch_bounds__(256, 2)
__global__ void k_gemm(float* __restrict__ x, const float* __restrict__ W,
                       const float* __restrict__ bias) {
  __shared__ float Wl[DM * DM];   // 64 KB
  __shared__ float xs[4][DM];

  for (int i = threadIdx.x; i < DM * DM / 4; i += blockDim.x) {
    reinterpret_cast<float4*>(Wl)[i] = reinterpret_cast<const float4*>(W)[i];
  }

  int sub = threadIdx.x >> 6;
  int lj  = (threadIdx.x & 63) * 2;
  float2 bj = *reinterpret_cast<const float2*>(bias + lj);
  __syncthreads();

  for (int p = 0; p < 10; ++p) {
    int row = p * 5000 + blockIdx.x * 4 + sub;
    float2 xv = *reinterpret_cast<const float2*>(x + (size_t)row * DM + lj);
    xs[sub][lj]     = xv.x;
    xs[sub][lj + 1] = xv.y;
    __syncthreads();

    float2 acc = bj;
#pragma unroll
    for (int k = 0; k < DM; ++k) {
      float xk = xs[sub][k];
      float2 w = *reinterpret_cast<const float2*>(&Wl[k * DM + lj]);
      acc.x += xk * w.x;
      acc.y += xk * w.y;
    }
    __syncthreads();
    *reinterpret_cast<float2*>(x + (size_t)row * DM + lj) = acc;
  }
}

extern "C" void kernel_launch(void* const* d_in, const int* in_sizes, int n_in,
                              void* d_out, int out_size, void* d_ws, size_t ws_size,
                              hipStream_t stream) {
  const float* in_feat = (const float*)d_in[0];
  const int*   ei      = (const int*)d_in[1];
  const float* Ws      = (const float*)d_in[2];
  const float* bs      = (const float*)d_in[3];
  float* out = (float*)d_out;

  const int* src = ei;
  const int* dst = ei + NE;

  char* w = (char*)d_ws;
  int* co     = (int*)w;            w += NN * sizeof(int);
  int* ci     = (int*)w;            w += NN * sizeof(int);
  int* rowptr = (int*)w;            w += (NN + 1) * sizeof(int);
  int* cursor = (int*)w;            w += NN * sizeof(int);
  int* bsum   = (int*)w;            w += NB * sizeof(int);
  int* boff   = (int*)w;            w += NB * sizeof(int);
  int* col    = (int*)w;            w += NE * sizeof(int);
  float* onorm = (float*)w;         w += NN * sizeof(float);
  float* inorm = (float*)w;         w += NN * sizeof(float);
  float* bufA  = (float*)w;         w += (size_t)NN * DM * sizeof(float);
  float* bufB  = (float*)w;

  hipMemsetAsync(co, 0, 2 * NN * sizeof(int), stream);  // co+ci contiguous
  k_count<<<(NE + 255) / 256, 256, 0, stream>>>(src, dst, co, ci);
  k_norms<<<(NN + 255) / 256, 256, 0, stream>>>(co, ci, onorm, inorm);
  k_scan_part<<<NB, 256, 0, stream>>>(ci, bsum);
  k_scan_mid<<<1, 256, 0, stream>>>(bsum, boff, rowptr);
  k_scan_out<<<NB, 256, 0, stream>>>(ci, boff, rowptr, cursor);
  k_fill<<<(NE + 255) / 256, 256, 0, stream>>>(src, dst, cursor, col);

  const float* hin[3]  = {in_feat, bufA, bufB};
  float*       hout[3] = {bufA, bufB, out};

  for (int i = 0; i < 3; ++i) {
    k_gather<<<(NN * 32 + 255) / 256, 256, 0, stream>>>(hin[i], rowptr, col, onorm,
                                                        inorm, hout[i]);
    k_gemm<<<1250, 256, 0, stream>>>(hout[i], Ws + (size_t)i * DM * DM, bs + (size_t)i * DM);
  }
}

// Round 6
// 431.454 us; speedup vs baseline: 4.1057x; 1.2800x over previous
//
#include <hip/hip_runtime.h>

// GCN: 3 layers GraphConv (norm='both'), N=50000, E=800000, D=128.
// Round 5: LINEAR COLLAPSE. No nonlinearity between layers, so with
// M = diag(inorm) A^T diag(onorm):
//   out = (M^3 h) W1W2W3 + (M^2 1) (b1^T W2 W3) + (M 1)(b2^T W3) + 1 b3^T
// -> 3 gathers + ONE dense GEMM (was 3) + tiny 128x128 GEMMs + N-vec gathers.
// GEMM: split-j (64-col halves, 32KB W tile) for 2x occupancy.

#define NN 50000
#define NE 800000
#define DM 128
#define NB 196   // ceil(NN/256) scan blocks

__global__ void k_count(const int* __restrict__ src, const int* __restrict__ dst,
                        int* __restrict__ co, int* __restrict__ ci) {
  int e = blockIdx.x * blockDim.x + threadIdx.x;
  if (e < NE) {
    atomicAdd(&co[src[e]], 1);
    atomicAdd(&ci[dst[e]], 1);
  }
}

__global__ void k_norms(const int* __restrict__ co, const int* __restrict__ ci,
                        float* __restrict__ onorm, float* __restrict__ inorm) {
  int i = blockIdx.x * blockDim.x + threadIdx.x;
  if (i < NN) {
    onorm[i] = rsqrtf(fmaxf((float)co[i], 1.0f));
    inorm[i] = rsqrtf(fmaxf((float)ci[i], 1.0f));
  }
}

// ---- hierarchical exclusive scan of ci -> rowptr, cursor ----
__global__ void k_scan_part(const int* __restrict__ ci, int* __restrict__ bsum) {
  __shared__ int s[256];
  int i = blockIdx.x * 256 + threadIdx.x;
  s[threadIdx.x] = (i < NN) ? ci[i] : 0;
  __syncthreads();
  for (int off = 128; off > 0; off >>= 1) {
    if (threadIdx.x < off) s[threadIdx.x] += s[threadIdx.x + off];
    __syncthreads();
  }
  if (threadIdx.x == 0) bsum[blockIdx.x] = s[0];
}

__global__ void k_scan_mid(const int* __restrict__ bsum, int* __restrict__ boff,
                           int* __restrict__ rowptr) {
  __shared__ int s[256];
  int t = threadIdx.x;
  int v = (t < NB) ? bsum[t] : 0;
  s[t] = v;
  __syncthreads();
  for (int off = 1; off < 256; off <<= 1) {
    int u = (t >= off) ? s[t - off] : 0;
    __syncthreads();
    s[t] += u;
    __syncthreads();
  }
  if (t < NB) boff[t] = s[t] - v;  // exclusive
  if (t == 0) rowptr[NN] = NE;
}

__global__ void k_scan_out(const int* __restrict__ ci, const int* __restrict__ boff,
                           int* __restrict__ rowptr, int* __restrict__ cursor) {
  __shared__ int s[256];
  int t = threadIdx.x;
  int i = blockIdx.x * 256 + t;
  int v = (i < NN) ? ci[i] : 0;
  s[t] = v;
  __syncthreads();
  for (int off = 1; off < 256; off <<= 1) {
    int u = (t >= off) ? s[t - off] : 0;
    __syncthreads();
    s[t] += u;
    __syncthreads();
  }
  if (i < NN) {
    int ex = boff[blockIdx.x] + s[t] - v;
    rowptr[i] = ex;
    cursor[i] = ex;
  }
}

__global__ void k_fill(const int* __restrict__ src, const int* __restrict__ dst,
                       int* __restrict__ cursor, int* __restrict__ col) {
  int e = blockIdx.x * blockDim.x + threadIdx.x;
  if (e < NE) {
    int p = atomicAdd(&cursor[dst[e]], 1);
    col[p] = src[e];
  }
}

// ---- tiny dense helpers ----
// C[128,128] = A @ B. grid 128 (rows) x block 128 (cols).
__global__ void k_mm128(const float* __restrict__ A, const float* __restrict__ B,
                        float* __restrict__ C) {
  int i = blockIdx.x, j = threadIdx.x;
  float acc = 0.f;
  for (int k = 0; k < DM; ++k) acc += A[i * DM + k] * B[k * DM + j];
  C[i * DM + j] = acc;
}

// c[128] = b[128] @ B[128,128]. one block of 128 threads.
__global__ void k_vm128(const float* __restrict__ b, const float* __restrict__ B,
                        float* __restrict__ c) {
  int j = threadIdx.x;
  float acc = 0.f;
  for (int k = 0; k < DM; ++k) acc += b[k] * B[k * DM + j];
  c[j] = acc;
}

// y = M x  (N-vector). useones: x treated as all-ones.
__global__ void k_mv(const int* __restrict__ rowptr, const int* __restrict__ col,
                     const float* __restrict__ onorm, const float* __restrict__ inorm,
                     const float* __restrict__ x, float* __restrict__ y, int useones) {
  int n = blockIdx.x * blockDim.x + threadIdx.x;
  if (n >= NN) return;
  int beg = rowptr[n], end = rowptr[n + 1];
  float s = 0.f;
  for (int e = beg; e < end; ++e) {
    int sc = col[e];
    s += useones ? onorm[sc] : onorm[sc] * x[sc];
  }
  y[n] = inorm[n] * s;
}

// ---- feature gather: Y = M X, 32 lanes/node, float4/lane, unroll 2 ----
__global__ void k_gather(const float* __restrict__ h, const int* __restrict__ rowptr,
                         const int* __restrict__ col, const float* __restrict__ onorm,
                         const float* __restrict__ inorm, float* __restrict__ agg) {
  int tid = blockIdx.x * blockDim.x + threadIdx.x;
  int n = tid >> 5;
  if (n >= NN) return;
  int lane = tid & 31;
  int beg = rowptr[n];
  int end = rowptr[n + 1];
  const float4* h4 = reinterpret_cast<const float4*>(h);
  float4 a0 = make_float4(0.f, 0.f, 0.f, 0.f);
  float4 a1 = make_float4(0.f, 0.f, 0.f, 0.f);
  int e = beg;
  for (; e + 2 <= end; e += 2) {
    int s0 = col[e], s1 = col[e + 1];
    float n0 = onorm[s0], n1 = onorm[s1];
    float4 v0 = h4[s0 * 32 + lane];
    float4 v1 = h4[s1 * 32 + lane];
    a0.x += v0.x * n0; a0.y += v0.y * n0; a0.z += v0.z * n0; a0.w += v0.w * n0;
    a1.x += v1.x * n1; a1.y += v1.y * n1; a1.z += v1.z * n1; a1.w += v1.w * n1;
  }
  if (e < end) {
    int s0 = col[e];
    float n0 = onorm[s0];
    float4 v0 = h4[s0 * 32 + lane];
    a0.x += v0.x * n0; a0.y += v0.y * n0; a0.z += v0.z * n0; a0.w += v0.w * n0;
  }
  float sc = inorm[n];
  float4 o = make_float4((a0.x + a1.x) * sc, (a0.y + a1.y) * sc,
                         (a0.z + a1.z) * sc, (a0.w + a1.w) * sc);
  reinterpret_cast<float4*>(agg)[n * 32 + lane] = o;
}

// ---- final GEMM: out = x @ W + v2*c1^T + v1*c2^T + 1*c3^T ----
// Split-j: each block owns a 64-col half (32KB W tile -> 4 blocks/CU).
// Block 256 = 8 row-slots x 32 lanes; thread = 1 row x 2 cols. 10 passes.
__launch_bounds__(256, 4)
__global__ void k_gemm_f(const float* __restrict__ x, const float* __restrict__ W,
                         const float* __restrict__ c1, const float* __restrict__ c2,
                         const float* __restrict__ c3, const float* __restrict__ v1,
                         const float* __restrict__ v2, float* __restrict__ out) {
  __shared__ float Wl[DM * 64];   // 32 KB: our 64 columns
  __shared__ float xs[8][DM];     // 4 KB

  int jhalf = blockIdx.x & 1;
  int grp   = blockIdx.x >> 1;    // 0..624
  int jbase = jhalf * 64;

  for (int i = threadIdx.x; i < DM * 64 / 4; i += 256) {
    int k = i >> 4;
    int jc4 = (i & 15) * 4;
    *reinterpret_cast<float4*>(&Wl[k * 64 + jc4]) =
        *reinterpret_cast<const float4*>(&W[k * DM + jbase + jc4]);
  }

  int slot = threadIdx.x >> 5;
  int lane = threadIdx.x & 31;
  int jc = lane * 2;
  float2 e1 = *reinterpret_cast<const float2*>(&c1[jbase + jc]);
  float2 e2 = *reinterpret_cast<const float2*>(&c2[jbase + jc]);
  float2 e3 = *reinterpret_cast<const float2*>(&c3[jbase + jc]);
  __syncthreads();

  for (int p = 0; p < 10; ++p) {
    int rbase = grp * 80 + p * 8;
    // stage 8 rows (256 float4, one per thread)
    const float4* xg = reinterpret_cast<const float4*>(x + (size_t)rbase * DM);
    reinterpret_cast<float4*>(xs)[threadIdx.x] = xg[threadIdx.x];
    __syncthreads();

    int row = rbase + slot;
    float rv1 = v1[row], rv2 = v2[row];
    float2 acc;
    acc.x = rv2 * e1.x + rv1 * e2.x + e3.x;
    acc.y = rv2 * e1.y + rv1 * e2.y + e3.y;
#pragma unroll
    for (int k = 0; k < DM; ++k) {
      float xk = xs[slot][k];
      float2 w = *reinterpret_cast<const float2*>(&Wl[k * 64 + jc]);
      acc.x += xk * w.x;
      acc.y += xk * w.y;
    }
    __syncthreads();
    *reinterpret_cast<float2*>(&out[(size_t)row * DM + jbase + jc]) = acc;
  }
}

extern "C" void kernel_launch(void* const* d_in, const int* in_sizes, int n_in,
                              void* d_out, int out_size, void* d_ws, size_t ws_size,
                              hipStream_t stream) {
  const float* in_feat = (const float*)d_in[0];
  const int*   ei      = (const int*)d_in[1];
  const float* Ws      = (const float*)d_in[2];
  const float* bs      = (const float*)d_in[3];
  float* out = (float*)d_out;

  const int* src = ei;
  const int* dst = ei + NE;
  const float* W1 = Ws;
  const float* W2 = Ws + DM * DM;
  const float* W3 = Ws + 2 * DM * DM;
  const float* b1 = bs;
  const float* b2 = bs + DM;
  const float* b3 = bs + 2 * DM;

  char* w = (char*)d_ws;
  int* co     = (int*)w;            w += NN * sizeof(int);
  int* ci     = (int*)w;            w += NN * sizeof(int);
  int* rowptr = (int*)w;            w += (NN + 1) * sizeof(int);
  int* cursor = (int*)w;            w += NN * sizeof(int);
  int* bsum   = (int*)w;            w += NB * sizeof(int);
  int* boff   = (int*)w;            w += NB * sizeof(int);
  int* col    = (int*)w;            w += NE * sizeof(int);
  float* onorm = (float*)w;         w += NN * sizeof(float);
  float* inorm = (float*)w;         w += NN * sizeof(float);
  float* v1    = (float*)w;         w += NN * sizeof(float);
  float* v2    = (float*)w;         w += NN * sizeof(float);
  float* W12   = (float*)w;         w += DM * DM * sizeof(float);
  float* W123  = (float*)w;         w += DM * DM * sizeof(float);
  float* tmpv  = (float*)w;         w += DM * sizeof(float);
  float* c1    = (float*)w;         w += DM * sizeof(float);
  float* c2    = (float*)w;         w += DM * sizeof(float);
  float* bufA  = (float*)w;         w += (size_t)NN * DM * sizeof(float);
  float* bufB  = (float*)w;

  // graph preprocessing
  hipMemsetAsync(co, 0, 2 * NN * sizeof(int), stream);  // co+ci contiguous
  k_count<<<(NE + 255) / 256, 256, 0, stream>>>(src, dst, co, ci);
  k_norms<<<(NN + 255) / 256, 256, 0, stream>>>(co, ci, onorm, inorm);
  k_scan_part<<<NB, 256, 0, stream>>>(ci, bsum);
  k_scan_mid<<<1, 256, 0, stream>>>(bsum, boff, rowptr);
  k_scan_out<<<NB, 256, 0, stream>>>(ci, boff, rowptr, cursor);
  k_fill<<<(NE + 255) / 256, 256, 0, stream>>>(src, dst, cursor, col);

  // weight/bias collapse: W123 = W1 W2 W3; c1 = b1 W2 W3; c2 = b2 W3
  k_mm128<<<DM, DM, 0, stream>>>(W1, W2, W12);
  k_mm128<<<DM, DM, 0, stream>>>(W12, W3, W123);
  k_vm128<<<1, DM, 0, stream>>>(b1, W2, tmpv);
  k_vm128<<<1, DM, 0, stream>>>(tmpv, W3, c1);
  k_vm128<<<1, DM, 0, stream>>>(b2, W3, c2);

  // v1 = M 1, v2 = M v1
  k_mv<<<NB, 256, 0, stream>>>(rowptr, col, onorm, inorm, nullptr, v1, 1);
  k_mv<<<NB, 256, 0, stream>>>(rowptr, col, onorm, inorm, v1, v2, 0);

  // g3 = M^3 h
  k_gather<<<(NN * 32 + 255) / 256, 256, 0, stream>>>(in_feat, rowptr, col, onorm, inorm, bufA);
  k_gather<<<(NN * 32 + 255) / 256, 256, 0, stream>>>(bufA, rowptr, col, onorm, inorm, bufB);
  k_gather<<<(NN * 32 + 255) / 256, 256, 0, stream>>>(bufB, rowptr, col, onorm, inorm, bufA);

  // out = g3 @ W123 + v2 c1^T + v1 c2^T + 1 b3^T
  k_gemm_f<<<1250, 256, 0, stream>>>(bufA, W123, c1, c2, b3, v1, v2, out);
}

// Round 8
// 406.572 us; speedup vs baseline: 4.3570x; 1.0612x over previous
//
#include <hip/hip_runtime.h>

// GCN: 3 layers GraphConv (norm='both'), N=50000, E=800000, D=128.
// Round 7 (fixed): (a) gather = one wave per node (even/odd edge halves,
// shfl-xor reduce); (b) GEMM = 2 rows x 4 cols per thread, all-b128 LDS
// reads, xs stride 132. Macro params renamed (prev round: param `w`
// substituted into `.w` member access -> compile failure).
//   out = (M^3 h) W1W2W3 + (M^2 1)(b1^T W2W3) + (M 1)(b2^T W3) + 1 b3^T

#define NN 50000
#define NE 800000
#define DM 128
#define NB 196   // ceil(NN/256) scan blocks

#define FMA4(av, sv, wv) \
  av.x += (sv) * (wv).x; av.y += (sv) * (wv).y; av.z += (sv) * (wv).z; av.w += (sv) * (wv).w;

__global__ void k_count(const int* __restrict__ src, const int* __restrict__ dst,
                        int* __restrict__ co, int* __restrict__ ci) {
  int e = blockIdx.x * blockDim.x + threadIdx.x;
  if (e < NE) {
    atomicAdd(&co[src[e]], 1);
    atomicAdd(&ci[dst[e]], 1);
  }
}

__global__ void k_norms(const int* __restrict__ co, const int* __restrict__ ci,
                        float* __restrict__ onorm, float* __restrict__ inorm) {
  int i = blockIdx.x * blockDim.x + threadIdx.x;
  if (i < NN) {
    onorm[i] = rsqrtf(fmaxf((float)co[i], 1.0f));
    inorm[i] = rsqrtf(fmaxf((float)ci[i], 1.0f));
  }
}

// ---- hierarchical exclusive scan of ci -> rowptr, cursor ----
__global__ void k_scan_part(const int* __restrict__ ci, int* __restrict__ bsum) {
  __shared__ int s[256];
  int i = blockIdx.x * 256 + threadIdx.x;
  s[threadIdx.x] = (i < NN) ? ci[i] : 0;
  __syncthreads();
  for (int off = 128; off > 0; off >>= 1) {
    if (threadIdx.x < off) s[threadIdx.x] += s[threadIdx.x + off];
    __syncthreads();
  }
  if (threadIdx.x == 0) bsum[blockIdx.x] = s[0];
}

__global__ void k_scan_mid(const int* __restrict__ bsum, int* __restrict__ boff,
                           int* __restrict__ rowptr) {
  __shared__ int s[256];
  int t = threadIdx.x;
  int v = (t < NB) ? bsum[t] : 0;
  s[t] = v;
  __syncthreads();
  for (int off = 1; off < 256; off <<= 1) {
    int u = (t >= off) ? s[t - off] : 0;
    __syncthreads();
    s[t] += u;
    __syncthreads();
  }
  if (t < NB) boff[t] = s[t] - v;  // exclusive
  if (t == 0) rowptr[NN] = NE;
}

__global__ void k_scan_out(const int* __restrict__ ci, const int* __restrict__ boff,
                           int* __restrict__ rowptr, int* __restrict__ cursor) {
  __shared__ int s[256];
  int t = threadIdx.x;
  int i = blockIdx.x * 256 + t;
  int v = (i < NN) ? ci[i] : 0;
  s[t] = v;
  __syncthreads();
  for (int off = 1; off < 256; off <<= 1) {
    int u = (t >= off) ? s[t - off] : 0;
    __syncthreads();
    s[t] += u;
    __syncthreads();
  }
  if (i < NN) {
    int ex = boff[blockIdx.x] + s[t] - v;
    rowptr[i] = ex;
    cursor[i] = ex;
  }
}

__global__ void k_fill(const int* __restrict__ src, const int* __restrict__ dst,
                       int* __restrict__ cursor, int* __restrict__ col) {
  int e = blockIdx.x * blockDim.x + threadIdx.x;
  if (e < NE) {
    int p = atomicAdd(&cursor[dst[e]], 1);
    col[p] = src[e];
  }
}

// ---- tiny dense helpers ----
__global__ void k_mm128(const float* __restrict__ A, const float* __restrict__ B,
                        float* __restrict__ C) {
  int i = blockIdx.x, j = threadIdx.x;
  float acc = 0.f;
  for (int k = 0; k < DM; ++k) acc += A[i * DM + k] * B[k * DM + j];
  C[i * DM + j] = acc;
}

__global__ void k_vm128(const float* __restrict__ b, const float* __restrict__ B,
                        float* __restrict__ c) {
  int j = threadIdx.x;
  float acc = 0.f;
  for (int k = 0; k < DM; ++k) acc += b[k] * B[k * DM + j];
  c[j] = acc;
}

// y = M x (N-vector). useones: x treated as all-ones.
__global__ void k_mv(const int* __restrict__ rowptr, const int* __restrict__ col,
                     const float* __restrict__ onorm, const float* __restrict__ inorm,
                     const float* __restrict__ x, float* __restrict__ y, int useones) {
  int n = blockIdx.x * blockDim.x + threadIdx.x;
  if (n >= NN) return;
  int beg = rowptr[n], end = rowptr[n + 1];
  float s = 0.f;
  for (int e = beg; e < end; ++e) {
    int sc = col[e];
    s += useones ? onorm[sc] : onorm[sc] * x[sc];
  }
  y[n] = inorm[n] * s;
}

// ---- feature gather: Y = M X. One 64-lane wave per node; halves take
// even/odd edges (4 edges in flight), shfl-xor(32) reduce, half-0 store.
__global__ void k_gather(const float* __restrict__ h, const int* __restrict__ rowptr,
                         const int* __restrict__ col, const float* __restrict__ onorm,
                         const float* __restrict__ inorm, float* __restrict__ agg) {
  int tid = blockIdx.x * blockDim.x + threadIdx.x;
  int n = tid >> 6;
  if (n >= NN) return;
  int lane = threadIdx.x & 63;
  int half = lane >> 5;
  int l32 = lane & 31;
  int beg = rowptr[n], end = rowptr[n + 1];
  const float4* h4 = reinterpret_cast<const float4*>(h);
  float4 a0 = make_float4(0.f, 0.f, 0.f, 0.f);
  float4 a1 = make_float4(0.f, 0.f, 0.f, 0.f);
  int e = beg + half;
  for (; e + 2 < end; e += 4) {
    int s0 = col[e], s1 = col[e + 2];
    float n0 = onorm[s0], n1 = onorm[s1];
    float4 v0 = h4[s0 * 32 + l32];
    float4 v1 = h4[s1 * 32 + l32];
    FMA4(a0, n0, v0)
    FMA4(a1, n1, v1)
  }
  if (e < end) {
    int s0 = col[e];
    float n0 = onorm[s0];
    float4 v0 = h4[s0 * 32 + l32];
    FMA4(a0, n0, v0)
  }
  a0.x += a1.x; a0.y += a1.y; a0.z += a1.z; a0.w += a1.w;
  a0.x += __shfl_xor(a0.x, 32);
  a0.y += __shfl_xor(a0.y, 32);
  a0.z += __shfl_xor(a0.z, 32);
  a0.w += __shfl_xor(a0.w, 32);
  if (half == 0) {
    float sc = inorm[n];
    reinterpret_cast<float4*>(agg)[n * 32 + l32] =
        make_float4(a0.x * sc, a0.y * sc, a0.z * sc, a0.w * sc);
  }
}

// ---- final GEMM: out = x @ W + v2*c1^T + v1*c2^T + 1*c3^T ----
// Split-j 64-col halves (32KB W tile). Block 256 = 16 slots x 16 lanes;
// thread = 2 rows x 4 cols, all-b128 LDS reads. 32 rows/pass, 2 passes.
// xs row stride 132 floats (16B-aligned, bank-spread broadcasts).
__launch_bounds__(256, 3)
__global__ void k_gemm_f(const float* __restrict__ x, const float* __restrict__ W,
                         const float* __restrict__ c1, const float* __restrict__ c2,
                         const float* __restrict__ c3, const float* __restrict__ v1,
                         const float* __restrict__ v2, float* __restrict__ out) {
  __shared__ float Wl[DM * 64];     // 32 KB
  __shared__ float xs[32 * 132];    // 16.9 KB

  int jhalf = blockIdx.x & 1;
  int grp   = blockIdx.x >> 1;      // 0..781
  int jbase = jhalf * 64;

  {
    const float4* W4 = reinterpret_cast<const float4*>(W);
    float4* Wl4 = reinterpret_cast<float4*>(Wl);
    for (int i = threadIdx.x; i < DM * 16; i += 256) {
      int k = i >> 4, j4 = i & 15;
      Wl4[i] = W4[k * 32 + jhalf * 16 + j4];
    }
  }

  int slot = threadIdx.x >> 4;      // 0..15
  int lane = threadIdx.x & 15;      // 0..15
  int jc = lane * 4;
  float4 e1 = *reinterpret_cast<const float4*>(&c1[jbase + jc]);
  float4 e2 = *reinterpret_cast<const float4*>(&c2[jbase + jc]);
  float4 e3 = *reinterpret_cast<const float4*>(&c3[jbase + jc]);

  for (int p = 0; p < 2; ++p) {
    int rbase = grp * 64 + p * 32;
    __syncthreads();  // Wl ready (p=0) / xs consumed (p=1)
    // stage 32 rows into padded xs
    const float4* xg = reinterpret_cast<const float4*>(x) + (size_t)rbase * 32;
    float4* xs4 = reinterpret_cast<float4*>(xs);
    int lim = (NN - rbase) * 32;
    for (int i = threadIdx.x; i < 1024; i += 256) {
      int r = i >> 5, seg = i & 31;
      float4 v = (i < lim) ? xg[i] : make_float4(0.f, 0.f, 0.f, 0.f);
      xs4[r * 33 + seg] = v;
    }
    __syncthreads();

    int r0 = rbase + slot * 2;
    int r1 = r0 + 1;
    const float* x0 = &xs[(slot * 2 + 0) * 132];
    const float* x1 = &xs[(slot * 2 + 1) * 132];
    int rc0 = (r0 < NN) ? r0 : 0;
    int rc1 = (r1 < NN) ? r1 : 0;
    float rv10 = v1[rc0], rv20 = v2[rc0];
    float rv11 = v1[rc1], rv21 = v2[rc1];
    float4 a0, a1;
    a0.x = rv20 * e1.x + rv10 * e2.x + e3.x;
    a0.y = rv20 * e1.y + rv10 * e2.y + e3.y;
    a0.z = rv20 * e1.z + rv10 * e2.z + e3.z;
    a0.w = rv20 * e1.w + rv10 * e2.w + e3.w;
    a1.x = rv21 * e1.x + rv11 * e2.x + e3.x;
    a1.y = rv21 * e1.y + rv11 * e2.y + e3.y;
    a1.z = rv21 * e1.z + rv11 * e2.z + e3.z;
    a1.w = rv21 * e1.w + rv11 * e2.w + e3.w;

    for (int k4 = 0; k4 < DM; k4 += 4) {
      float4 xv0 = *reinterpret_cast<const float4*>(&x0[k4]);
      float4 xv1 = *reinterpret_cast<const float4*>(&x1[k4]);
      float4 w0 = *reinterpret_cast<const float4*>(&Wl[(k4 + 0) * 64 + jc]);
      float4 w1 = *reinterpret_cast<const float4*>(&Wl[(k4 + 1) * 64 + jc]);
      float4 w2 = *reinterpret_cast<const float4*>(&Wl[(k4 + 2) * 64 + jc]);
      float4 w3 = *reinterpret_cast<const float4*>(&Wl[(k4 + 3) * 64 + jc]);
      FMA4(a0, xv0.x, w0) FMA4(a0, xv0.y, w1) FMA4(a0, xv0.z, w2) FMA4(a0, xv0.w, w3)
      FMA4(a1, xv1.x, w0) FMA4(a1, xv1.y, w1) FMA4(a1, xv1.z, w2) FMA4(a1, xv1.w, w3)
    }

    if (r0 < NN) *reinterpret_cast<float4*>(&out[(size_t)r0 * DM + jbase + jc]) = a0;
    if (r1 < NN) *reinterpret_cast<float4*>(&out[(size_t)r1 * DM + jbase + jc]) = a1;
  }
}

extern "C" void kernel_launch(void* const* d_in, const int* in_sizes, int n_in,
                              void* d_out, int out_size, void* d_ws, size_t ws_size,
                              hipStream_t stream) {
  const float* in_feat = (const float*)d_in[0];
  const int*   ei      = (const int*)d_in[1];
  const float* Ws      = (const float*)d_in[2];
  const float* bs      = (const float*)d_in[3];
  float* out = (float*)d_out;

  const int* src = ei;
  const int* dst = ei + NE;
  const float* W1 = Ws;
  const float* W2 = Ws + DM * DM;
  const float* W3 = Ws + 2 * DM * DM;
  const float* b1 = bs;
  const float* b2 = bs + DM;
  const float* b3 = bs + 2 * DM;

  char* w = (char*)d_ws;
  int* co     = (int*)w;            w += NN * sizeof(int);
  int* ci     = (int*)w;            w += NN * sizeof(int);
  int* rowptr = (int*)w;            w += (NN + 1) * sizeof(int);
  int* cursor = (int*)w;            w += NN * sizeof(int);
  int* bsum   = (int*)w;            w += NB * sizeof(int);
  int* boff   = (int*)w;            w += NB * sizeof(int);
  int* col    = (int*)w;            w += NE * sizeof(int);
  float* onorm = (float*)w;         w += NN * sizeof(float);
  float* inorm = (float*)w;         w += NN * sizeof(float);
  float* v1    = (float*)w;         w += NN * sizeof(float);
  float* v2    = (float*)w;         w += NN * sizeof(float);
  float* W12   = (float*)w;         w += DM * DM * sizeof(float);
  float* W123  = (float*)w;         w += DM * DM * sizeof(float);
  float* tmpv  = (float*)w;         w += DM * sizeof(float);
  float* c1    = (float*)w;         w += DM * sizeof(float);
  float* c2    = (float*)w;         w += DM * sizeof(float);
  float* bufA  = (float*)w;         w += (size_t)NN * DM * sizeof(float);
  float* bufB  = (float*)w;

  // graph preprocessing
  hipMemsetAsync(co, 0, 2 * NN * sizeof(int), stream);  // co+ci contiguous
  k_count<<<(NE + 255) / 256, 256, 0, stream>>>(src, dst, co, ci);
  k_norms<<<(NN + 255) / 256, 256, 0, stream>>>(co, ci, onorm, inorm);
  k_scan_part<<<NB, 256, 0, stream>>>(ci, bsum);
  k_scan_mid<<<1, 256, 0, stream>>>(bsum, boff, rowptr);
  k_scan_out<<<NB, 256, 0, stream>>>(ci, boff, rowptr, cursor);
  k_fill<<<(NE + 255) / 256, 256, 0, stream>>>(src, dst, cursor, col);

  // weight/bias collapse
  k_mm128<<<DM, DM, 0, stream>>>(W1, W2, W12);
  k_mm128<<<DM, DM, 0, stream>>>(W12, W3, W123);
  k_vm128<<<1, DM, 0, stream>>>(b1, W2, tmpv);
  k_vm128<<<1, DM, 0, stream>>>(tmpv, W3, c1);
  k_vm128<<<1, DM, 0, stream>>>(b2, W3, c2);

  // v1 = M 1, v2 = M v1
  k_mv<<<NB, 256, 0, stream>>>(rowptr, col, onorm, inorm, nullptr, v1, 1);
  k_mv<<<NB, 256, 0, stream>>>(rowptr, col, onorm, inorm, v1, v2, 0);

  // g3 = M^3 h
  k_gather<<<NN * 64 / 256, 256, 0, stream>>>(in_feat, rowptr, col, onorm, inorm, bufA);
  k_gather<<<NN * 64 / 256, 256, 0, stream>>>(bufA, rowptr, col, onorm, inorm, bufB);
  k_gather<<<NN * 64 / 256, 256, 0, stream>>>(bufB, rowptr, col, onorm, inorm, bufA);

  // out = g3 @ W123 + v2 c1^T + v1 c2^T + 1 b3^T
  k_gemm_f<<<1564, 256, 0, stream>>>(bufA, W123, c1, c2, b3, v1, v2, out);
}

// Round 9
// 377.999 us; speedup vs baseline: 4.6863x; 1.0756x over previous
//
#include <hip/hip_runtime.h>

// GCN: 3 layers GraphConv (norm='both'), N=50000, E=800000, D=128.
// Round 9: (a) gather unroll 4-per-half (8 rows in flight) as latency A/B;
// (b) v1 = M·1 and v2 = M·v1 fused into gathers 1/2 (k_mv deleted);
// (c) weight collapse reassociated: W23=W2W3; W123=W1·W23; c1=b1·W23; c2=b2·W3.
//   out = (M^3 h) W123 + v2 c1^T + v1 c2^T + 1 b3^T

#define NN 50000
#define NE 800000
#define DM 128
#define NB 196   // ceil(NN/256) scan blocks

#define FMA4(av, sv, wv) \
  av.x += (sv) * (wv).x; av.y += (sv) * (wv).y; av.z += (sv) * (wv).z; av.w += (sv) * (wv).w;

__global__ void k_count(const int* __restrict__ src, const int* __restrict__ dst,
                        int* __restrict__ co, int* __restrict__ ci) {
  int e = blockIdx.x * blockDim.x + threadIdx.x;
  if (e < NE) {
    atomicAdd(&co[src[e]], 1);
    atomicAdd(&ci[dst[e]], 1);
  }
}

__global__ void k_norms(const int* __restrict__ co, const int* __restrict__ ci,
                        float* __restrict__ onorm, float* __restrict__ inorm) {
  int i = blockIdx.x * blockDim.x + threadIdx.x;
  if (i < NN) {
    onorm[i] = rsqrtf(fmaxf((float)co[i], 1.0f));
    inorm[i] = rsqrtf(fmaxf((float)ci[i], 1.0f));
  }
}

// ---- hierarchical exclusive scan of ci -> rowptr, cursor ----
__global__ void k_scan_part(const int* __restrict__ ci, int* __restrict__ bsum) {
  __shared__ int s[256];
  int i = blockIdx.x * 256 + threadIdx.x;
  s[threadIdx.x] = (i < NN) ? ci[i] : 0;
  __syncthreads();
  for (int off = 128; off > 0; off >>= 1) {
    if (threadIdx.x < off) s[threadIdx.x] += s[threadIdx.x + off];
    __syncthreads();
  }
  if (threadIdx.x == 0) bsum[blockIdx.x] = s[0];
}

__global__ void k_scan_mid(const int* __restrict__ bsum, int* __restrict__ boff,
                           int* __restrict__ rowptr) {
  __shared__ int s[256];
  int t = threadIdx.x;
  int v = (t < NB) ? bsum[t] : 0;
  s[t] = v;
  __syncthreads();
  for (int off = 1; off < 256; off <<= 1) {
    int u = (t >= off) ? s[t - off] : 0;
    __syncthreads();
    s[t] += u;
    __syncthreads();
  }
  if (t < NB) boff[t] = s[t] - v;  // exclusive
  if (t == 0) rowptr[NN] = NE;
}

__global__ void k_scan_out(const int* __restrict__ ci, const int* __restrict__ boff,
                           int* __restrict__ rowptr, int* __restrict__ cursor) {
  __shared__ int s[256];
  int t = threadIdx.x;
  int i = blockIdx.x * 256 + t;
  int v = (i < NN) ? ci[i] : 0;
  s[t] = v;
  __syncthreads();
  for (int off = 1; off < 256; off <<= 1) {
    int u = (t >= off) ? s[t - off] : 0;
    __syncthreads();
    s[t] += u;
    __syncthreads();
  }
  if (i < NN) {
    int ex = boff[blockIdx.x] + s[t] - v;
    rowptr[i] = ex;
    cursor[i] = ex;
  }
}

__global__ void k_fill(const int* __restrict__ src, const int* __restrict__ dst,
                       int* __restrict__ cursor, int* __restrict__ col) {
  int e = blockIdx.x * blockDim.x + threadIdx.x;
  if (e < NE) {
    int p = atomicAdd(&cursor[dst[e]], 1);
    col[p] = src[e];
  }
}

// ---- tiny dense helpers ----
__global__ void k_mm128(const float* __restrict__ A, const float* __restrict__ B,
                        float* __restrict__ C) {
  int i = blockIdx.x, j = threadIdx.x;
  float acc = 0.f;
  for (int k = 0; k < DM; ++k) acc += A[i * DM + k] * B[k * DM + j];
  C[i * DM + j] = acc;
}

__global__ void k_vm128(const float* __restrict__ b, const float* __restrict__ B,
                        float* __restrict__ c) {
  int j = threadIdx.x;
  float acc = 0.f;
  for (int k = 0; k < DM; ++k) acc += b[k] * B[k * DM + j];
  c[j] = acc;
}

// ---- feature gather: Y = M X. One 64-lane wave per node; halves take
// even/odd edges; unroll 4 per half (8 rows in flight); shfl-xor(32) reduce.
// VMODE 0: features only. 1: also vout[n] = inorm[n]*sum(onorm[s]) (= M·1).
// 2: also vout[n] = inorm[n]*sum(onorm[s]*vin[s]) (= M·vin).
template <int VMODE>
__global__ void k_gather_t(const float* __restrict__ h, const int* __restrict__ rowptr,
                           const int* __restrict__ col, const float* __restrict__ onorm,
                           const float* __restrict__ inorm, const float* __restrict__ vin,
                           float* __restrict__ agg, float* __restrict__ vout) {
  int tid = blockIdx.x * blockDim.x + threadIdx.x;
  int n = tid >> 6;
  if (n >= NN) return;
  int lane = threadIdx.x & 63;
  int half = lane >> 5;
  int l32 = lane & 31;
  int beg = rowptr[n], end = rowptr[n + 1];
  const float4* h4 = reinterpret_cast<const float4*>(h);
  float4 a0 = make_float4(0.f, 0.f, 0.f, 0.f);
  float4 a1 = make_float4(0.f, 0.f, 0.f, 0.f);
  float4 a2 = make_float4(0.f, 0.f, 0.f, 0.f);
  float4 a3 = make_float4(0.f, 0.f, 0.f, 0.f);
  float av = 0.f;
  int e = beg + half;
  for (; e + 6 < end; e += 8) {
    int s0 = col[e], s1 = col[e + 2], s2 = col[e + 4], s3 = col[e + 6];
    float n0 = onorm[s0], n1 = onorm[s1], n2 = onorm[s2], n3 = onorm[s3];
    float4 v0 = h4[(size_t)s0 * 32 + l32];
    float4 v1 = h4[(size_t)s1 * 32 + l32];
    float4 v2 = h4[(size_t)s2 * 32 + l32];
    float4 v3 = h4[(size_t)s3 * 32 + l32];
    if (VMODE == 1) av += n0 + n1 + n2 + n3;
    if (VMODE == 2) av += n0 * vin[s0] + n1 * vin[s1] + n2 * vin[s2] + n3 * vin[s3];
    FMA4(a0, n0, v0)
    FMA4(a1, n1, v1)
    FMA4(a2, n2, v2)
    FMA4(a3, n3, v3)
  }
  for (; e < end; e += 2) {
    int s0 = col[e];
    float n0 = onorm[s0];
    float4 v0 = h4[(size_t)s0 * 32 + l32];
    if (VMODE == 1) av += n0;
    if (VMODE == 2) av += n0 * vin[s0];
    FMA4(a0, n0, v0)
  }
  a0.x += a1.x + a2.x + a3.x;
  a0.y += a1.y + a2.y + a3.y;
  a0.z += a1.z + a2.z + a3.z;
  a0.w += a1.w + a2.w + a3.w;
  a0.x += __shfl_xor(a0.x, 32);
  a0.y += __shfl_xor(a0.y, 32);
  a0.z += __shfl_xor(a0.z, 32);
  a0.w += __shfl_xor(a0.w, 32);
  if (VMODE) av += __shfl_xor(av, 32);
  if (half == 0) {
    float sc = inorm[n];
    reinterpret_cast<float4*>(agg)[n * 32 + l32] =
        make_float4(a0.x * sc, a0.y * sc, a0.z * sc, a0.w * sc);
    if (VMODE && l32 == 0) vout[n] = av * sc;
  }
}

// ---- final GEMM: out = x @ W + v2*c1^T + v1*c2^T + 1*c3^T ----
// Split-j 64-col halves (32KB W tile). Block 256 = 16 slots x 16 lanes;
// thread = 2 rows x 4 cols, all-b128 LDS reads. 32 rows/pass, 2 passes.
__launch_bounds__(256, 3)
__global__ void k_gemm_f(const float* __restrict__ x, const float* __restrict__ W,
                         const float* __restrict__ c1, const float* __restrict__ c2,
                         const float* __restrict__ c3, const float* __restrict__ v1,
                         const float* __restrict__ v2, float* __restrict__ out) {
  __shared__ float Wl[DM * 64];     // 32 KB
  __shared__ float xs[32 * 132];    // 16.9 KB

  int jhalf = blockIdx.x & 1;
  int grp   = blockIdx.x >> 1;      // 0..781
  int jbase = jhalf * 64;

  {
    const float4* W4 = reinterpret_cast<const float4*>(W);
    float4* Wl4 = reinterpret_cast<float4*>(Wl);
    for (int i = threadIdx.x; i < DM * 16; i += 256) {
      int k = i >> 4, j4 = i & 15;
      Wl4[i] = W4[k * 32 + jhalf * 16 + j4];
    }
  }

  int slot = threadIdx.x >> 4;      // 0..15
  int lane = threadIdx.x & 15;      // 0..15
  int jc = lane * 4;
  float4 e1 = *reinterpret_cast<const float4*>(&c1[jbase + jc]);
  float4 e2 = *reinterpret_cast<const float4*>(&c2[jbase + jc]);
  float4 e3 = *reinterpret_cast<const float4*>(&c3[jbase + jc]);

  for (int p = 0; p < 2; ++p) {
    int rbase = grp * 64 + p * 32;
    __syncthreads();  // Wl ready (p=0) / xs consumed (p=1)
    const float4* xg = reinterpret_cast<const float4*>(x) + (size_t)rbase * 32;
    float4* xs4 = reinterpret_cast<float4*>(xs);
    int lim = (NN - rbase) * 32;
    for (int i = threadIdx.x; i < 1024; i += 256) {
      int r = i >> 5, seg = i & 31;
      float4 v = (i < lim) ? xg[i] : make_float4(0.f, 0.f, 0.f, 0.f);
      xs4[r * 33 + seg] = v;
    }
    __syncthreads();

    int r0 = rbase + slot * 2;
    int r1 = r0 + 1;
    const float* x0 = &xs[(slot * 2 + 0) * 132];
    const float* x1 = &xs[(slot * 2 + 1) * 132];
    int rc0 = (r0 < NN) ? r0 : 0;
    int rc1 = (r1 < NN) ? r1 : 0;
    float rv10 = v1[rc0], rv20 = v2[rc0];
    float rv11 = v1[rc1], rv21 = v2[rc1];
    float4 a0, a1;
    a0.x = rv20 * e1.x + rv10 * e2.x + e3.x;
    a0.y = rv20 * e1.y + rv10 * e2.y + e3.y;
    a0.z = rv20 * e1.z + rv10 * e2.z + e3.z;
    a0.w = rv20 * e1.w + rv10 * e2.w + e3.w;
    a1.x = rv21 * e1.x + rv11 * e2.x + e3.x;
    a1.y = rv21 * e1.y + rv11 * e2.y + e3.y;
    a1.z = rv21 * e1.z + rv11 * e2.z + e3.z;
    a1.w = rv21 * e1.w + rv11 * e2.w + e3.w;

    for (int k4 = 0; k4 < DM; k4 += 4) {
      float4 xv0 = *reinterpret_cast<const float4*>(&x0[k4]);
      float4 xv1 = *reinterpret_cast<const float4*>(&x1[k4]);
      float4 w0 = *reinterpret_cast<const float4*>(&Wl[(k4 + 0) * 64 + jc]);
      float4 w1 = *reinterpret_cast<const float4*>(&Wl[(k4 + 1) * 64 + jc]);
      float4 w2 = *reinterpret_cast<const float4*>(&Wl[(k4 + 2) * 64 + jc]);
      float4 w3 = *reinterpret_cast<const float4*>(&Wl[(k4 + 3) * 64 + jc]);
      FMA4(a0, xv0.x, w0) FMA4(a0, xv0.y, w1) FMA4(a0, xv0.z, w2) FMA4(a0, xv0.w, w3)
      FMA4(a1, xv1.x, w0) FMA4(a1, xv1.y, w1) FMA4(a1, xv1.z, w2) FMA4(a1, xv1.w, w3)
    }

    if (r0 < NN) *reinterpret_cast<float4*>(&out[(size_t)r0 * DM + jbase + jc]) = a0;
    if (r1 < NN) *reinterpret_cast<float4*>(&out[(size_t)r1 * DM + jbase + jc]) = a1;
  }
}

extern "C" void kernel_launch(void* const* d_in, const int* in_sizes, int n_in,
                              void* d_out, int out_size, void* d_ws, size_t ws_size,
                              hipStream_t stream) {
  const float* in_feat = (const float*)d_in[0];
  const int*   ei      = (const int*)d_in[1];
  const float* Ws      = (const float*)d_in[2];
  const float* bs      = (const float*)d_in[3];
  float* out = (float*)d_out;

  const int* src = ei;
  const int* dst = ei + NE;
  const float* W1 = Ws;
  const float* W2 = Ws + DM * DM;
  const float* W3 = Ws + 2 * DM * DM;
  const float* b1 = bs;
  const float* b2 = bs + DM;
  const float* b3 = bs + 2 * DM;

  char* w = (char*)d_ws;
  int* co     = (int*)w;            w += NN * sizeof(int);
  int* ci     = (int*)w;            w += NN * sizeof(int);
  int* rowptr = (int*)w;            w += (NN + 1) * sizeof(int);
  int* cursor = (int*)w;            w += NN * sizeof(int);
  int* bsum   = (int*)w;            w += NB * sizeof(int);
  int* boff   = (int*)w;            w += NB * sizeof(int);
  int* col    = (int*)w;            w += NE * sizeof(int);
  float* onorm = (float*)w;         w += NN * sizeof(float);
  float* inorm = (float*)w;         w += NN * sizeof(float);
  float* v1    = (float*)w;         w += NN * sizeof(float);
  float* v2    = (float*)w;         w += NN * sizeof(float);
  float* W23   = (float*)w;         w += DM * DM * sizeof(float);
  float* W123  = (float*)w;         w += DM * DM * sizeof(float);
  float* c1    = (float*)w;         w += DM * sizeof(float);
  float* c2    = (float*)w;         w += DM * sizeof(float);
  float* bufA  = (float*)w;         w += (size_t)NN * DM * sizeof(float);
  float* bufB  = (float*)w;

  // graph preprocessing
  hipMemsetAsync(co, 0, 2 * NN * sizeof(int), stream);  // co+ci contiguous
  k_count<<<(NE + 255) / 256, 256, 0, stream>>>(src, dst, co, ci);
  k_norms<<<(NN + 255) / 256, 256, 0, stream>>>(co, ci, onorm, inorm);
  k_scan_part<<<NB, 256, 0, stream>>>(ci, bsum);
  k_scan_mid<<<1, 256, 0, stream>>>(bsum, boff, rowptr);
  k_scan_out<<<NB, 256, 0, stream>>>(ci, boff, rowptr, cursor);
  k_fill<<<(NE + 255) / 256, 256, 0, stream>>>(src, dst, cursor, col);

  // weight/bias collapse: W23 = W2 W3; W123 = W1 W23; c1 = b1 W23; c2 = b2 W3
  k_mm128<<<DM, DM, 0, stream>>>(W2, W3, W23);
  k_mm128<<<DM, DM, 0, stream>>>(W1, W23, W123);
  k_vm128<<<1, DM, 0, stream>>>(b1, W23, c1);
  k_vm128<<<1, DM, 0, stream>>>(b2, W3, c2);

  // g3 = M^3 h, with v1 = M 1 (gather 1) and v2 = M v1 (gather 2) fused in
  k_gather_t<1><<<NN * 64 / 256, 256, 0, stream>>>(in_feat, rowptr, col, onorm, inorm,
                                                   nullptr, bufA, v1);
  k_gather_t<2><<<NN * 64 / 256, 256, 0, stream>>>(bufA, rowptr, col, onorm, inorm,
                                                   v1, bufB, v2);
  k_gather_t<0><<<NN * 64 / 256, 256, 0, stream>>>(bufB, rowptr, col, onorm, inorm,
                                                   nullptr, bufA, nullptr);

  // out = g3 @ W123 + v2 c1^T + v1 c2^T + 1 b3^T
  k_gemm_f<<<1564, 256, 0, stream>>>(bufA, W123, c1, c2, b3, v1, v2, out);
}

// Round 10
// 377.960 us; speedup vs baseline: 4.6868x; 1.0001x over previous
//
#include <hip/hip_runtime.h>

// GCN: 3 layers GraphConv (norm='both'), N=50000, E=800000, D=128.
// Round 10: gather reverted to unroll-2 (unroll-4 A/B was flat -> pattern
// ceiling ~66us/pass); k_norms fused into k_scan_out; two k_vm128 merged.
//   out = (M^3 h) W123 + v2 c1^T + v1 c2^T + 1 b3^T
// with v1 = M·1, v2 = M·v1 fused into gathers 1/2.

#define NN 50000
#define NE 800000
#define DM 128
#define NB 196   // ceil(NN/256) scan blocks

#define FMA4(av, sv, wv) \
  av.x += (sv) * (wv).x; av.y += (sv) * (wv).y; av.z += (sv) * (wv).z; av.w += (sv) * (wv).w;

__global__ void k_count(const int* __restrict__ src, const int* __restrict__ dst,
                        int* __restrict__ co, int* __restrict__ ci) {
  int e = blockIdx.x * blockDim.x + threadIdx.x;
  if (e < NE) {
    atomicAdd(&co[src[e]], 1);
    atomicAdd(&ci[dst[e]], 1);
  }
}

// ---- hierarchical exclusive scan of ci -> rowptr, cursor (+norms fused) ----
__global__ void k_scan_part(const int* __restrict__ ci, int* __restrict__ bsum) {
  __shared__ int s[256];
  int i = blockIdx.x * 256 + threadIdx.x;
  s[threadIdx.x] = (i < NN) ? ci[i] : 0;
  __syncthreads();
  for (int off = 128; off > 0; off >>= 1) {
    if (threadIdx.x < off) s[threadIdx.x] += s[threadIdx.x + off];
    __syncthreads();
  }
  if (threadIdx.x == 0) bsum[blockIdx.x] = s[0];
}

__global__ void k_scan_mid(const int* __restrict__ bsum, int* __restrict__ boff,
                           int* __restrict__ rowptr) {
  __shared__ int s[256];
  int t = threadIdx.x;
  int v = (t < NB) ? bsum[t] : 0;
  s[t] = v;
  __syncthreads();
  for (int off = 1; off < 256; off <<= 1) {
    int u = (t >= off) ? s[t - off] : 0;
    __syncthreads();
    s[t] += u;
    __syncthreads();
  }
  if (t < NB) boff[t] = s[t] - v;  // exclusive
  if (t == 0) rowptr[NN] = NE;
}

__global__ void k_scan_out(const int* __restrict__ ci, const int* __restrict__ co,
                           const int* __restrict__ boff, int* __restrict__ rowptr,
                           int* __restrict__ cursor, float* __restrict__ onorm,
                           float* __restrict__ inorm) {
  __shared__ int s[256];
  int t = threadIdx.x;
  int i = blockIdx.x * 256 + t;
  int v = (i < NN) ? ci[i] : 0;
  s[t] = v;
  __syncthreads();
  for (int off = 1; off < 256; off <<= 1) {
    int u = (t >= off) ? s[t - off] : 0;
    __syncthreads();
    s[t] += u;
    __syncthreads();
  }
  if (i < NN) {
    int ex = boff[blockIdx.x] + s[t] - v;
    rowptr[i] = ex;
    cursor[i] = ex;
    onorm[i] = rsqrtf(fmaxf((float)co[i], 1.0f));
    inorm[i] = rsqrtf(fmaxf((float)v, 1.0f));
  }
}

__global__ void k_fill(const int* __restrict__ src, const int* __restrict__ dst,
                       int* __restrict__ cursor, int* __restrict__ col) {
  int e = blockIdx.x * blockDim.x + threadIdx.x;
  if (e < NE) {
    int p = atomicAdd(&cursor[dst[e]], 1);
    col[p] = src[e];
  }
}

// ---- tiny dense helpers ----
__global__ void k_mm128(const float* __restrict__ A, const float* __restrict__ B,
                        float* __restrict__ C) {
  int i = blockIdx.x, j = threadIdx.x;
  float acc = 0.f;
  for (int k = 0; k < DM; ++k) acc += A[i * DM + k] * B[k * DM + j];
  C[i * DM + j] = acc;
}

// block 0: c1 = b1 @ W23 ; block 1: c2 = b2 @ W3
__global__ void k_vm2(const float* __restrict__ b1, const float* __restrict__ W23,
                      const float* __restrict__ b2, const float* __restrict__ W3,
                      float* __restrict__ c1, float* __restrict__ c2) {
  int j = threadIdx.x;
  const float* bv = blockIdx.x ? b2 : b1;
  const float* B  = blockIdx.x ? W3 : W23;
  float* cv       = blockIdx.x ? c2 : c1;
  float acc = 0.f;
  for (int k = 0; k < DM; ++k) acc += bv[k] * B[k * DM + j];
  cv[j] = acc;
}

// ---- feature gather: Y = M X. One 64-lane wave per node; halves take
// even/odd edges (unroll 2 per half = 4 rows in flight); shfl-xor(32) reduce.
// VMODE 0: features only. 1: also vout = M·1. 2: also vout = M·vin.
template <int VMODE>
__global__ void k_gather_t(const float* __restrict__ h, const int* __restrict__ rowptr,
                           const int* __restrict__ col, const float* __restrict__ onorm,
                           const float* __restrict__ inorm, const float* __restrict__ vin,
                           float* __restrict__ agg, float* __restrict__ vout) {
  int tid = blockIdx.x * blockDim.x + threadIdx.x;
  int n = tid >> 6;
  if (n >= NN) return;
  int lane = threadIdx.x & 63;
  int half = lane >> 5;
  int l32 = lane & 31;
  int beg = rowptr[n], end = rowptr[n + 1];
  const float4* h4 = reinterpret_cast<const float4*>(h);
  float4 a0 = make_float4(0.f, 0.f, 0.f, 0.f);
  float4 a1 = make_float4(0.f, 0.f, 0.f, 0.f);
  float av = 0.f;
  int e = beg + half;
  for (; e + 2 < end; e += 4) {
    int s0 = col[e], s1 = col[e + 2];
    float n0 = onorm[s0], n1 = onorm[s1];
    float4 v0 = h4[(size_t)s0 * 32 + l32];
    float4 v1 = h4[(size_t)s1 * 32 + l32];
    if (VMODE == 1) av += n0 + n1;
    if (VMODE == 2) av += n0 * vin[s0] + n1 * vin[s1];
    FMA4(a0, n0, v0)
    FMA4(a1, n1, v1)
  }
  if (e < end) {
    int s0 = col[e];
    float n0 = onorm[s0];
    float4 v0 = h4[(size_t)s0 * 32 + l32];
    if (VMODE == 1) av += n0;
    if (VMODE == 2) av += n0 * vin[s0];
    FMA4(a0, n0, v0)
  }
  a0.x += a1.x; a0.y += a1.y; a0.z += a1.z; a0.w += a1.w;
  a0.x += __shfl_xor(a0.x, 32);
  a0.y += __shfl_xor(a0.y, 32);
  a0.z += __shfl_xor(a0.z, 32);
  a0.w += __shfl_xor(a0.w, 32);
  if (VMODE) av += __shfl_xor(av, 32);
  if (half == 0) {
    float sc = inorm[n];
    reinterpret_cast<float4*>(agg)[n * 32 + l32] =
        make_float4(a0.x * sc, a0.y * sc, a0.z * sc, a0.w * sc);
    if (VMODE && l32 == 0) vout[n] = av * sc;
  }
}

// ---- final GEMM: out = x @ W + v2*c1^T + v1*c2^T + 1*c3^T ----
// Split-j 64-col halves (32KB W tile). Block 256 = 16 slots x 16 lanes;
// thread = 2 rows x 4 cols, all-b128 LDS reads. 32 rows/pass, 2 passes.
__launch_bounds__(256, 3)
__global__ void k_gemm_f(const float* __restrict__ x, const float* __restrict__ W,
                         const float* __restrict__ c1, const float* __restrict__ c2,
                         const float* __restrict__ c3, const float* __restrict__ v1,
                         const float* __restrict__ v2, float* __restrict__ out) {
  __shared__ float Wl[DM * 64];     // 32 KB
  __shared__ float xs[32 * 132];    // 16.9 KB

  int jhalf = blockIdx.x & 1;
  int grp   = blockIdx.x >> 1;      // 0..781
  int jbase = jhalf * 64;

  {
    const float4* W4 = reinterpret_cast<const float4*>(W);
    float4* Wl4 = reinterpret_cast<float4*>(Wl);
    for (int i = threadIdx.x; i < DM * 16; i += 256) {
      int k = i >> 4, j4 = i & 15;
      Wl4[i] = W4[k * 32 + jhalf * 16 + j4];
    }
  }

  int slot = threadIdx.x >> 4;      // 0..15
  int lane = threadIdx.x & 15;      // 0..15
  int jc = lane * 4;
  float4 e1 = *reinterpret_cast<const float4*>(&c1[jbase + jc]);
  float4 e2 = *reinterpret_cast<const float4*>(&c2[jbase + jc]);
  float4 e3 = *reinterpret_cast<const float4*>(&c3[jbase + jc]);

  for (int p = 0; p < 2; ++p) {
    int rbase = grp * 64 + p * 32;
    __syncthreads();  // Wl ready (p=0) / xs consumed (p=1)
    const float4* xg = reinterpret_cast<const float4*>(x) + (size_t)rbase * 32;
    float4* xs4 = reinterpret_cast<float4*>(xs);
    int lim = (NN - rbase) * 32;
    for (int i = threadIdx.x; i < 1024; i += 256) {
      int r = i >> 5, seg = i & 31;
      float4 v = (i < lim) ? xg[i] : make_float4(0.f, 0.f, 0.f, 0.f);
      xs4[r * 33 + seg] = v;
    }
    __syncthreads();

    int r0 = rbase + slot * 2;
    int r1 = r0 + 1;
    const float* x0 = &xs[(slot * 2 + 0) * 132];
    const float* x1 = &xs[(slot * 2 + 1) * 132];
    int rc0 = (r0 < NN) ? r0 : 0;
    int rc1 = (r1 < NN) ? r1 : 0;
    float rv10 = v1[rc0], rv20 = v2[rc0];
    float rv11 = v1[rc1], rv21 = v2[rc1];
    float4 a0, a1;
    a0.x = rv20 * e1.x + rv10 * e2.x + e3.x;
    a0.y = rv20 * e1.y + rv10 * e2.y + e3.y;
    a0.z = rv20 * e1.z + rv10 * e2.z + e3.z;
    a0.w = rv20 * e1.w + rv10 * e2.w + e3.w;
    a1.x = rv21 * e1.x + rv11 * e2.x + e3.x;
    a1.y = rv21 * e1.y + rv11 * e2.y + e3.y;
    a1.z = rv21 * e1.z + rv11 * e2.z + e3.z;
    a1.w = rv21 * e1.w + rv11 * e2.w + e3.w;

    for (int k4 = 0; k4 < DM; k4 += 4) {
      float4 xv0 = *reinterpret_cast<const float4*>(&x0[k4]);
      float4 xv1 = *reinterpret_cast<const float4*>(&x1[k4]);
      float4 w0 = *reinterpret_cast<const float4*>(&Wl[(k4 + 0) * 64 + jc]);
      float4 w1 = *reinterpret_cast<const float4*>(&Wl[(k4 + 1) * 64 + jc]);
      float4 w2 = *reinterpret_cast<const float4*>(&Wl[(k4 + 2) * 64 + jc]);
      float4 w3 = *reinterpret_cast<const float4*>(&Wl[(k4 + 3) * 64 + jc]);
      FMA4(a0, xv0.x, w0) FMA4(a0, xv0.y, w1) FMA4(a0, xv0.z, w2) FMA4(a0, xv0.w, w3)
      FMA4(a1, xv1.x, w0) FMA4(a1, xv1.y, w1) FMA4(a1, xv1.z, w2) FMA4(a1, xv1.w, w3)
    }

    if (r0 < NN) *reinterpret_cast<float4*>(&out[(size_t)r0 * DM + jbase + jc]) = a0;
    if (r1 < NN) *reinterpret_cast<float4*>(&out[(size_t)r1 * DM + jbase + jc]) = a1;
  }
}

extern "C" void kernel_launch(void* const* d_in, const int* in_sizes, int n_in,
                              void* d_out, int out_size, void* d_ws, size_t ws_size,
                              hipStream_t stream) {
  const float* in_feat = (const float*)d_in[0];
  const int*   ei      = (const int*)d_in[1];
  const float* Ws      = (const float*)d_in[2];
  const float* bs      = (const float*)d_in[3];
  float* out = (float*)d_out;

  const int* src = ei;
  const int* dst = ei + NE;
  const float* W1 = Ws;
  const float* W2 = Ws + DM * DM;
  const float* W3 = Ws + 2 * DM * DM;
  const float* b1 = bs;
  const float* b2 = bs + DM;
  const float* b3 = bs + 2 * DM;

  char* w = (char*)d_ws;
  int* co     = (int*)w;            w += NN * sizeof(int);
  int* ci     = (int*)w;            w += NN * sizeof(int);
  int* rowptr = (int*)w;            w += (NN + 1) * sizeof(int);
  int* cursor = (int*)w;            w += NN * sizeof(int);
  int* bsum   = (int*)w;            w += NB * sizeof(int);
  int* boff   = (int*)w;            w += NB * sizeof(int);
  int* col    = (int*)w;            w += NE * sizeof(int);
  float* onorm = (float*)w;         w += NN * sizeof(float);
  float* inorm = (float*)w;         w += NN * sizeof(float);
  float* v1    = (float*)w;         w += NN * sizeof(float);
  float* v2    = (float*)w;         w += NN * sizeof(float);
  float* W23   = (float*)w;         w += DM * DM * sizeof(float);
  float* W123  = (float*)w;         w += DM * DM * sizeof(float);
  float* c1    = (float*)w;         w += DM * sizeof(float);
  float* c2    = (float*)w;         w += DM * sizeof(float);
  float* bufA  = (float*)w;         w += (size_t)NN * DM * sizeof(float);
  float* bufB  = (float*)w;

  // graph preprocessing
  hipMemsetAsync(co, 0, 2 * NN * sizeof(int), stream);  // co+ci contiguous
  k_count<<<(NE + 255) / 256, 256, 0, stream>>>(src, dst, co, ci);
  k_scan_part<<<NB, 256, 0, stream>>>(ci, bsum);
  k_scan_mid<<<1, 256, 0, stream>>>(bsum, boff, rowptr);
  k_scan_out<<<NB, 256, 0, stream>>>(ci, co, boff, rowptr, cursor, onorm, inorm);
  k_fill<<<(NE + 255) / 256, 256, 0, stream>>>(src, dst, cursor, col);

  // weight/bias collapse: W23 = W2 W3; W123 = W1 W23; c1 = b1 W23; c2 = b2 W3
  k_mm128<<<DM, DM, 0, stream>>>(W2, W3, W23);
  k_mm128<<<DM, DM, 0, stream>>>(W1, W23, W123);
  k_vm2<<<2, DM, 0, stream>>>(b1, W23, b2, W3, c1, c2);

  // g3 = M^3 h, with v1 = M 1 (gather 1) and v2 = M v1 (gather 2) fused in
  k_gather_t<1><<<NN * 64 / 256, 256, 0, stream>>>(in_feat, rowptr, col, onorm, inorm,
                                                   nullptr, bufA, v1);
  k_gather_t<2><<<NN * 64 / 256, 256, 0, stream>>>(bufA, rowptr, col, onorm, inorm,
                                                   v1, bufB, v2);
  k_gather_t<0><<<NN * 64 / 256, 256, 0, stream>>>(bufB, rowptr, col, onorm, inorm,
                                                   nullptr, bufA, nullptr);

  // out = g3 @ W123 + v2 c1^T + v1 c2^T + 1 b3^T
  k_gemm_f<<<1564, 256, 0, stream>>>(bufA, W123, c1, c2, b3, v1, v2, out);
}

// Round 11
// 358.586 us; speedup vs baseline: 4.9400x; 1.0540x over previous
//
#include <hip/hip_runtime.h>

// GCN: 3 layers GraphConv (norm='both'), N=50000, E=800000, D=128.
// Round 11: (a) weight-collapse mm/vm kernels ride as extra blocks on
// gather1/gather2 (idle VALU there; -3 dispatches); (b) GEMM 4rx4c/thread,
// single 64-row pass, broadcast b128 LDS reads (8 FMA/read), unroll-capped
// to avoid round-3 spill; (c) int4-vectorized count/fill.
//   out = (M^3 h) W123 + v2 c1^T + v1 c2^T + 1 b3^T,  v1=M·1, v2=M·v1.

#define NN 50000
#define NE 800000
#define DM 128
#define NB 196     // ceil(NN/256) scan blocks
#define NGB 12500  // gather blocks (NN*64/256)

#define FMA4(av, sv, wv) \
  av.x += (sv) * (wv).x; av.y += (sv) * (wv).y; av.z += (sv) * (wv).z; av.w += (sv) * (wv).w;

__global__ void k_count(const int* __restrict__ src, const int* __restrict__ dst,
                        int* __restrict__ co, int* __restrict__ ci) {
  int t = blockIdx.x * blockDim.x + threadIdx.x;
  if (t < NE / 4) {
    int4 s4 = reinterpret_cast<const int4*>(src)[t];
    int4 d4 = reinterpret_cast<const int4*>(dst)[t];
    atomicAdd(&co[s4.x], 1); atomicAdd(&co[s4.y], 1);
    atomicAdd(&co[s4.z], 1); atomicAdd(&co[s4.w], 1);
    atomicAdd(&ci[d4.x], 1); atomicAdd(&ci[d4.y], 1);
    atomicAdd(&ci[d4.z], 1); atomicAdd(&ci[d4.w], 1);
  }
}

// ---- hierarchical exclusive scan of ci -> rowptr, cursor (+norms fused) ----
__global__ void k_scan_part(const int* __restrict__ ci, int* __restrict__ bsum) {
  __shared__ int s[256];
  int i = blockIdx.x * 256 + threadIdx.x;
  s[threadIdx.x] = (i < NN) ? ci[i] : 0;
  __syncthreads();
  for (int off = 128; off > 0; off >>= 1) {
    if (threadIdx.x < off) s[threadIdx.x] += s[threadIdx.x + off];
    __syncthreads();
  }
  if (threadIdx.x == 0) bsum[blockIdx.x] = s[0];
}

__global__ void k_scan_mid(const int* __restrict__ bsum, int* __restrict__ boff,
                           int* __restrict__ rowptr) {
  __shared__ int s[256];
  int t = threadIdx.x;
  int v = (t < NB) ? bsum[t] : 0;
  s[t] = v;
  __syncthreads();
  for (int off = 1; off < 256; off <<= 1) {
    int u = (t >= off) ? s[t - off] : 0;
    __syncthreads();
    s[t] += u;
    __syncthreads();
  }
  if (t < NB) boff[t] = s[t] - v;  // exclusive
  if (t == 0) rowptr[NN] = NE;
}

__global__ void k_scan_out(const int* __restrict__ ci, const int* __restrict__ co,
                           const int* __restrict__ boff, int* __restrict__ rowptr,
                           int* __restrict__ cursor, float* __restrict__ onorm,
                           float* __restrict__ inorm) {
  __shared__ int s[256];
  int t = threadIdx.x;
  int i = blockIdx.x * 256 + t;
  int v = (i < NN) ? ci[i] : 0;
  s[t] = v;
  __syncthreads();
  for (int off = 1; off < 256; off <<= 1) {
    int u = (t >= off) ? s[t - off] : 0;
    __syncthreads();
    s[t] += u;
    __syncthreads();
  }
  if (i < NN) {
    int ex = boff[blockIdx.x] + s[t] - v;
    rowptr[i] = ex;
    cursor[i] = ex;
    onorm[i] = rsqrtf(fmaxf((float)co[i], 1.0f));
    inorm[i] = rsqrtf(fmaxf((float)v, 1.0f));
  }
}

__global__ void k_fill(const int* __restrict__ src, const int* __restrict__ dst,
                       int* __restrict__ cursor, int* __restrict__ col) {
  int t = blockIdx.x * blockDim.x + threadIdx.x;
  if (t < NE / 4) {
    int4 s4 = reinterpret_cast<const int4*>(src)[t];
    int4 d4 = reinterpret_cast<const int4*>(dst)[t];
    int p;
    p = atomicAdd(&cursor[d4.x], 1); col[p] = s4.x;
    p = atomicAdd(&cursor[d4.y], 1); col[p] = s4.y;
    p = atomicAdd(&cursor[d4.z], 1); col[p] = s4.z;
    p = atomicAdd(&cursor[d4.w], 1); col[p] = s4.w;
  }
}

// ---- feature gather: Y = M X. One 64-lane wave per node; halves take
// even/odd edges (unroll 2/half); shfl-xor(32) reduce.
// VMODE 0: features only. 1: also vout = M·1. 2: also vout = M·vin.
// EXTRA>=1: blocks beyond NGB compute mC = mA @ mB (64 blocks, 2 rows each).
// EXTRA==2: block NGB+64 computes vc1 = vb1 @ vB1, vc2 = vb2 @ vB2.
template <int VMODE, int EXTRA>
__global__ void k_gather_t(const float* __restrict__ h, const int* __restrict__ rowptr,
                           const int* __restrict__ col, const float* __restrict__ onorm,
                           const float* __restrict__ inorm, const float* __restrict__ vin,
                           float* __restrict__ agg, float* __restrict__ vout,
                           const float* __restrict__ mA, const float* __restrict__ mB,
                           float* __restrict__ mC,
                           const float* __restrict__ vb1, const float* __restrict__ vB1,
                           float* __restrict__ vc1,
                           const float* __restrict__ vb2, const float* __restrict__ vB2,
                           float* __restrict__ vc2) {
  if (EXTRA) {
    int eb = (int)blockIdx.x - NGB;
    if (eb >= 0) {
      if (eb < 64) {            // mC = mA @ mB, rows 2eb, 2eb+1
        int i0 = eb * 2 + (threadIdx.x >> 7);
        int j = threadIdx.x & 127;
        float acc = 0.f;
        for (int k = 0; k < DM; ++k) acc += mA[i0 * DM + k] * mB[k * DM + j];
        mC[i0 * DM + j] = acc;
      } else if (EXTRA == 2) {  // vc1 = vb1@vB1 (tid<128), vc2 = vb2@vB2
        int t = threadIdx.x;
        if (t < DM) {
          float acc = 0.f;
          for (int k = 0; k < DM; ++k) acc += vb1[k] * vB1[k * DM + t];
          vc1[t] = acc;
        } else {
          int j = t - DM;
          float acc = 0.f;
          for (int k = 0; k < DM; ++k) acc += vb2[k] * vB2[k * DM + j];
          vc2[j] = acc;
        }
      }
      return;
    }
  }
  int tid = blockIdx.x * blockDim.x + threadIdx.x;
  int n = tid >> 6;
  if (n >= NN) return;
  int lane = threadIdx.x & 63;
  int half = lane >> 5;
  int l32 = lane & 31;
  int beg = rowptr[n], end = rowptr[n + 1];
  const float4* h4 = reinterpret_cast<const float4*>(h);
  float4 a0 = make_float4(0.f, 0.f, 0.f, 0.f);
  float4 a1 = make_float4(0.f, 0.f, 0.f, 0.f);
  float av = 0.f;
  int e = beg + half;
  for (; e + 2 < end; e += 4) {
    int s0 = col[e], s1 = col[e + 2];
    float n0 = onorm[s0], n1 = onorm[s1];
    float4 v0 = h4[(size_t)s0 * 32 + l32];
    float4 v1 = h4[(size_t)s1 * 32 + l32];
    if (VMODE == 1) av += n0 + n1;
    if (VMODE == 2) av += n0 * vin[s0] + n1 * vin[s1];
    FMA4(a0, n0, v0)
    FMA4(a1, n1, v1)
  }
  if (e < end) {
    int s0 = col[e];
    float n0 = onorm[s0];
    float4 v0 = h4[(size_t)s0 * 32 + l32];
    if (VMODE == 1) av += n0;
    if (VMODE == 2) av += n0 * vin[s0];
    FMA4(a0, n0, v0)
  }
  a0.x += a1.x; a0.y += a1.y; a0.z += a1.z; a0.w += a1.w;
  a0.x += __shfl_xor(a0.x, 32);
  a0.y += __shfl_xor(a0.y, 32);
  a0.z += __shfl_xor(a0.z, 32);
  a0.w += __shfl_xor(a0.w, 32);
  if (VMODE) av += __shfl_xor(av, 32);
  if (half == 0) {
    float sc = inorm[n];
    reinterpret_cast<float4*>(agg)[n * 32 + l32] =
        make_float4(a0.x * sc, a0.y * sc, a0.z * sc, a0.w * sc);
    if (VMODE && l32 == 0) vout[n] = av * sc;
  }
}

// ---- final GEMM: out = x @ W + v2*c1^T + v1*c2^T + 1*c3^T ----
// Split-j 64-col halves (32KB W tile). Block 256 = 16 row-slots x 16 lanes;
// thread = 4 rows x 4 cols; 64 rows per block, single pass. All LDS reads
// are b128 and wave-broadcast (x uniform across lanes, W uniform across
// slots): 8 FMA per ds_read_b128.
__launch_bounds__(256, 2)
__global__ void k_gemm_f(const float* __restrict__ x, const float* __restrict__ W,
                         const float* __restrict__ c1, const float* __restrict__ c2,
                         const float* __restrict__ c3, const float* __restrict__ v1,
                         const float* __restrict__ v2, float* __restrict__ out) {
  __shared__ float Wl[DM * 64];     // 32 KB
  __shared__ float xs[64 * 132];    // 33.8 KB (pad keeps staging coalesced)

  int jhalf = blockIdx.x & 1;
  int grp   = blockIdx.x >> 1;      // 0..781
  int jbase = jhalf * 64;
  int rbase = grp * 64;

  {
    const float4* W4 = reinterpret_cast<const float4*>(W);
    float4* Wl4 = reinterpret_cast<float4*>(Wl);
    for (int i = threadIdx.x; i < DM * 16; i += 256) {
      int k = i >> 4, j4 = i & 15;
      Wl4[k * 16 + j4] = W4[k * 32 + jhalf * 16 + j4];
    }
    const float4* xg = reinterpret_cast<const float4*>(x) + (size_t)rbase * 32;
    float4* xs4 = reinterpret_cast<float4*>(xs);
    int lim = (NN - rbase) * 32;
    for (int i = threadIdx.x; i < 2048; i += 256) {
      int r = i >> 5, seg = i & 31;
      float4 v = (i < lim) ? xg[i] : make_float4(0.f, 0.f, 0.f, 0.f);
      xs4[r * 33 + seg] = v;
    }
  }
  __syncthreads();

  int slot = threadIdx.x >> 4;      // 0..15 -> 4 rows each
  int lane = threadIdx.x & 15;      // 0..15 -> 4 cols each
  int jc = lane * 4;
  float4 e1 = *reinterpret_cast<const float4*>(&c1[jbase + jc]);
  float4 e2 = *reinterpret_cast<const float4*>(&c2[jbase + jc]);
  float4 e3 = *reinterpret_cast<const float4*>(&c3[jbase + jc]);

  int r0 = rbase + slot * 4;
  int rc0 = (r0 < NN) ? r0 : NN - 1;
  int rc1 = (r0 + 1 < NN) ? r0 + 1 : NN - 1;
  int rc2 = (r0 + 2 < NN) ? r0 + 2 : NN - 1;
  int rc3 = (r0 + 3 < NN) ? r0 + 3 : NN - 1;
  const float* x0 = &xs[(slot * 4 + 0) * 132];
  const float* x1 = &xs[(slot * 4 + 1) * 132];
  const float* x2 = &xs[(slot * 4 + 2) * 132];
  const float* x3 = &xs[(slot * 4 + 3) * 132];

  float4 a0, a1, a2, a3;
  {
    float q1, q2;
    q1 = v1[rc0]; q2 = v2[rc0];
    a0.x = q2 * e1.x + q1 * e2.x + e3.x; a0.y = q2 * e1.y + q1 * e2.y + e3.y;
    a0.z = q2 * e1.z + q1 * e2.z + e3.z; a0.w = q2 * e1.w + q1 * e2.w + e3.w;
    q1 = v1[rc1]; q2 = v2[rc1];
    a1.x = q2 * e1.x + q1 * e2.x + e3.x; a1.y = q2 * e1.y + q1 * e2.y + e3.y;
    a1.z = q2 * e1.z + q1 * e2.z + e3.z; a1.w = q2 * e1.w + q1 * e2.w + e3.w;
    q1 = v1[rc2]; q2 = v2[rc2];
    a2.x = q2 * e1.x + q1 * e2.x + e3.x; a2.y = q2 * e1.y + q1 * e2.y + e3.y;
    a2.z = q2 * e1.z + q1 * e2.z + e3.z; a2.w = q2 * e1.w + q1 * e2.w + e3.w;
    q1 = v1[rc3]; q2 = v2[rc3];
    a3.x = q2 * e1.x + q1 * e2.x + e3.x; a3.y = q2 * e1.y + q1 * e2.y + e3.y;
    a3.z = q2 * e1.z + q1 * e2.z + e3.z; a3.w = q2 * e1.w + q1 * e2.w + e3.w;
  }

#pragma unroll 4
  for (int k4 = 0; k4 < DM; k4 += 4) {
    float4 xv0 = *reinterpret_cast<const float4*>(&x0[k4]);
    float4 xv1 = *reinterpret_cast<const float4*>(&x1[k4]);
    float4 xv2 = *reinterpret_cast<const float4*>(&x2[k4]);
    float4 xv3 = *reinterpret_cast<const float4*>(&x3[k4]);
    float4 w0 = *reinterpret_cast<const float4*>(&Wl[(k4 + 0) * 64 + jc]);
    float4 w1 = *reinterpret_cast<const float4*>(&Wl[(k4 + 1) * 64 + jc]);
    float4 w2 = *reinterpret_cast<const float4*>(&Wl[(k4 + 2) * 64 + jc]);
    float4 w3 = *reinterpret_cast<const float4*>(&Wl[(k4 + 3) * 64 + jc]);
    FMA4(a0, xv0.x, w0) FMA4(a0, xv0.y, w1) FMA4(a0, xv0.z, w2) FMA4(a0, xv0.w, w3)
    FMA4(a1, xv1.x, w0) FMA4(a1, xv1.y, w1) FMA4(a1, xv1.z, w2) FMA4(a1, xv1.w, w3)
    FMA4(a2, xv2.x, w0) FMA4(a2, xv2.y, w1) FMA4(a2, xv2.z, w2) FMA4(a2, xv2.w, w3)
    FMA4(a3, xv3.x, w0) FMA4(a3, xv3.y, w1) FMA4(a3, xv3.z, w2) FMA4(a3, xv3.w, w3)
  }

  float* o = out + (size_t)r0 * DM + jbase + jc;
  if (r0 + 3 < NN) {
    *reinterpret_cast<float4*>(o)          = a0;
    *reinterpret_cast<float4*>(o + DM)     = a1;
    *reinterpret_cast<float4*>(o + 2 * DM) = a2;
    *reinterpret_cast<float4*>(o + 3 * DM) = a3;
  } else {
    if (r0 + 0 < NN) *reinterpret_cast<float4*>(o)          = a0;
    if (r0 + 1 < NN) *reinterpret_cast<float4*>(o + DM)     = a1;
    if (r0 + 2 < NN) *reinterpret_cast<float4*>(o + 2 * DM) = a2;
  }
}

extern "C" void kernel_launch(void* const* d_in, const int* in_sizes, int n_in,
                              void* d_out, int out_size, void* d_ws, size_t ws_size,
                              hipStream_t stream) {
  const float* in_feat = (const float*)d_in[0];
  const int*   ei      = (const int*)d_in[1];
  const float* Ws      = (const float*)d_in[2];
  const float* bs      = (const float*)d_in[3];
  float* out = (float*)d_out;

  const int* src = ei;
  const int* dst = ei + NE;
  const float* W1 = Ws;
  const float* W2 = Ws + DM * DM;
  const float* W3 = Ws + 2 * DM * DM;
  const float* b1 = bs;
  const float* b2 = bs + DM;
  const float* b3 = bs + 2 * DM;

  char* w = (char*)d_ws;
  int* co     = (int*)w;            w += NN * sizeof(int);
  int* ci     = (int*)w;            w += NN * sizeof(int);
  int* rowptr = (int*)w;            w += (NN + 1) * sizeof(int);
  int* cursor = (int*)w;            w += NN * sizeof(int);
  int* bsum   = (int*)w;            w += NB * sizeof(int);
  int* boff   = (int*)w;            w += NB * sizeof(int);
  int* col    = (int*)w;            w += NE * sizeof(int);
  float* onorm = (float*)w;         w += NN * sizeof(float);
  float* inorm = (float*)w;         w += NN * sizeof(float);
  float* v1    = (float*)w;         w += NN * sizeof(float);
  float* v2    = (float*)w;         w += NN * sizeof(float);
  float* W23   = (float*)w;         w += DM * DM * sizeof(float);
  float* W123  = (float*)w;         w += DM * DM * sizeof(float);
  float* c1    = (float*)w;         w += DM * sizeof(float);
  float* c2    = (float*)w;         w += DM * sizeof(float);
  float* bufA  = (float*)w;         w += (size_t)NN * DM * sizeof(float);
  float* bufB  = (float*)w;

  // graph preprocessing
  hipMemsetAsync(co, 0, 2 * NN * sizeof(int), stream);  // co+ci contiguous
  k_count<<<(NE / 4 + 255) / 256, 256, 0, stream>>>(src, dst, co, ci);
  k_scan_part<<<NB, 256, 0, stream>>>(ci, bsum);
  k_scan_mid<<<1, 256, 0, stream>>>(bsum, boff, rowptr);
  k_scan_out<<<NB, 256, 0, stream>>>(ci, co, boff, rowptr, cursor, onorm, inorm);
  k_fill<<<(NE / 4 + 255) / 256, 256, 0, stream>>>(src, dst, cursor, col);

  // g3 = M^3 h; v1 = M·1 rides gather1, v2 = M·v1 rides gather2;
  // W23 = W2 W3 rides gather1; W123 = W1 W23, c1 = b1 W23, c2 = b2 W3 ride gather2.
  k_gather_t<1, 1><<<NGB + 64, 256, 0, stream>>>(in_feat, rowptr, col, onorm, inorm,
                                                 nullptr, bufA, v1,
                                                 W2, W3, W23,
                                                 nullptr, nullptr, nullptr,
                                                 nullptr, nullptr, nullptr);
  k_gather_t<2, 2><<<NGB + 65, 256, 0, stream>>>(bufA, rowptr, col, onorm, inorm,
                                                 v1, bufB, v2,
                                                 W1, W23, W123,
                                                 b1, W23, c1, b2, W3, c2);
  k_gather_t<0, 0><<<NGB, 256, 0, stream>>>(bufB, rowptr, col, onorm, inorm,
                                            nullptr, bufA, nullptr,
                                            nullptr, nullptr, nullptr,
                                            nullptr, nullptr, nullptr,
                                            nullptr, nullptr, nullptr);

  // out = g3 @ W123 + v2 c1^T + v1 c2^T + 1 b3^T
  k_gemm_f<<<1564, 256, 0, stream>>>(bufA, W123, c1, c2, b3, v1, v2, out);
}

// Round 12
// 357.196 us; speedup vs baseline: 4.9593x; 1.0039x over previous
//
#include <hip/hip_runtime.h>

// GCN: 3 layers GraphConv (norm='both'), N=50000, E=800000, D=128.
// Round 12: XCD-privatized degree histograms (8 copies, blockIdx&7 proxy)
// -> kills device-scope atomic line ping-pong in k_count (was 69us, 50MB
// write-through). 8-way sum folded into k_scan_part. Rest as round 11.
//   out = (M^3 h) W123 + v2 c1^T + v1 c2^T + 1 b3^T,  v1=M·1, v2=M·v1.

#define NN 50000
#define NE 800000
#define DM 128
#define NB 196     // ceil(NN/256) scan blocks
#define NGB 12500  // gather blocks (NN*64/256)

#define FMA4(av, sv, wv) \
  av.x += (sv) * (wv).x; av.y += (sv) * (wv).y; av.z += (sv) * (wv).z; av.w += (sv) * (wv).w;

// 8 privatized copies: cnt8[k][0..NN) = co_k, cnt8[k][NN..2NN) = ci_k
__global__ void k_count(const int* __restrict__ src, const int* __restrict__ dst,
                        int* __restrict__ cnt8) {
  int t = blockIdx.x * blockDim.x + threadIdx.x;
  int* co = cnt8 + (size_t)(blockIdx.x & 7) * 2 * NN;
  int* ci = co + NN;
  if (t < NE / 4) {
    int4 s4 = reinterpret_cast<const int4*>(src)[t];
    int4 d4 = reinterpret_cast<const int4*>(dst)[t];
    atomicAdd(&co[s4.x], 1); atomicAdd(&co[s4.y], 1);
    atomicAdd(&co[s4.z], 1); atomicAdd(&co[s4.w], 1);
    atomicAdd(&ci[d4.x], 1); atomicAdd(&ci[d4.y], 1);
    atomicAdd(&ci[d4.z], 1); atomicAdd(&ci[d4.w], 1);
  }
}

// ---- hierarchical exclusive scan of ci -> rowptr, cursor (+norms fused) ----
// Also reduces the 8 privatized copies into compact co/ci.
__global__ void k_scan_part(const int* __restrict__ cnt8, int* __restrict__ co,
                            int* __restrict__ ci, int* __restrict__ bsum) {
  __shared__ int s[256];
  int i = blockIdx.x * 256 + threadIdx.x;
  int sco = 0, sci = 0;
  if (i < NN) {
#pragma unroll
    for (int k = 0; k < 8; ++k) {
      sco += cnt8[(size_t)k * 2 * NN + i];
      sci += cnt8[(size_t)k * 2 * NN + NN + i];
    }
    co[i] = sco;
    ci[i] = sci;
  }
  s[threadIdx.x] = sci;
  __syncthreads();
  for (int off = 128; off > 0; off >>= 1) {
    if (threadIdx.x < off) s[threadIdx.x] += s[threadIdx.x + off];
    __syncthreads();
  }
  if (threadIdx.x == 0) bsum[blockIdx.x] = s[0];
}

__global__ void k_scan_mid(const int* __restrict__ bsum, int* __restrict__ boff,
                           int* __restrict__ rowptr) {
  __shared__ int s[256];
  int t = threadIdx.x;
  int v = (t < NB) ? bsum[t] : 0;
  s[t] = v;
  __syncthreads();
  for (int off = 1; off < 256; off <<= 1) {
    int u = (t >= off) ? s[t - off] : 0;
    __syncthreads();
    s[t] += u;
    __syncthreads();
  }
  if (t < NB) boff[t] = s[t] - v;  // exclusive
  if (t == 0) rowptr[NN] = NE;
}

__global__ void k_scan_out(const int* __restrict__ ci, const int* __restrict__ co,
                           const int* __restrict__ boff, int* __restrict__ rowptr,
                           int* __restrict__ cursor, float* __restrict__ onorm,
                           float* __restrict__ inorm) {
  __shared__ int s[256];
  int t = threadIdx.x;
  int i = blockIdx.x * 256 + t;
  int v = (i < NN) ? ci[i] : 0;
  s[t] = v;
  __syncthreads();
  for (int off = 1; off < 256; off <<= 1) {
    int u = (t >= off) ? s[t - off] : 0;
    __syncthreads();
    s[t] += u;
    __syncthreads();
  }
  if (i < NN) {
    int ex = boff[blockIdx.x] + s[t] - v;
    rowptr[i] = ex;
    cursor[i] = ex;
    onorm[i] = rsqrtf(fmaxf((float)co[i], 1.0f));
    inorm[i] = rsqrtf(fmaxf((float)v, 1.0f));
  }
}

__global__ void k_fill(const int* __restrict__ src, const int* __restrict__ dst,
                       int* __restrict__ cursor, int* __restrict__ col) {
  int t = blockIdx.x * blockDim.x + threadIdx.x;
  if (t < NE / 4) {
    int4 s4 = reinterpret_cast<const int4*>(src)[t];
    int4 d4 = reinterpret_cast<const int4*>(dst)[t];
    int p;
    p = atomicAdd(&cursor[d4.x], 1); col[p] = s4.x;
    p = atomicAdd(&cursor[d4.y], 1); col[p] = s4.y;
    p = atomicAdd(&cursor[d4.z], 1); col[p] = s4.z;
    p = atomicAdd(&cursor[d4.w], 1); col[p] = s4.w;
  }
}

// ---- feature gather: Y = M X. One 64-lane wave per node; halves take
// even/odd edges (unroll 2/half); shfl-xor(32) reduce.
// VMODE 0: features only. 1: also vout = M·1. 2: also vout = M·vin.
// EXTRA>=1: blocks beyond NGB compute mC = mA @ mB (64 blocks, 2 rows each).
// EXTRA==2: block NGB+64 computes vc1 = vb1 @ vB1, vc2 = vb2 @ vB2.
template <int VMODE, int EXTRA>
__global__ void k_gather_t(const float* __restrict__ h, const int* __restrict__ rowptr,
                           const int* __restrict__ col, const float* __restrict__ onorm,
                           const float* __restrict__ inorm, const float* __restrict__ vin,
                           float* __restrict__ agg, float* __restrict__ vout,
                           const float* __restrict__ mA, const float* __restrict__ mB,
                           float* __restrict__ mC,
                           const float* __restrict__ vb1, const float* __restrict__ vB1,
                           float* __restrict__ vc1,
                           const float* __restrict__ vb2, const float* __restrict__ vB2,
                           float* __restrict__ vc2) {
  if (EXTRA) {
    int eb = (int)blockIdx.x - NGB;
    if (eb >= 0) {
      if (eb < 64) {            // mC = mA @ mB, rows 2eb, 2eb+1
        int i0 = eb * 2 + (threadIdx.x >> 7);
        int j = threadIdx.x & 127;
        float acc = 0.f;
        for (int k = 0; k < DM; ++k) acc += mA[i0 * DM + k] * mB[k * DM + j];
        mC[i0 * DM + j] = acc;
      } else if (EXTRA == 2) {  // vc1 = vb1@vB1 (tid<128), vc2 = vb2@vB2
        int t = threadIdx.x;
        if (t < DM) {
          float acc = 0.f;
          for (int k = 0; k < DM; ++k) acc += vb1[k] * vB1[k * DM + t];
          vc1[t] = acc;
        } else {
          int j = t - DM;
          float acc = 0.f;
          for (int k = 0; k < DM; ++k) acc += vb2[k] * vB2[k * DM + j];
          vc2[j] = acc;
        }
      }
      return;
    }
  }
  int tid = blockIdx.x * blockDim.x + threadIdx.x;
  int n = tid >> 6;
  if (n >= NN) return;
  int lane = threadIdx.x & 63;
  int half = lane >> 5;
  int l32 = lane & 31;
  int beg = rowptr[n], end = rowptr[n + 1];
  const float4* h4 = reinterpret_cast<const float4*>(h);
  float4 a0 = make_float4(0.f, 0.f, 0.f, 0.f);
  float4 a1 = make_float4(0.f, 0.f, 0.f, 0.f);
  float av = 0.f;
  int e = beg + half;
  for (; e + 2 < end; e += 4) {
    int s0 = col[e], s1 = col[e + 2];
    float n0 = onorm[s0], n1 = onorm[s1];
    float4 v0 = h4[(size_t)s0 * 32 + l32];
    float4 v1 = h4[(size_t)s1 * 32 + l32];
    if (VMODE == 1) av += n0 + n1;
    if (VMODE == 2) av += n0 * vin[s0] + n1 * vin[s1];
    FMA4(a0, n0, v0)
    FMA4(a1, n1, v1)
  }
  if (e < end) {
    int s0 = col[e];
    float n0 = onorm[s0];
    float4 v0 = h4[(size_t)s0 * 32 + l32];
    if (VMODE == 1) av += n0;
    if (VMODE == 2) av += n0 * vin[s0];
    FMA4(a0, n0, v0)
  }
  a0.x += a1.x; a0.y += a1.y; a0.z += a1.z; a0.w += a1.w;
  a0.x += __shfl_xor(a0.x, 32);
  a0.y += __shfl_xor(a0.y, 32);
  a0.z += __shfl_xor(a0.z, 32);
  a0.w += __shfl_xor(a0.w, 32);
  if (VMODE) av += __shfl_xor(av, 32);
  if (half == 0) {
    float sc = inorm[n];
    reinterpret_cast<float4*>(agg)[n * 32 + l32] =
        make_float4(a0.x * sc, a0.y * sc, a0.z * sc, a0.w * sc);
    if (VMODE && l32 == 0) vout[n] = av * sc;
  }
}

// ---- final GEMM: out = x @ W + v2*c1^T + v1*c2^T + 1*c3^T ----
// Split-j 64-col halves (32KB W tile). Block 256 = 16 row-slots x 16 lanes;
// thread = 4 rows x 4 cols; 64 rows per block, single pass. All LDS reads
// b128 and wave-broadcast: 8 FMA per ds_read_b128.
__launch_bounds__(256, 2)
__global__ void k_gemm_f(const float* __restrict__ x, const float* __restrict__ W,
                         const float* __restrict__ c1, const float* __restrict__ c2,
                         const float* __restrict__ c3, const float* __restrict__ v1,
                         const float* __restrict__ v2, float* __restrict__ out) {
  __shared__ float Wl[DM * 64];     // 32 KB
  __shared__ float xs[64 * 132];    // 33.8 KB

  int jhalf = blockIdx.x & 1;
  int grp   = blockIdx.x >> 1;      // 0..781
  int jbase = jhalf * 64;
  int rbase = grp * 64;

  {
    const float4* W4 = reinterpret_cast<const float4*>(W);
    float4* Wl4 = reinterpret_cast<float4*>(Wl);
    for (int i = threadIdx.x; i < DM * 16; i += 256) {
      int k = i >> 4, j4 = i & 15;
      Wl4[k * 16 + j4] = W4[k * 32 + jhalf * 16 + j4];
    }
    const float4* xg = reinterpret_cast<const float4*>(x) + (size_t)rbase * 32;
    float4* xs4 = reinterpret_cast<float4*>(xs);
    int lim = (NN - rbase) * 32;
    for (int i = threadIdx.x; i < 2048; i += 256) {
      int r = i >> 5, seg = i & 31;
      float4 v = (i < lim) ? xg[i] : make_float4(0.f, 0.f, 0.f, 0.f);
      xs4[r * 33 + seg] = v;
    }
  }
  __syncthreads();

  int slot = threadIdx.x >> 4;      // 0..15 -> 4 rows each
  int lane = threadIdx.x & 15;      // 0..15 -> 4 cols each
  int jc = lane * 4;
  float4 e1 = *reinterpret_cast<const float4*>(&c1[jbase + jc]);
  float4 e2 = *reinterpret_cast<const float4*>(&c2[jbase + jc]);
  float4 e3 = *reinterpret_cast<const float4*>(&c3[jbase + jc]);

  int r0 = rbase + slot * 4;
  int rc0 = (r0 < NN) ? r0 : NN - 1;
  int rc1 = (r0 + 1 < NN) ? r0 + 1 : NN - 1;
  int rc2 = (r0 + 2 < NN) ? r0 + 2 : NN - 1;
  int rc3 = (r0 + 3 < NN) ? r0 + 3 : NN - 1;
  const float* x0 = &xs[(slot * 4 + 0) * 132];
  const float* x1 = &xs[(slot * 4 + 1) * 132];
  const float* x2 = &xs[(slot * 4 + 2) * 132];
  const float* x3 = &xs[(slot * 4 + 3) * 132];

  float4 a0, a1, a2, a3;
  {
    float q1, q2;
    q1 = v1[rc0]; q2 = v2[rc0];
    a0.x = q2 * e1.x + q1 * e2.x + e3.x; a0.y = q2 * e1.y + q1 * e2.y + e3.y;
    a0.z = q2 * e1.z + q1 * e2.z + e3.z; a0.w = q2 * e1.w + q1 * e2.w + e3.w;
    q1 = v1[rc1]; q2 = v2[rc1];
    a1.x = q2 * e1.x + q1 * e2.x + e3.x; a1.y = q2 * e1.y + q1 * e2.y + e3.y;
    a1.z = q2 * e1.z + q1 * e2.z + e3.z; a1.w = q2 * e1.w + q1 * e2.w + e3.w;
    q1 = v1[rc2]; q2 = v2[rc2];
    a2.x = q2 * e1.x + q1 * e2.x + e3.x; a2.y = q2 * e1.y + q1 * e2.y + e3.y;
    a2.z = q2 * e1.z + q1 * e2.z + e3.z; a2.w = q2 * e1.w + q1 * e2.w + e3.w;
    q1 = v1[rc3]; q2 = v2[rc3];
    a3.x = q2 * e1.x + q1 * e2.x + e3.x; a3.y = q2 * e1.y + q1 * e2.y + e3.y;
    a3.z = q2 * e1.z + q1 * e2.z + e3.z; a3.w = q2 * e1.w + q1 * e2.w + e3.w;
  }

#pragma unroll 4
  for (int k4 = 0; k4 < DM; k4 += 4) {
    float4 xv0 = *reinterpret_cast<const float4*>(&x0[k4]);
    float4 xv1 = *reinterpret_cast<const float4*>(&x1[k4]);
    float4 xv2 = *reinterpret_cast<const float4*>(&x2[k4]);
    float4 xv3 = *reinterpret_cast<const float4*>(&x3[k4]);
    float4 w0 = *reinterpret_cast<const float4*>(&Wl[(k4 + 0) * 64 + jc]);
    float4 w1 = *reinterpret_cast<const float4*>(&Wl[(k4 + 1) * 64 + jc]);
    float4 w2 = *reinterpret_cast<const float4*>(&Wl[(k4 + 2) * 64 + jc]);
    float4 w3 = *reinterpret_cast<const float4*>(&Wl[(k4 + 3) * 64 + jc]);
    FMA4(a0, xv0.x, w0) FMA4(a0, xv0.y, w1) FMA4(a0, xv0.z, w2) FMA4(a0, xv0.w, w3)
    FMA4(a1, xv1.x, w0) FMA4(a1, xv1.y, w1) FMA4(a1, xv1.z, w2) FMA4(a1, xv1.w, w3)
    FMA4(a2, xv2.x, w0) FMA4(a2, xv2.y, w1) FMA4(a2, xv2.z, w2) FMA4(a2, xv2.w, w3)
    FMA4(a3, xv3.x, w0) FMA4(a3, xv3.y, w1) FMA4(a3, xv3.z, w2) FMA4(a3, xv3.w, w3)
  }

  float* o = out + (size_t)r0 * DM + jbase + jc;
  if (r0 + 3 < NN) {
    *reinterpret_cast<float4*>(o)          = a0;
    *reinterpret_cast<float4*>(o + DM)     = a1;
    *reinterpret_cast<float4*>(o + 2 * DM) = a2;
    *reinterpret_cast<float4*>(o + 3 * DM) = a3;
  } else {
    if (r0 + 0 < NN) *reinterpret_cast<float4*>(o)          = a0;
    if (r0 + 1 < NN) *reinterpret_cast<float4*>(o + DM)     = a1;
    if (r0 + 2 < NN) *reinterpret_cast<float4*>(o + 2 * DM) = a2;
  }
}

extern "C" void kernel_launch(void* const* d_in, const int* in_sizes, int n_in,
                              void* d_out, int out_size, void* d_ws, size_t ws_size,
                              hipStream_t stream) {
  const float* in_feat = (const float*)d_in[0];
  const int*   ei      = (const int*)d_in[1];
  const float* Ws      = (const float*)d_in[2];
  const float* bs      = (const float*)d_in[3];
  float* out = (float*)d_out;

  const int* src = ei;
  const int* dst = ei + NE;
  const float* W1 = Ws;
  const float* W2 = Ws + DM * DM;
  const float* W3 = Ws + 2 * DM * DM;
  const float* b1 = bs;
  const float* b2 = bs + DM;
  const float* b3 = bs + 2 * DM;

  char* w = (char*)d_ws;
  int* cnt8   = (int*)w;            w += (size_t)16 * NN * sizeof(int);  // 8 copies x (co,ci)
  int* co     = (int*)w;            w += NN * sizeof(int);
  int* ci     = (int*)w;            w += NN * sizeof(int);
  int* rowptr = (int*)w;            w += (NN + 1) * sizeof(int);
  int* cursor = (int*)w;            w += NN * sizeof(int);
  int* bsum   = (int*)w;            w += NB * sizeof(int);
  int* boff   = (int*)w;            w += NB * sizeof(int);
  int* col    = (int*)w;            w += NE * sizeof(int);
  float* onorm = (float*)w;         w += NN * sizeof(float);
  float* inorm = (float*)w;         w += NN * sizeof(float);
  float* v1    = (float*)w;         w += NN * sizeof(float);
  float* v2    = (float*)w;         w += NN * sizeof(float);
  float* W23   = (float*)w;         w += DM * DM * sizeof(float);
  float* W123  = (float*)w;         w += DM * DM * sizeof(float);
  float* c1    = (float*)w;         w += DM * sizeof(float);
  float* c2    = (float*)w;         w += DM * sizeof(float);
  float* bufA  = (float*)w;         w += (size_t)NN * DM * sizeof(float);
  float* bufB  = (float*)w;

  // graph preprocessing
  hipMemsetAsync(cnt8, 0, (size_t)16 * NN * sizeof(int), stream);
  k_count<<<(NE / 4 + 255) / 256, 256, 0, stream>>>(src, dst, cnt8);
  k_scan_part<<<NB, 256, 0, stream>>>(cnt8, co, ci, bsum);
  k_scan_mid<<<1, 256, 0, stream>>>(bsum, boff, rowptr);
  k_scan_out<<<NB, 256, 0, stream>>>(ci, co, boff, rowptr, cursor, onorm, inorm);
  k_fill<<<(NE / 4 + 255) / 256, 256, 0, stream>>>(src, dst, cursor, col);

  // g3 = M^3 h; v1 = M·1 rides gather1, v2 = M·v1 rides gather2;
  // W23 = W2 W3 rides gather1; W123 = W1 W23, c1 = b1 W23, c2 = b2 W3 ride gather2.
  k_gather_t<1, 1><<<NGB + 64, 256, 0, stream>>>(in_feat, rowptr, col, onorm, inorm,
                                                 nullptr, bufA, v1,
                                                 W2, W3, W23,
                                                 nullptr, nullptr, nullptr,
                                                 nullptr, nullptr, nullptr);
  k_gather_t<2, 2><<<NGB + 65, 256, 0, stream>>>(bufA, rowptr, col, onorm, inorm,
                                                 v1, bufB, v2,
                                                 W1, W23, W123,
                                                 b1, W23, c1, b2, W3, c2);
  k_gather_t<0, 0><<<NGB, 256, 0, stream>>>(bufB, rowptr, col, onorm, inorm,
                                            nullptr, bufA, nullptr,
                                            nullptr, nullptr, nullptr,
                                            nullptr, nullptr, nullptr,
                                            nullptr, nullptr, nullptr);

  // out = g3 @ W123 + v2 c1^T + v1 c2^T + 1 b3^T
  k_gemm_f<<<1564, 256, 0, stream>>>(bufA, W123, c1, c2, b3, v1, v2, out);
}

// Round 13
// 314.912 us; speedup vs baseline: 5.6251x; 1.1343x over previous
//
#include <hip/hip_runtime.h>

// GCN: 3 layers GraphConv (norm='both'), N=50000, E=800000, D=128.
// Round 13: degree counting WITHOUT global atomics (round-12 null result:
// device atomics resolve at a shared memory-side point, privatization no-op).
// k_hist: 4 node-chunks x 50KB LDS histograms x 32 edge-slice copies,
// non-atomic global flush; k_scan_part sums the copies. Memset deleted.
//   out = (M^3 h) W123 + v2 c1^T + v1 c2^T + 1 b3^T,  v1=M·1, v2=M·v1.

#define NN 50000
#define NE 800000
#define DM 128
#define NB 196     // ceil(NN/256) scan blocks
#define NGB 12500  // gather blocks (NN*64/256)
#define CHN 12500  // nodes per histogram chunk (50KB LDS)
#define NCOP 32    // edge-slice copies per (array, chunk)

#define FMA4(av, sv, wv) \
  av.x += (sv) * (wv).x; av.y += (sv) * (wv).y; av.z += (sv) * (wv).z; av.w += (sv) * (wv).w;

// grid 256: b = arr*128 + chunk*32 + copy. LDS histogram of its node chunk
// over its edge slice; non-atomic flush to hcop[b*CHN ..].
__global__ void k_hist(const int* __restrict__ src, const int* __restrict__ dst,
                       int* __restrict__ hcop) {
  __shared__ int h[CHN];
  int b = blockIdx.x;
  int arr   = b >> 7;
  int chunk = (b >> 5) & 3;
  int copy  = b & 31;
  const int* idx = arr ? dst : src;
  int lo = chunk * CHN;
  for (int i = threadIdx.x; i < CHN; i += 256) h[i] = 0;
  __syncthreads();
  const int4* e4 = reinterpret_cast<const int4*>(idx) + copy * (NE / 4 / NCOP);
  for (int i = threadIdx.x; i < NE / 4 / NCOP; i += 256) {
    int4 v = e4[i];
    unsigned a;
    a = (unsigned)(v.x - lo); if (a < (unsigned)CHN) atomicAdd(&h[a], 1);
    a = (unsigned)(v.y - lo); if (a < (unsigned)CHN) atomicAdd(&h[a], 1);
    a = (unsigned)(v.z - lo); if (a < (unsigned)CHN) atomicAdd(&h[a], 1);
    a = (unsigned)(v.w - lo); if (a < (unsigned)CHN) atomicAdd(&h[a], 1);
  }
  __syncthreads();
  int* o = hcop + (size_t)b * CHN;
  for (int i = threadIdx.x; i < CHN; i += 256) o[i] = h[i];
}

// ---- scan stage 1: reduce 32 copies -> co/ci, block sums of ci ----
__global__ void k_scan_part(const int* __restrict__ hcop, int* __restrict__ co,
                            int* __restrict__ ci, int* __restrict__ bsum) {
  __shared__ int s[256];
  int i = blockIdx.x * 256 + threadIdx.x;
  int sco = 0, sci = 0;
  if (i < NN) {
    int ch = i / CHN;
    int loc = i - ch * CHN;
    const int* pco = hcop + (size_t)(ch * 32) * CHN + loc;
    const int* pci = hcop + (size_t)(128 + ch * 32) * CHN + loc;
#pragma unroll
    for (int p = 0; p < NCOP; ++p) {
      sco += pco[(size_t)p * CHN];
      sci += pci[(size_t)p * CHN];
    }
    co[i] = sco;
    ci[i] = sci;
  }
  s[threadIdx.x] = sci;
  __syncthreads();
  for (int off = 128; off > 0; off >>= 1) {
    if (threadIdx.x < off) s[threadIdx.x] += s[threadIdx.x + off];
    __syncthreads();
  }
  if (threadIdx.x == 0) bsum[blockIdx.x] = s[0];
}

__global__ void k_scan_mid(const int* __restrict__ bsum, int* __restrict__ boff,
                           int* __restrict__ rowptr) {
  __shared__ int s[256];
  int t = threadIdx.x;
  int v = (t < NB) ? bsum[t] : 0;
  s[t] = v;
  __syncthreads();
  for (int off = 1; off < 256; off <<= 1) {
    int u = (t >= off) ? s[t - off] : 0;
    __syncthreads();
    s[t] += u;
    __syncthreads();
  }
  if (t < NB) boff[t] = s[t] - v;  // exclusive
  if (t == 0) rowptr[NN] = NE;
}

__global__ void k_scan_out(const int* __restrict__ ci, const int* __restrict__ co,
                           const int* __restrict__ boff, int* __restrict__ rowptr,
                           int* __restrict__ cursor, float* __restrict__ onorm,
                           float* __restrict__ inorm) {
  __shared__ int s[256];
  int t = threadIdx.x;
  int i = blockIdx.x * 256 + t;
  int v = (i < NN) ? ci[i] : 0;
  s[t] = v;
  __syncthreads();
  for (int off = 1; off < 256; off <<= 1) {
    int u = (t >= off) ? s[t - off] : 0;
    __syncthreads();
    s[t] += u;
    __syncthreads();
  }
  if (i < NN) {
    int ex = boff[blockIdx.x] + s[t] - v;
    rowptr[i] = ex;
    cursor[i] = ex;
    onorm[i] = rsqrtf(fmaxf((float)co[i], 1.0f));
    inorm[i] = rsqrtf(fmaxf((float)v, 1.0f));
  }
}

__global__ void k_fill(const int* __restrict__ src, const int* __restrict__ dst,
                       int* __restrict__ cursor, int* __restrict__ col) {
  int t = blockIdx.x * blockDim.x + threadIdx.x;
  if (t < NE / 4) {
    int4 s4 = reinterpret_cast<const int4*>(src)[t];
    int4 d4 = reinterpret_cast<const int4*>(dst)[t];
    int p;
    p = atomicAdd(&cursor[d4.x], 1); col[p] = s4.x;
    p = atomicAdd(&cursor[d4.y], 1); col[p] = s4.y;
    p = atomicAdd(&cursor[d4.z], 1); col[p] = s4.z;
    p = atomicAdd(&cursor[d4.w], 1); col[p] = s4.w;
  }
}

// ---- feature gather: Y = M X. One 64-lane wave per node; halves take
// even/odd edges (unroll 2/half); shfl-xor(32) reduce.
// VMODE 0: features only. 1: also vout = M·1. 2: also vout = M·vin.
// EXTRA>=1: blocks beyond NGB compute mC = mA @ mB (64 blocks, 2 rows each).
// EXTRA==2: block NGB+64 computes vc1 = vb1 @ vB1, vc2 = vb2 @ vB2.
template <int VMODE, int EXTRA>
__global__ void k_gather_t(const float* __restrict__ h, const int* __restrict__ rowptr,
                           const int* __restrict__ col, const float* __restrict__ onorm,
                           const float* __restrict__ inorm, const float* __restrict__ vin,
                           float* __restrict__ agg, float* __restrict__ vout,
                           const float* __restrict__ mA, const float* __restrict__ mB,
                           float* __restrict__ mC,
                           const float* __restrict__ vb1, const float* __restrict__ vB1,
                           float* __restrict__ vc1,
                           const float* __restrict__ vb2, const float* __restrict__ vB2,
                           float* __restrict__ vc2) {
  if (EXTRA) {
    int eb = (int)blockIdx.x - NGB;
    if (eb >= 0) {
      if (eb < 64) {            // mC = mA @ mB, rows 2eb, 2eb+1
        int i0 = eb * 2 + (threadIdx.x >> 7);
        int j = threadIdx.x & 127;
        float acc = 0.f;
        for (int k = 0; k < DM; ++k) acc += mA[i0 * DM + k] * mB[k * DM + j];
        mC[i0 * DM + j] = acc;
      } else if (EXTRA == 2) {  // vc1 = vb1@vB1 (tid<128), vc2 = vb2@vB2
        int t = threadIdx.x;
        if (t < DM) {
          float acc = 0.f;
          for (int k = 0; k < DM; ++k) acc += vb1[k] * vB1[k * DM + t];
          vc1[t] = acc;
        } else {
          int j = t - DM;
          float acc = 0.f;
          for (int k = 0; k < DM; ++k) acc += vb2[k] * vB2[k * DM + j];
          vc2[j] = acc;
        }
      }
      return;
    }
  }
  int tid = blockIdx.x * blockDim.x + threadIdx.x;
  int n = tid >> 6;
  if (n >= NN) return;
  int lane = threadIdx.x & 63;
  int half = lane >> 5;
  int l32 = lane & 31;
  int beg = rowptr[n], end = rowptr[n + 1];
  const float4* h4 = reinterpret_cast<const float4*>(h);
  float4 a0 = make_float4(0.f, 0.f, 0.f, 0.f);
  float4 a1 = make_float4(0.f, 0.f, 0.f, 0.f);
  float av = 0.f;
  int e = beg + half;
  for (; e + 2 < end; e += 4) {
    int s0 = col[e], s1 = col[e + 2];
    float n0 = onorm[s0], n1 = onorm[s1];
    float4 v0 = h4[(size_t)s0 * 32 + l32];
    float4 v1 = h4[(size_t)s1 * 32 + l32];
    if (VMODE == 1) av += n0 + n1;
    if (VMODE == 2) av += n0 * vin[s0] + n1 * vin[s1];
    FMA4(a0, n0, v0)
    FMA4(a1, n1, v1)
  }
  if (e < end) {
    int s0 = col[e];
    float n0 = onorm[s0];
    float4 v0 = h4[(size_t)s0 * 32 + l32];
    if (VMODE == 1) av += n0;
    if (VMODE == 2) av += n0 * vin[s0];
    FMA4(a0, n0, v0)
  }
  a0.x += a1.x; a0.y += a1.y; a0.z += a1.z; a0.w += a1.w;
  a0.x += __shfl_xor(a0.x, 32);
  a0.y += __shfl_xor(a0.y, 32);
  a0.z += __shfl_xor(a0.z, 32);
  a0.w += __shfl_xor(a0.w, 32);
  if (VMODE) av += __shfl_xor(av, 32);
  if (half == 0) {
    float sc = inorm[n];
    reinterpret_cast<float4*>(agg)[n * 32 + l32] =
        make_float4(a0.x * sc, a0.y * sc, a0.z * sc, a0.w * sc);
    if (VMODE && l32 == 0) vout[n] = av * sc;
  }
}

// ---- final GEMM: out = x @ W + v2*c1^T + v1*c2^T + 1*c3^T ----
// Split-j 64-col halves (32KB W tile). Block 256 = 16 row-slots x 16 lanes;
// thread = 4 rows x 4 cols; 64 rows per block, single pass. All LDS reads
// b128 and wave-broadcast: 8 FMA per ds_read_b128.
__launch_bounds__(256, 2)
__global__ void k_gemm_f(const float* __restrict__ x, const float* __restrict__ W,
                         const float* __restrict__ c1, const float* __restrict__ c2,
                         const float* __restrict__ c3, const float* __restrict__ v1,
                         const float* __restrict__ v2, float* __restrict__ out) {
  __shared__ float Wl[DM * 64];     // 32 KB
  __shared__ float xs[64 * 132];    // 33.8 KB

  int jhalf = blockIdx.x & 1;
  int grp   = blockIdx.x >> 1;      // 0..781
  int jbase = jhalf * 64;
  int rbase = grp * 64;

  {
    const float4* W4 = reinterpret_cast<const float4*>(W);
    float4* Wl4 = reinterpret_cast<float4*>(Wl);
    for (int i = threadIdx.x; i < DM * 16; i += 256) {
      int k = i >> 4, j4 = i & 15;
      Wl4[k * 16 + j4] = W4[k * 32 + jhalf * 16 + j4];
    }
    const float4* xg = reinterpret_cast<const float4*>(x) + (size_t)rbase * 32;
    float4* xs4 = reinterpret_cast<float4*>(xs);
    int lim = (NN - rbase) * 32;
    for (int i = threadIdx.x; i < 2048; i += 256) {
      int r = i >> 5, seg = i & 31;
      float4 v = (i < lim) ? xg[i] : make_float4(0.f, 0.f, 0.f, 0.f);
      xs4[r * 33 + seg] = v;
    }
  }
  __syncthreads();

  int slot = threadIdx.x >> 4;      // 0..15 -> 4 rows each
  int lane = threadIdx.x & 15;      // 0..15 -> 4 cols each
  int jc = lane * 4;
  float4 e1 = *reinterpret_cast<const float4*>(&c1[jbase + jc]);
  float4 e2 = *reinterpret_cast<const float4*>(&c2[jbase + jc]);
  float4 e3 = *reinterpret_cast<const float4*>(&c3[jbase + jc]);

  int r0 = rbase + slot * 4;
  int rc0 = (r0 < NN) ? r0 : NN - 1;
  int rc1 = (r0 + 1 < NN) ? r0 + 1 : NN - 1;
  int rc2 = (r0 + 2 < NN) ? r0 + 2 : NN - 1;
  int rc3 = (r0 + 3 < NN) ? r0 + 3 : NN - 1;
  const float* x0 = &xs[(slot * 4 + 0) * 132];
  const float* x1 = &xs[(slot * 4 + 1) * 132];
  const float* x2 = &xs[(slot * 4 + 2) * 132];
  const float* x3 = &xs[(slot * 4 + 3) * 132];

  float4 a0, a1, a2, a3;
  {
    float q1, q2;
    q1 = v1[rc0]; q2 = v2[rc0];
    a0.x = q2 * e1.x + q1 * e2.x + e3.x; a0.y = q2 * e1.y + q1 * e2.y + e3.y;
    a0.z = q2 * e1.z + q1 * e2.z + e3.z; a0.w = q2 * e1.w + q1 * e2.w + e3.w;
    q1 = v1[rc1]; q2 = v2[rc1];
    a1.x = q2 * e1.x + q1 * e2.x + e3.x; a1.y = q2 * e1.y + q1 * e2.y + e3.y;
    a1.z = q2 * e1.z + q1 * e2.z + e3.z; a1.w = q2 * e1.w + q1 * e2.w + e3.w;
    q1 = v1[rc2]; q2 = v2[rc2];
    a2.x = q2 * e1.x + q1 * e2.x + e3.x; a2.y = q2 * e1.y + q1 * e2.y + e3.y;
    a2.z = q2 * e1.z + q1 * e2.z + e3.z; a2.w = q2 * e1.w + q1 * e2.w + e3.w;
    q1 = v1[rc3]; q2 = v2[rc3];
    a3.x = q2 * e1.x + q1 * e2.x + e3.x; a3.y = q2 * e1.y + q1 * e2.y + e3.y;
    a3.z = q2 * e1.z + q1 * e2.z + e3.z; a3.w = q2 * e1.w + q1 * e2.w + e3.w;
  }

#pragma unroll 4
  for (int k4 = 0; k4 < DM; k4 += 4) {
    float4 xv0 = *reinterpret_cast<const float4*>(&x0[k4]);
    float4 xv1 = *reinterpret_cast<const float4*>(&x1[k4]);
    float4 xv2 = *reinterpret_cast<const float4*>(&x2[k4]);
    float4 xv3 = *reinterpret_cast<const float4*>(&x3[k4]);
    float4 w0 = *reinterpret_cast<const float4*>(&Wl[(k4 + 0) * 64 + jc]);
    float4 w1 = *reinterpret_cast<const float4*>(&Wl[(k4 + 1) * 64 + jc]);
    float4 w2 = *reinterpret_cast<const float4*>(&Wl[(k4 + 2) * 64 + jc]);
    float4 w3 = *reinterpret_cast<const float4*>(&Wl[(k4 + 3) * 64 + jc]);
    FMA4(a0, xv0.x, w0) FMA4(a0, xv0.y, w1) FMA4(a0, xv0.z, w2) FMA4(a0, xv0.w, w3)
    FMA4(a1, xv1.x, w0) FMA4(a1, xv1.y, w1) FMA4(a1, xv1.z, w2) FMA4(a1, xv1.w, w3)
    FMA4(a2, xv2.x, w0) FMA4(a2, xv2.y, w1) FMA4(a2, xv2.z, w2) FMA4(a2, xv2.w, w3)
    FMA4(a3, xv3.x, w0) FMA4(a3, xv3.y, w1) FMA4(a3, xv3.z, w2) FMA4(a3, xv3.w, w3)
  }

  float* o = out + (size_t)r0 * DM + jbase + jc;
  if (r0 + 3 < NN) {
    *reinterpret_cast<float4*>(o)          = a0;
    *reinterpret_cast<float4*>(o + DM)     = a1;
    *reinterpret_cast<float4*>(o + 2 * DM) = a2;
    *reinterpret_cast<float4*>(o + 3 * DM) = a3;
  } else {
    if (r0 + 0 < NN) *reinterpret_cast<float4*>(o)          = a0;
    if (r0 + 1 < NN) *reinterpret_cast<float4*>(o + DM)     = a1;
    if (r0 + 2 < NN) *reinterpret_cast<float4*>(o + 2 * DM) = a2;
  }
}

extern "C" void kernel_launch(void* const* d_in, const int* in_sizes, int n_in,
                              void* d_out, int out_size, void* d_ws, size_t ws_size,
                              hipStream_t stream) {
  const float* in_feat = (const float*)d_in[0];
  const int*   ei      = (const int*)d_in[1];
  const float* Ws      = (const float*)d_in[2];
  const float* bs      = (const float*)d_in[3];
  float* out = (float*)d_out;

  const int* src = ei;
  const int* dst = ei + NE;
  const float* W1 = Ws;
  const float* W2 = Ws + DM * DM;
  const float* W3 = Ws + 2 * DM * DM;
  const float* b1 = bs;
  const float* b2 = bs + DM;
  const float* b3 = bs + 2 * DM;

  char* w = (char*)d_ws;
  int* hcop   = (int*)w;            w += (size_t)256 * CHN * sizeof(int);  // 12.8MB
  int* co     = (int*)w;            w += NN * sizeof(int);
  int* ci     = (int*)w;            w += NN * sizeof(int);
  int* rowptr = (int*)w;            w += (NN + 1) * sizeof(int);
  int* cursor = (int*)w;            w += NN * sizeof(int);
  int* bsum   = (int*)w;            w += NB * sizeof(int);
  int* boff   = (int*)w;            w += NB * sizeof(int);
  int* col    = (int*)w;            w += NE * sizeof(int);
  float* onorm = (float*)w;         w += NN * sizeof(float);
  float* inorm = (float*)w;         w += NN * sizeof(float);
  float* v1    = (float*)w;         w += NN * sizeof(float);
  float* v2    = (float*)w;         w += NN * sizeof(float);
  float* W23   = (float*)w;         w += DM * DM * sizeof(float);
  float* W123  = (float*)w;         w += DM * DM * sizeof(float);
  float* c1    = (float*)w;         w += DM * sizeof(float);
  float* c2    = (float*)w;         w += DM * sizeof(float);
  float* bufA  = (float*)w;         w += (size_t)NN * DM * sizeof(float);
  float* bufB  = (float*)w;

  // graph preprocessing (no global atomics in counting; no memset needed)
  k_hist<<<256, 256, 0, stream>>>(src, dst, hcop);
  k_scan_part<<<NB, 256, 0, stream>>>(hcop, co, ci, bsum);
  k_scan_mid<<<1, 256, 0, stream>>>(bsum, boff, rowptr);
  k_scan_out<<<NB, 256, 0, stream>>>(ci, co, boff, rowptr, cursor, onorm, inorm);
  k_fill<<<(NE / 4 + 255) / 256, 256, 0, stream>>>(src, dst, cursor, col);

  // g3 = M^3 h; v1 = M·1 rides gather1, v2 = M·v1 rides gather2;
  // W23 = W2 W3 rides gather1; W123 = W1 W23, c1 = b1 W23, c2 = b2 W3 ride gather2.
  k_gather_t<1, 1><<<NGB + 64, 256, 0, stream>>>(in_feat, rowptr, col, onorm, inorm,
                                                 nullptr, bufA, v1,
                                                 W2, W3, W23,
                                                 nullptr, nullptr, nullptr,
                                                 nullptr, nullptr, nullptr);
  k_gather_t<2, 2><<<NGB + 65, 256, 0, stream>>>(bufA, rowptr, col, onorm, inorm,
                                                 v1, bufB, v2,
                                                 W1, W23, W123,
                                                 b1, W23, c1, b2, W3, c2);
  k_gather_t<0, 0><<<NGB, 256, 0, stream>>>(bufB, rowptr, col, onorm, inorm,
                                            nullptr, bufA, nullptr,
                                            nullptr, nullptr, nullptr,
                                            nullptr, nullptr, nullptr,
                                            nullptr, nullptr, nullptr);

  // out = g3 @ W123 + v2 c1^T + v1 c2^T + 1 b3^T
  k_gemm_f<<<1564, 256, 0, stream>>>(bufA, W123, c1, c2, b3, v1, v2, out);
}

// Round 14
// 257.229 us; speedup vs baseline: 6.8866x; 1.2243x over previous
//
#include <hip/hip_runtime.h>

// GCN: 3 layers GraphConv (norm='both'), N=50000, E=800000, D=128.
// Round 14: bf16 feature storage for gather inputs (halves the compulsory
// random-row fetch: 512B -> 256B rows). Accumulation stays f32; g3 written
// f32 for the GEMM. in_feat->bf16 conversion rides on k_fill's grid.
//   out = (M^3 h) W123 + v2 c1^T + v1 c2^T + 1 b3^T,  v1=M·1, v2=M·v1.

#define NN 50000
#define NE 800000
#define DM 128
#define NB 196     // ceil(NN/256) scan blocks
#define NGB 12500  // gather blocks (NN*64/256)
#define CHN 12500  // nodes per histogram chunk (50KB LDS)
#define NCOP 32    // edge-slice copies per (array, chunk)
#define NFB 782    // fill blocks (ceil(NE/4/256)); conversion rider doubles it

typedef unsigned short u16;

#define FMA4(av, sv, wv) \
  av.x += (sv) * (wv).x; av.y += (sv) * (wv).y; av.z += (sv) * (wv).z; av.w += (sv) * (wv).w;

__device__ __forceinline__ float bf2f(u16 u) {
  return __uint_as_float((unsigned)u << 16);
}
__device__ __forceinline__ u16 f2bf(float f) {
  unsigned x = __float_as_uint(f);
  return (u16)((x + 0x7fffu + ((x >> 16) & 1u)) >> 16);  // RNE, finite inputs
}

// grid 256: b = arr*128 + chunk*32 + copy. LDS histogram of its node chunk
// over its edge slice; non-atomic flush to hcop[b*CHN ..].
__global__ void k_hist(const int* __restrict__ src, const int* __restrict__ dst,
                       int* __restrict__ hcop) {
  __shared__ int h[CHN];
  int b = blockIdx.x;
  int arr   = b >> 7;
  int chunk = (b >> 5) & 3;
  int copy  = b & 31;
  const int* idx = arr ? dst : src;
  int lo = chunk * CHN;
  for (int i = threadIdx.x; i < CHN; i += 256) h[i] = 0;
  __syncthreads();
  const int4* e4 = reinterpret_cast<const int4*>(idx) + copy * (NE / 4 / NCOP);
  for (int i = threadIdx.x; i < NE / 4 / NCOP; i += 256) {
    int4 v = e4[i];
    unsigned a;
    a = (unsigned)(v.x - lo); if (a < (unsigned)CHN) atomicAdd(&h[a], 1);
    a = (unsigned)(v.y - lo); if (a < (unsigned)CHN) atomicAdd(&h[a], 1);
    a = (unsigned)(v.z - lo); if (a < (unsigned)CHN) atomicAdd(&h[a], 1);
    a = (unsigned)(v.w - lo); if (a < (unsigned)CHN) atomicAdd(&h[a], 1);
  }
  __syncthreads();
  int* o = hcop + (size_t)b * CHN;
  for (int i = threadIdx.x; i < CHN; i += 256) o[i] = h[i];
}

// ---- scan stage 1: reduce 32 copies -> co/ci, block sums of ci ----
__global__ void k_scan_part(const int* __restrict__ hcop, int* __restrict__ co,
                            int* __restrict__ ci, int* __restrict__ bsum) {
  __shared__ int s[256];
  int i = blockIdx.x * 256 + threadIdx.x;
  int sco = 0, sci = 0;
  if (i < NN) {
    int ch = i / CHN;
    int loc = i - ch * CHN;
    const int* pco = hcop + (size_t)(ch * 32) * CHN + loc;
    const int* pci = hcop + (size_t)(128 + ch * 32) * CHN + loc;
#pragma unroll
    for (int p = 0; p < NCOP; ++p) {
      sco += pco[(size_t)p * CHN];
      sci += pci[(size_t)p * CHN];
    }
    co[i] = sco;
    ci[i] = sci;
  }
  s[threadIdx.x] = sci;
  __syncthreads();
  for (int off = 128; off > 0; off >>= 1) {
    if (threadIdx.x < off) s[threadIdx.x] += s[threadIdx.x + off];
    __syncthreads();
  }
  if (threadIdx.x == 0) bsum[blockIdx.x] = s[0];
}

__global__ void k_scan_mid(const int* __restrict__ bsum, int* __restrict__ boff,
                           int* __restrict__ rowptr) {
  __shared__ int s[256];
  int t = threadIdx.x;
  int v = (t < NB) ? bsum[t] : 0;
  s[t] = v;
  __syncthreads();
  for (int off = 1; off < 256; off <<= 1) {
    int u = (t >= off) ? s[t - off] : 0;
    __syncthreads();
    s[t] += u;
    __syncthreads();
  }
  if (t < NB) boff[t] = s[t] - v;  // exclusive
  if (t == 0) rowptr[NN] = NE;
}

__global__ void k_scan_out(const int* __restrict__ ci, const int* __restrict__ co,
                           const int* __restrict__ boff, int* __restrict__ rowptr,
                           int* __restrict__ cursor, float* __restrict__ onorm,
                           float* __restrict__ inorm) {
  __shared__ int s[256];
  int t = threadIdx.x;
  int i = blockIdx.x * 256 + t;
  int v = (i < NN) ? ci[i] : 0;
  s[t] = v;
  __syncthreads();
  for (int off = 1; off < 256; off <<= 1) {
    int u = (t >= off) ? s[t - off] : 0;
    __syncthreads();
    s[t] += u;
    __syncthreads();
  }
  if (i < NN) {
    int ex = boff[blockIdx.x] + s[t] - v;
    rowptr[i] = ex;
    cursor[i] = ex;
    onorm[i] = rsqrtf(fmaxf((float)co[i], 1.0f));
    inorm[i] = rsqrtf(fmaxf((float)v, 1.0f));
  }
}

// blocks < NFB: CSR column fill. blocks >= NFB: in_feat f32 -> bf16 rider.
__global__ void k_fill(const int* __restrict__ src, const int* __restrict__ dst,
                       int* __restrict__ cursor, int* __restrict__ col,
                       const float* __restrict__ feat, u16* __restrict__ featb) {
  int b = blockIdx.x;
  if (b >= NFB) {
    size_t base = ((size_t)(b - NFB) * 256 + threadIdx.x) * 8;
    const size_t stride = (size_t)NFB * 256 * 8;
#pragma unroll
    for (int it = 0; it < 4; ++it, base += stride) {
      if (base < (size_t)NN * DM) {
        float4 f0 = *reinterpret_cast<const float4*>(feat + base);
        float4 f1 = *reinterpret_cast<const float4*>(feat + base + 4);
        ushort4 u0 = make_ushort4(f2bf(f0.x), f2bf(f0.y), f2bf(f0.z), f2bf(f0.w));
        ushort4 u1 = make_ushort4(f2bf(f1.x), f2bf(f1.y), f2bf(f1.z), f2bf(f1.w));
        *reinterpret_cast<ushort4*>(featb + base) = u0;
        *reinterpret_cast<ushort4*>(featb + base + 4) = u1;
      }
    }
    return;
  }
  int t = b * 256 + threadIdx.x;
  if (t < NE / 4) {
    int4 s4 = reinterpret_cast<const int4*>(src)[t];
    int4 d4 = reinterpret_cast<const int4*>(dst)[t];
    int p;
    p = atomicAdd(&cursor[d4.x], 1); col[p] = s4.x;
    p = atomicAdd(&cursor[d4.y], 1); col[p] = s4.y;
    p = atomicAdd(&cursor[d4.z], 1); col[p] = s4.z;
    p = atomicAdd(&cursor[d4.w], 1); col[p] = s4.w;
  }
}

// ---- feature gather: Y = M X with bf16 X. One wave per node; halves take
// even/odd edges (unroll 2/half); f32 accumulate; shfl-xor(32) reduce.
// OUTBF: write bf16 (passes 1,2) or f32 (pass 3, GEMM input).
// VMODE 0: features only. 1: also vout = M·1. 2: also vout = M·vin.
// EXTRA>=1: blocks beyond NGB compute mC = mA @ mB (64 blocks, 2 rows each).
// EXTRA==2: block NGB+64 computes vc1 = vb1 @ vB1, vc2 = vb2 @ vB2.
template <int VMODE, int EXTRA, int OUTBF>
__global__ void k_gather_t(const u16* __restrict__ h, const int* __restrict__ rowptr,
                           const int* __restrict__ col, const float* __restrict__ onorm,
                           const float* __restrict__ inorm, const float* __restrict__ vin,
                           u16* __restrict__ aggb, float* __restrict__ aggf,
                           float* __restrict__ vout,
                           const float* __restrict__ mA, const float* __restrict__ mB,
                           float* __restrict__ mC,
                           const float* __restrict__ vb1, const float* __restrict__ vB1,
                           float* __restrict__ vc1,
                           const float* __restrict__ vb2, const float* __restrict__ vB2,
                           float* __restrict__ vc2) {
  if (EXTRA) {
    int eb = (int)blockIdx.x - NGB;
    if (eb >= 0) {
      if (eb < 64) {            // mC = mA @ mB, rows 2eb, 2eb+1
        int i0 = eb * 2 + (threadIdx.x >> 7);
        int j = threadIdx.x & 127;
        float acc = 0.f;
        for (int k = 0; k < DM; ++k) acc += mA[i0 * DM + k] * mB[k * DM + j];
        mC[i0 * DM + j] = acc;
      } else if (EXTRA == 2) {  // vc1 = vb1@vB1 (tid<128), vc2 = vb2@vB2
        int t = threadIdx.x;
        if (t < DM) {
          float acc = 0.f;
          for (int k = 0; k < DM; ++k) acc += vb1[k] * vB1[k * DM + t];
          vc1[t] = acc;
        } else {
          int j = t - DM;
          float acc = 0.f;
          for (int k = 0; k < DM; ++k) acc += vb2[k] * vB2[k * DM + j];
          vc2[j] = acc;
        }
      }
      return;
    }
  }
  int tid = blockIdx.x * blockDim.x + threadIdx.x;
  int n = tid >> 6;
  if (n >= NN) return;
  int lane = threadIdx.x & 63;
  int half = lane >> 5;
  int l32 = lane & 31;
  int beg = rowptr[n], end = rowptr[n + 1];
  const ushort4* h4 = reinterpret_cast<const ushort4*>(h);  // 4 bf16 per elem
  float4 a0 = make_float4(0.f, 0.f, 0.f, 0.f);
  float4 a1 = make_float4(0.f, 0.f, 0.f, 0.f);
  float av = 0.f;
  int e = beg + half;
  for (; e + 2 < end; e += 4) {
    int s0 = col[e], s1 = col[e + 2];
    float n0 = onorm[s0], n1 = onorm[s1];
    ushort4 u0 = h4[(size_t)s0 * 32 + l32];
    ushort4 u1 = h4[(size_t)s1 * 32 + l32];
    float4 v0 = make_float4(bf2f(u0.x), bf2f(u0.y), bf2f(u0.z), bf2f(u0.w));
    float4 v1 = make_float4(bf2f(u1.x), bf2f(u1.y), bf2f(u1.z), bf2f(u1.w));
    if (VMODE == 1) av += n0 + n1;
    if (VMODE == 2) av += n0 * vin[s0] + n1 * vin[s1];
    FMA4(a0, n0, v0)
    FMA4(a1, n1, v1)
  }
  if (e < end) {
    int s0 = col[e];
    float n0 = onorm[s0];
    ushort4 u0 = h4[(size_t)s0 * 32 + l32];
    float4 v0 = make_float4(bf2f(u0.x), bf2f(u0.y), bf2f(u0.z), bf2f(u0.w));
    if (VMODE == 1) av += n0;
    if (VMODE == 2) av += n0 * vin[s0];
    FMA4(a0, n0, v0)
  }
  a0.x += a1.x; a0.y += a1.y; a0.z += a1.z; a0.w += a1.w;
  a0.x += __shfl_xor(a0.x, 32);
  a0.y += __shfl_xor(a0.y, 32);
  a0.z += __shfl_xor(a0.z, 32);
  a0.w += __shfl_xor(a0.w, 32);
  if (VMODE) av += __shfl_xor(av, 32);
  if (half == 0) {
    float sc = inorm[n];
    float4 o = make_float4(a0.x * sc, a0.y * sc, a0.z * sc, a0.w * sc);
    if (OUTBF) {
      reinterpret_cast<ushort4*>(aggb)[(size_t)n * 32 + l32] =
          make_ushort4(f2bf(o.x), f2bf(o.y), f2bf(o.z), f2bf(o.w));
    } else {
      reinterpret_cast<float4*>(aggf)[(size_t)n * 32 + l32] = o;
    }
    if (VMODE && l32 == 0) vout[n] = av * sc;
  }
}

// ---- final GEMM: out = x @ W + v2*c1^T + v1*c2^T + 1*c3^T ----
// Split-j 64-col halves (32KB W tile). Block 256 = 16 row-slots x 16 lanes;
// thread = 4 rows x 4 cols; 64 rows per block, single pass. All LDS reads
// b128 and wave-broadcast: 8 FMA per ds_read_b128.
__launch_bounds__(256, 2)
__global__ void k_gemm_f(const float* __restrict__ x, const float* __restrict__ W,
                         const float* __restrict__ c1, const float* __restrict__ c2,
                         const float* __restrict__ c3, const float* __restrict__ v1,
                         const float* __restrict__ v2, float* __restrict__ out) {
  __shared__ float Wl[DM * 64];     // 32 KB
  __shared__ float xs[64 * 132];    // 33.8 KB

  int jhalf = blockIdx.x & 1;
  int grp   = blockIdx.x >> 1;      // 0..781
  int jbase = jhalf * 64;
  int rbase = grp * 64;

  {
    const float4* W4 = reinterpret_cast<const float4*>(W);
    float4* Wl4 = reinterpret_cast<float4*>(Wl);
    for (int i = threadIdx.x; i < DM * 16; i += 256) {
      int k = i >> 4, j4 = i & 15;
      Wl4[k * 16 + j4] = W4[k * 32 + jhalf * 16 + j4];
    }
    const float4* xg = reinterpret_cast<const float4*>(x) + (size_t)rbase * 32;
    float4* xs4 = reinterpret_cast<float4*>(xs);
    int lim = (NN - rbase) * 32;
    for (int i = threadIdx.x; i < 2048; i += 256) {
      int r = i >> 5, seg = i & 31;
      float4 v = (i < lim) ? xg[i] : make_float4(0.f, 0.f, 0.f, 0.f);
      xs4[r * 33 + seg] = v;
    }
  }
  __syncthreads();

  int slot = threadIdx.x >> 4;      // 0..15 -> 4 rows each
  int lane = threadIdx.x & 15;      // 0..15 -> 4 cols each
  int jc = lane * 4;
  float4 e1 = *reinterpret_cast<const float4*>(&c1[jbase + jc]);
  float4 e2 = *reinterpret_cast<const float4*>(&c2[jbase + jc]);
  float4 e3 = *reinterpret_cast<const float4*>(&c3[jbase + jc]);

  int r0 = rbase + slot * 4;
  int rc0 = (r0 < NN) ? r0 : NN - 1;
  int rc1 = (r0 + 1 < NN) ? r0 + 1 : NN - 1;
  int rc2 = (r0 + 2 < NN) ? r0 + 2 : NN - 1;
  int rc3 = (r0 + 3 < NN) ? r0 + 3 : NN - 1;
  const float* x0 = &xs[(slot * 4 + 0) * 132];
  const float* x1 = &xs[(slot * 4 + 1) * 132];
  const float* x2 = &xs[(slot * 4 + 2) * 132];
  const float* x3 = &xs[(slot * 4 + 3) * 132];

  float4 a0, a1, a2, a3;
  {
    float q1, q2;
    q1 = v1[rc0]; q2 = v2[rc0];
    a0.x = q2 * e1.x + q1 * e2.x + e3.x; a0.y = q2 * e1.y + q1 * e2.y + e3.y;
    a0.z = q2 * e1.z + q1 * e2.z + e3.z; a0.w = q2 * e1.w + q1 * e2.w + e3.w;
    q1 = v1[rc1]; q2 = v2[rc1];
    a1.x = q2 * e1.x + q1 * e2.x + e3.x; a1.y = q2 * e1.y + q1 * e2.y + e3.y;
    a1.z = q2 * e1.z + q1 * e2.z + e3.z; a1.w = q2 * e1.w + q1 * e2.w + e3.w;
    q1 = v1[rc2]; q2 = v2[rc2];
    a2.x = q2 * e1.x + q1 * e2.x + e3.x; a2.y = q2 * e1.y + q1 * e2.y + e3.y;
    a2.z = q2 * e1.z + q1 * e2.z + e3.z; a2.w = q2 * e1.w + q1 * e2.w + e3.w;
    q1 = v1[rc3]; q2 = v2[rc3];
    a3.x = q2 * e1.x + q1 * e2.x + e3.x; a3.y = q2 * e1.y + q1 * e2.y + e3.y;
    a3.z = q2 * e1.z + q1 * e2.z + e3.z; a3.w = q2 * e1.w + q1 * e2.w + e3.w;
  }

#pragma unroll 4
  for (int k4 = 0; k4 < DM; k4 += 4) {
    float4 xv0 = *reinterpret_cast<const float4*>(&x0[k4]);
    float4 xv1 = *reinterpret_cast<const float4*>(&x1[k4]);
    float4 xv2 = *reinterpret_cast<const float4*>(&x2[k4]);
    float4 xv3 = *reinterpret_cast<const float4*>(&x3[k4]);
    float4 w0 = *reinterpret_cast<const float4*>(&Wl[(k4 + 0) * 64 + jc]);
    float4 w1 = *reinterpret_cast<const float4*>(&Wl[(k4 + 1) * 64 + jc]);
    float4 w2 = *reinterpret_cast<const float4*>(&Wl[(k4 + 2) * 64 + jc]);
    float4 w3 = *reinterpret_cast<const float4*>(&Wl[(k4 + 3) * 64 + jc]);
    FMA4(a0, xv0.x, w0) FMA4(a0, xv0.y, w1) FMA4(a0, xv0.z, w2) FMA4(a0, xv0.w, w3)
    FMA4(a1, xv1.x, w0) FMA4(a1, xv1.y, w1) FMA4(a1, xv1.z, w2) FMA4(a1, xv1.w, w3)
    FMA4(a2, xv2.x, w0) FMA4(a2, xv2.y, w1) FMA4(a2, xv2.z, w2) FMA4(a2, xv2.w, w3)
    FMA4(a3, xv3.x, w0) FMA4(a3, xv3.y, w1) FMA4(a3, xv3.z, w2) FMA4(a3, xv3.w, w3)
  }

  float* o = out + (size_t)r0 * DM + jbase + jc;
  if (r0 + 3 < NN) {
    *reinterpret_cast<float4*>(o)          = a0;
    *reinterpret_cast<float4*>(o + DM)     = a1;
    *reinterpret_cast<float4*>(o + 2 * DM) = a2;
    *reinterpret_cast<float4*>(o + 3 * DM) = a3;
  } else {
    if (r0 + 0 < NN) *reinterpret_cast<float4*>(o)          = a0;
    if (r0 + 1 < NN) *reinterpret_cast<float4*>(o + DM)     = a1;
    if (r0 + 2 < NN) *reinterpret_cast<float4*>(o + 2 * DM) = a2;
  }
}

extern "C" void kernel_launch(void* const* d_in, const int* in_sizes, int n_in,
                              void* d_out, int out_size, void* d_ws, size_t ws_size,
                              hipStream_t stream) {
  const float* in_feat = (const float*)d_in[0];
  const int*   ei      = (const int*)d_in[1];
  const float* Ws      = (const float*)d_in[2];
  const float* bs      = (const float*)d_in[3];
  float* out = (float*)d_out;

  const int* src = ei;
  const int* dst = ei + NE;
  const float* W1 = Ws;
  const float* W2 = Ws + DM * DM;
  const float* W3 = Ws + 2 * DM * DM;
  const float* b1 = bs;
  const float* b2 = bs + DM;
  const float* b3 = bs + 2 * DM;

  char* w = (char*)d_ws;
  int* hcop   = (int*)w;            w += (size_t)256 * CHN * sizeof(int);  // 12.8MB
  int* co     = (int*)w;            w += NN * sizeof(int);
  int* ci     = (int*)w;            w += NN * sizeof(int);
  int* rowptr = (int*)w;            w += (NN + 1) * sizeof(int);
  int* cursor = (int*)w;            w += NN * sizeof(int);
  int* bsum   = (int*)w;            w += NB * sizeof(int);
  int* boff   = (int*)w;            w += NB * sizeof(int);
  int* col    = (int*)w;            w += NE * sizeof(int);
  float* onorm = (float*)w;         w += NN * sizeof(float);
  float* inorm = (float*)w;         w += NN * sizeof(float);
  float* v1    = (float*)w;         w += NN * sizeof(float);
  float* v2    = (float*)w;         w += NN * sizeof(float);
  float* W23   = (float*)w;         w += DM * DM * sizeof(float);
  float* W123  = (float*)w;         w += DM * DM * sizeof(float);
  float* c1    = (float*)w;         w += DM * sizeof(float);
  float* c2    = (float*)w;         w += DM * sizeof(float);
  u16* featb  = (u16*)w;            w += (size_t)NN * DM * sizeof(u16);   // bf16 in_feat
  u16* g1b    = (u16*)w;            w += (size_t)NN * DM * sizeof(u16);   // bf16 M h
  u16* g2b    = (u16*)w;            w += (size_t)NN * DM * sizeof(u16);   // bf16 M^2 h
  float* bufA  = (float*)w;         w += (size_t)NN * DM * sizeof(float); // f32 M^3 h

  // graph preprocessing (no global atomics in counting; no memset needed)
  k_hist<<<256, 256, 0, stream>>>(src, dst, hcop);
  k_scan_part<<<NB, 256, 0, stream>>>(hcop, co, ci, bsum);
  k_scan_mid<<<1, 256, 0, stream>>>(bsum, boff, rowptr);
  k_scan_out<<<NB, 256, 0, stream>>>(ci, co, boff, rowptr, cursor, onorm, inorm);
  // fill + (in_feat -> bf16) rider
  k_fill<<<2 * NFB, 256, 0, stream>>>(src, dst, cursor, col, in_feat, featb);

  // g3 = M^3 h; v1 = M·1 rides gather1, v2 = M·v1 rides gather2;
  // W23 = W2 W3 rides gather1; W123 = W1 W23, c1 = b1 W23, c2 = b2 W3 ride gather2.
  k_gather_t<1, 1, 1><<<NGB + 64, 256, 0, stream>>>(featb, rowptr, col, onorm, inorm,
                                                    nullptr, g1b, nullptr, v1,
                                                    W2, W3, W23,
                                                    nullptr, nullptr, nullptr,
                                                    nullptr, nullptr, nullptr);
  k_gather_t<2, 2, 1><<<NGB + 65, 256, 0, stream>>>(g1b, rowptr, col, onorm, inorm,
                                                    v1, g2b, nullptr, v2,
                                                    W1, W23, W123,
                                                    b1, W23, c1, b2, W3, c2);
  k_gather_t<0, 0, 0><<<NGB, 256, 0, stream>>>(g2b, rowptr, col, onorm, inorm,
                                               nullptr, nullptr, bufA, nullptr,
                                               nullptr, nullptr, nullptr,
                                               nullptr, nullptr, nullptr,
                                               nullptr, nullptr, nullptr);

  // out = g3 @ W123 + v2 c1^T + v1 c2^T + 1 b3^T
  k_gemm_f<<<1564, 256, 0, stream>>>(bufA, W123, c1, c2, b3, v1, v2, out);
}

// Round 15
// 228.380 us; speedup vs baseline: 7.7565x; 1.1263x over previous
//
#include <hip/hip_runtime.h>

// GCN: 3 layers GraphConv (norm='both'), N=50000, E=800000, D=128.
// Round 15: CSR fill WITHOUT global atomics. k_pcur derives per-(chunk,slice)
// LDS cursors from k_hist's histograms (pcur aliases hcop's src half);
// k_fill2 does LDS-atomic cursor bumps + plain col stores. bf16 conversion
// rides k_fill2. (Round-14: bf16 features halved gather fetch, 315->257;
// k_fill's 800K global atomics now the exposed 72us tail.)
//   out = (M^3 h) W123 + v2 c1^T + v1 c2^T + 1 b3^T,  v1=M·1, v2=M·v1.

#define NN 50000
#define NE 800000
#define DM 128
#define NB 196     // ceil(NN/256) scan blocks
#define NGB 12500  // gather blocks (NN*64/256)
#define CHN 12500  // nodes per histogram chunk (50KB LDS)
#define NCOP 32    // edge-slice copies per (array, chunk)
#define NFB 782    // bf16-conversion rider blocks

typedef unsigned short u16;

#define FMA4(av, sv, wv) \
  av.x += (sv) * (wv).x; av.y += (sv) * (wv).y; av.z += (sv) * (wv).z; av.w += (sv) * (wv).w;

__device__ __forceinline__ float bf2f(u16 u) {
  return __uint_as_float((unsigned)u << 16);
}
__device__ __forceinline__ u16 f2bf(float f) {
  unsigned x = __float_as_uint(f);
  return (u16)((x + 0x7fffu + ((x >> 16) & 1u)) >> 16);  // RNE, finite inputs
}

// grid 256: b = arr*128 + chunk*32 + copy. LDS histogram of its node chunk
// over its edge slice; non-atomic flush to hcop[b*CHN ..].
__global__ void k_hist(const int* __restrict__ src, const int* __restrict__ dst,
                       int* __restrict__ hcop) {
  __shared__ int h[CHN];
  int b = blockIdx.x;
  int arr   = b >> 7;
  int chunk = (b >> 5) & 3;
  int copy  = b & 31;
  const int* idx = arr ? dst : src;
  int lo = chunk * CHN;
  for (int i = threadIdx.x; i < CHN; i += 256) h[i] = 0;
  __syncthreads();
  const int4* e4 = reinterpret_cast<const int4*>(idx) + copy * (NE / 4 / NCOP);
  for (int i = threadIdx.x; i < NE / 4 / NCOP; i += 256) {
    int4 v = e4[i];
    unsigned a;
    a = (unsigned)(v.x - lo); if (a < (unsigned)CHN) atomicAdd(&h[a], 1);
    a = (unsigned)(v.y - lo); if (a < (unsigned)CHN) atomicAdd(&h[a], 1);
    a = (unsigned)(v.z - lo); if (a < (unsigned)CHN) atomicAdd(&h[a], 1);
    a = (unsigned)(v.w - lo); if (a < (unsigned)CHN) atomicAdd(&h[a], 1);
  }
  __syncthreads();
  int* o = hcop + (size_t)b * CHN;
  for (int i = threadIdx.x; i < CHN; i += 256) o[i] = h[i];
}

// ---- scan stage 1: reduce 32 copies -> co/ci, block sums of ci ----
__global__ void k_scan_part(const int* __restrict__ hcop, int* __restrict__ co,
                            int* __restrict__ ci, int* __restrict__ bsum) {
  __shared__ int s[256];
  int i = blockIdx.x * 256 + threadIdx.x;
  int sco = 0, sci = 0;
  if (i < NN) {
    int ch = i / CHN;
    int loc = i - ch * CHN;
    const int* pco = hcop + (size_t)(ch * 32) * CHN + loc;
    const int* pci = hcop + (size_t)(128 + ch * 32) * CHN + loc;
#pragma unroll
    for (int p = 0; p < NCOP; ++p) {
      sco += pco[(size_t)p * CHN];
      sci += pci[(size_t)p * CHN];
    }
    co[i] = sco;
    ci[i] = sci;
  }
  s[threadIdx.x] = sci;
  __syncthreads();
  for (int off = 128; off > 0; off >>= 1) {
    if (threadIdx.x < off) s[threadIdx.x] += s[threadIdx.x + off];
    __syncthreads();
  }
  if (threadIdx.x == 0) bsum[blockIdx.x] = s[0];
}

__global__ void k_scan_mid(const int* __restrict__ bsum, int* __restrict__ boff,
                           int* __restrict__ rowptr) {
  __shared__ int s[256];
  int t = threadIdx.x;
  int v = (t < NB) ? bsum[t] : 0;
  s[t] = v;
  __syncthreads();
  for (int off = 1; off < 256; off <<= 1) {
    int u = (t >= off) ? s[t - off] : 0;
    __syncthreads();
    s[t] += u;
    __syncthreads();
  }
  if (t < NB) boff[t] = s[t] - v;  // exclusive
  if (t == 0) rowptr[NN] = NE;
}

__global__ void k_scan_out(const int* __restrict__ ci, const int* __restrict__ co,
                           const int* __restrict__ boff, int* __restrict__ rowptr,
                           float* __restrict__ onorm, float* __restrict__ inorm) {
  __shared__ int s[256];
  int t = threadIdx.x;
  int i = blockIdx.x * 256 + t;
  int v = (i < NN) ? ci[i] : 0;
  s[t] = v;
  __syncthreads();
  for (int off = 1; off < 256; off <<= 1) {
    int u = (t >= off) ? s[t - off] : 0;
    __syncthreads();
    s[t] += u;
    __syncthreads();
  }
  if (i < NN) {
    int ex = boff[blockIdx.x] + s[t] - v;
    rowptr[i] = ex;
    onorm[i] = rsqrtf(fmaxf((float)co[i], 1.0f));
    inorm[i] = rsqrtf(fmaxf((float)v, 1.0f));
  }
}

// pcur[(chunk*32+copy)*CHN + loc] = rowptr[node] + sum_{p<copy} hist_dst[chunk][p][loc]
// (pcur aliases hcop's src half — safe: k_scan_part already consumed it.)
__global__ void k_pcur(const int* __restrict__ hcop_dst, const int* __restrict__ rowptr,
                       int* __restrict__ pcur) {
  int i = blockIdx.x * 256 + threadIdx.x;
  if (i >= NN) return;
  int ch = i / CHN;
  int loc = i - ch * CHN;
  int run = rowptr[i];
  const int* hb = hcop_dst + (size_t)(ch * 32) * CHN + loc;
  int* pb = pcur + (size_t)(ch * 32) * CHN + loc;
#pragma unroll
  for (int p = 0; p < NCOP; ++p) {
    pb[(size_t)p * CHN] = run;
    run += hb[(size_t)p * CHN];
  }
}

// blocks <128: (chunk,slice) CSR fill via LDS cursors, no global atomics.
// blocks >=128: in_feat f32 -> bf16 conversion rider.
__global__ void k_fill2(const int* __restrict__ src, const int* __restrict__ dst,
                        const int* __restrict__ pcur, int* __restrict__ col,
                        const float* __restrict__ feat, u16* __restrict__ featb) {
  __shared__ int cur[CHN];
  int b = blockIdx.x;
  if (b >= 128) {
    size_t base = ((size_t)(b - 128) * 256 + threadIdx.x) * 8;
    const size_t stride = (size_t)NFB * 256 * 8;
#pragma unroll
    for (int it = 0; it < 4; ++it, base += stride) {
      if (base < (size_t)NN * DM) {
        float4 f0 = *reinterpret_cast<const float4*>(feat + base);
        float4 f1 = *reinterpret_cast<const float4*>(feat + base + 4);
        ushort4 u0 = make_ushort4(f2bf(f0.x), f2bf(f0.y), f2bf(f0.z), f2bf(f0.w));
        ushort4 u1 = make_ushort4(f2bf(f1.x), f2bf(f1.y), f2bf(f1.z), f2bf(f1.w));
        *reinterpret_cast<ushort4*>(featb + base) = u0;
        *reinterpret_cast<ushort4*>(featb + base + 4) = u1;
      }
    }
    return;
  }
  int chunk = b >> 5;
  int copy  = b & 31;
  int lo = chunk * CHN;
  const int* pc = pcur + (size_t)b * CHN;
  for (int i = threadIdx.x; i < CHN; i += 256) cur[i] = pc[i];
  __syncthreads();
  const int4* s4 = reinterpret_cast<const int4*>(src) + copy * (NE / 4 / NCOP);
  const int4* d4 = reinterpret_cast<const int4*>(dst) + copy * (NE / 4 / NCOP);
  for (int i = threadIdx.x; i < NE / 4 / NCOP; i += 256) {
    int4 s = s4[i];
    int4 d = d4[i];
    unsigned a;
    int p;
    a = (unsigned)(d.x - lo); if (a < (unsigned)CHN) { p = atomicAdd(&cur[a], 1); col[p] = s.x; }
    a = (unsigned)(d.y - lo); if (a < (unsigned)CHN) { p = atomicAdd(&cur[a], 1); col[p] = s.y; }
    a = (unsigned)(d.z - lo); if (a < (unsigned)CHN) { p = atomicAdd(&cur[a], 1); col[p] = s.z; }
    a = (unsigned)(d.w - lo); if (a < (unsigned)CHN) { p = atomicAdd(&cur[a], 1); col[p] = s.w; }
  }
}

// ---- feature gather: Y = M X with bf16 X. One wave per node; halves take
// even/odd edges (unroll 2/half); f32 accumulate; shfl-xor(32) reduce.
// OUTBF: write bf16 (passes 1,2) or f32 (pass 3, GEMM input).
// VMODE 0: features only. 1: also vout = M·1. 2: also vout = M·vin.
// EXTRA>=1: blocks beyond NGB compute mC = mA @ mB (64 blocks, 2 rows each).
// EXTRA==2: block NGB+64 computes vc1 = vb1 @ vB1, vc2 = vb2 @ vB2.
template <int VMODE, int EXTRA, int OUTBF>
__global__ void k_gather_t(const u16* __restrict__ h, const int* __restrict__ rowptr,
                           const int* __restrict__ col, const float* __restrict__ onorm,
                           const float* __restrict__ inorm, const float* __restrict__ vin,
                           u16* __restrict__ aggb, float* __restrict__ aggf,
                           float* __restrict__ vout,
                           const float* __restrict__ mA, const float* __restrict__ mB,
                           float* __restrict__ mC,
                           const float* __restrict__ vb1, const float* __restrict__ vB1,
                           float* __restrict__ vc1,
                           const float* __restrict__ vb2, const float* __restrict__ vB2,
                           float* __restrict__ vc2) {
  if (EXTRA) {
    int eb = (int)blockIdx.x - NGB;
    if (eb >= 0) {
      if (eb < 64) {            // mC = mA @ mB, rows 2eb, 2eb+1
        int i0 = eb * 2 + (threadIdx.x >> 7);
        int j = threadIdx.x & 127;
        float acc = 0.f;
        for (int k = 0; k < DM; ++k) acc += mA[i0 * DM + k] * mB[k * DM + j];
        mC[i0 * DM + j] = acc;
      } else if (EXTRA == 2) {  // vc1 = vb1@vB1 (tid<128), vc2 = vb2@vB2
        int t = threadIdx.x;
        if (t < DM) {
          float acc = 0.f;
          for (int k = 0; k < DM; ++k) acc += vb1[k] * vB1[k * DM + t];
          vc1[t] = acc;
        } else {
          int j = t - DM;
          float acc = 0.f;
          for (int k = 0; k < DM; ++k) acc += vb2[k] * vB2[k * DM + j];
          vc2[j] = acc;
        }
      }
      return;
    }
  }
  int tid = blockIdx.x * blockDim.x + threadIdx.x;
  int n = tid >> 6;
  if (n >= NN) return;
  int lane = threadIdx.x & 63;
  int half = lane >> 5;
  int l32 = lane & 31;
  int beg = rowptr[n], end = rowptr[n + 1];
  const ushort4* h4 = reinterpret_cast<const ushort4*>(h);  // 4 bf16 per elem
  float4 a0 = make_float4(0.f, 0.f, 0.f, 0.f);
  float4 a1 = make_float4(0.f, 0.f, 0.f, 0.f);
  float av = 0.f;
  int e = beg + half;
  for (; e + 2 < end; e += 4) {
    int s0 = col[e], s1 = col[e + 2];
    float n0 = onorm[s0], n1 = onorm[s1];
    ushort4 u0 = h4[(size_t)s0 * 32 + l32];
    ushort4 u1 = h4[(size_t)s1 * 32 + l32];
    float4 v0 = make_float4(bf2f(u0.x), bf2f(u0.y), bf2f(u0.z), bf2f(u0.w));
    float4 v1 = make_float4(bf2f(u1.x), bf2f(u1.y), bf2f(u1.z), bf2f(u1.w));
    if (VMODE == 1) av += n0 + n1;
    if (VMODE == 2) av += n0 * vin[s0] + n1 * vin[s1];
    FMA4(a0, n0, v0)
    FMA4(a1, n1, v1)
  }
  if (e < end) {
    int s0 = col[e];
    float n0 = onorm[s0];
    ushort4 u0 = h4[(size_t)s0 * 32 + l32];
    float4 v0 = make_float4(bf2f(u0.x), bf2f(u0.y), bf2f(u0.z), bf2f(u0.w));
    if (VMODE == 1) av += n0;
    if (VMODE == 2) av += n0 * vin[s0];
    FMA4(a0, n0, v0)
  }
  a0.x += a1.x; a0.y += a1.y; a0.z += a1.z; a0.w += a1.w;
  a0.x += __shfl_xor(a0.x, 32);
  a0.y += __shfl_xor(a0.y, 32);
  a0.z += __shfl_xor(a0.z, 32);
  a0.w += __shfl_xor(a0.w, 32);
  if (VMODE) av += __shfl_xor(av, 32);
  if (half == 0) {
    float sc = inorm[n];
    float4 o = make_float4(a0.x * sc, a0.y * sc, a0.z * sc, a0.w * sc);
    if (OUTBF) {
      reinterpret_cast<ushort4*>(aggb)[(size_t)n * 32 + l32] =
          make_ushort4(f2bf(o.x), f2bf(o.y), f2bf(o.z), f2bf(o.w));
    } else {
      reinterpret_cast<float4*>(aggf)[(size_t)n * 32 + l32] = o;
    }
    if (VMODE && l32 == 0) vout[n] = av * sc;
  }
}

// ---- final GEMM: out = x @ W + v2*c1^T + v1*c2^T + 1*c3^T ----
// Split-j 64-col halves (32KB W tile). Block 256 = 16 row-slots x 16 lanes;
// thread = 4 rows x 4 cols; 64 rows per block, single pass. All LDS reads
// b128 and wave-broadcast: 8 FMA per ds_read_b128.
__launch_bounds__(256, 2)
__global__ void k_gemm_f(const float* __restrict__ x, const float* __restrict__ W,
                         const float* __restrict__ c1, const float* __restrict__ c2,
                         const float* __restrict__ c3, const float* __restrict__ v1,
                         const float* __restrict__ v2, float* __restrict__ out) {
  __shared__ float Wl[DM * 64];     // 32 KB
  __shared__ float xs[64 * 132];    // 33.8 KB

  int jhalf = blockIdx.x & 1;
  int grp   = blockIdx.x >> 1;      // 0..781
  int jbase = jhalf * 64;
  int rbase = grp * 64;

  {
    const float4* W4 = reinterpret_cast<const float4*>(W);
    float4* Wl4 = reinterpret_cast<float4*>(Wl);
    for (int i = threadIdx.x; i < DM * 16; i += 256) {
      int k = i >> 4, j4 = i & 15;
      Wl4[k * 16 + j4] = W4[k * 32 + jhalf * 16 + j4];
    }
    const float4* xg = reinterpret_cast<const float4*>(x) + (size_t)rbase * 32;
    float4* xs4 = reinterpret_cast<float4*>(xs);
    int lim = (NN - rbase) * 32;
    for (int i = threadIdx.x; i < 2048; i += 256) {
      int r = i >> 5, seg = i & 31;
      float4 v = (i < lim) ? xg[i] : make_float4(0.f, 0.f, 0.f, 0.f);
      xs4[r * 33 + seg] = v;
    }
  }
  __syncthreads();

  int slot = threadIdx.x >> 4;      // 0..15 -> 4 rows each
  int lane = threadIdx.x & 15;      // 0..15 -> 4 cols each
  int jc = lane * 4;
  float4 e1 = *reinterpret_cast<const float4*>(&c1[jbase + jc]);
  float4 e2 = *reinterpret_cast<const float4*>(&c2[jbase + jc]);
  float4 e3 = *reinterpret_cast<const float4*>(&c3[jbase + jc]);

  int r0 = rbase + slot * 4;
  int rc0 = (r0 < NN) ? r0 : NN - 1;
  int rc1 = (r0 + 1 < NN) ? r0 + 1 : NN - 1;
  int rc2 = (r0 + 2 < NN) ? r0 + 2 : NN - 1;
  int rc3 = (r0 + 3 < NN) ? r0 + 3 : NN - 1;
  const float* x0 = &xs[(slot * 4 + 0) * 132];
  const float* x1 = &xs[(slot * 4 + 1) * 132];
  const float* x2 = &xs[(slot * 4 + 2) * 132];
  const float* x3 = &xs[(slot * 4 + 3) * 132];

  float4 a0, a1, a2, a3;
  {
    float q1, q2;
    q1 = v1[rc0]; q2 = v2[rc0];
    a0.x = q2 * e1.x + q1 * e2.x + e3.x; a0.y = q2 * e1.y + q1 * e2.y + e3.y;
    a0.z = q2 * e1.z + q1 * e2.z + e3.z; a0.w = q2 * e1.w + q1 * e2.w + e3.w;
    q1 = v1[rc1]; q2 = v2[rc1];
    a1.x = q2 * e1.x + q1 * e2.x + e3.x; a1.y = q2 * e1.y + q1 * e2.y + e3.y;
    a1.z = q2 * e1.z + q1 * e2.z + e3.z; a1.w = q2 * e1.w + q1 * e2.w + e3.w;
    q1 = v1[rc2]; q2 = v2[rc2];
    a2.x = q2 * e1.x + q1 * e2.x + e3.x; a2.y = q2 * e1.y + q1 * e2.y + e3.y;
    a2.z = q2 * e1.z + q1 * e2.z + e3.z; a2.w = q2 * e1.w + q1 * e2.w + e3.w;
    q1 = v1[rc3]; q2 = v2[rc3];
    a3.x = q2 * e1.x + q1 * e2.x + e3.x; a3.y = q2 * e1.y + q1 * e2.y + e3.y;
    a3.z = q2 * e1.z + q1 * e2.z + e3.z; a3.w = q2 * e1.w + q1 * e2.w + e3.w;
  }

#pragma unroll 4
  for (int k4 = 0; k4 < DM; k4 += 4) {
    float4 xv0 = *reinterpret_cast<const float4*>(&x0[k4]);
    float4 xv1 = *reinterpret_cast<const float4*>(&x1[k4]);
    float4 xv2 = *reinterpret_cast<const float4*>(&x2[k4]);
    float4 xv3 = *reinterpret_cast<const float4*>(&x3[k4]);
    float4 w0 = *reinterpret_cast<const float4*>(&Wl[(k4 + 0) * 64 + jc]);
    float4 w1 = *reinterpret_cast<const float4*>(&Wl[(k4 + 1) * 64 + jc]);
    float4 w2 = *reinterpret_cast<const float4*>(&Wl[(k4 + 2) * 64 + jc]);
    float4 w3 = *reinterpret_cast<const float4*>(&Wl[(k4 + 3) * 64 + jc]);
    FMA4(a0, xv0.x, w0) FMA4(a0, xv0.y, w1) FMA4(a0, xv0.z, w2) FMA4(a0, xv0.w, w3)
    FMA4(a1, xv1.x, w0) FMA4(a1, xv1.y, w1) FMA4(a1, xv1.z, w2) FMA4(a1, xv1.w, w3)
    FMA4(a2, xv2.x, w0) FMA4(a2, xv2.y, w1) FMA4(a2, xv2.z, w2) FMA4(a2, xv2.w, w3)
    FMA4(a3, xv3.x, w0) FMA4(a3, xv3.y, w1) FMA4(a3, xv3.z, w2) FMA4(a3, xv3.w, w3)
  }

  float* o = out + (size_t)r0 * DM + jbase + jc;
  if (r0 + 3 < NN) {
    *reinterpret_cast<float4*>(o)          = a0;
    *reinterpret_cast<float4*>(o + DM)     = a1;
    *reinterpret_cast<float4*>(o + 2 * DM) = a2;
    *reinterpret_cast<float4*>(o + 3 * DM) = a3;
  } else {
    if (r0 + 0 < NN) *reinterpret_cast<float4*>(o)          = a0;
    if (r0 + 1 < NN) *reinterpret_cast<float4*>(o + DM)     = a1;
    if (r0 + 2 < NN) *reinterpret_cast<float4*>(o + 2 * DM) = a2;
  }
}

extern "C" void kernel_launch(void* const* d_in, const int* in_sizes, int n_in,
                              void* d_out, int out_size, void* d_ws, size_t ws_size,
                              hipStream_t stream) {
  const float* in_feat = (const float*)d_in[0];
  const int*   ei      = (const int*)d_in[1];
  const float* Ws      = (const float*)d_in[2];
  const float* bs      = (const float*)d_in[3];
  float* out = (float*)d_out;

  const int* src = ei;
  const int* dst = ei + NE;
  const float* W1 = Ws;
  const float* W2 = Ws + DM * DM;
  const float* W3 = Ws + 2 * DM * DM;
  const float* b1 = bs;
  const float* b2 = bs + DM;
  const float* b3 = bs + 2 * DM;

  char* w = (char*)d_ws;
  int* hcop   = (int*)w;            w += (size_t)256 * CHN * sizeof(int);  // 12.8MB
  int* co     = (int*)w;            w += NN * sizeof(int);
  int* ci     = (int*)w;            w += NN * sizeof(int);
  int* rowptr = (int*)w;            w += (NN + 1) * sizeof(int);
  int* bsum   = (int*)w;            w += NB * sizeof(int);
  int* boff   = (int*)w;            w += NB * sizeof(int);
  int* col    = (int*)w;            w += NE * sizeof(int);
  float* onorm = (float*)w;         w += NN * sizeof(float);
  float* inorm = (float*)w;         w += NN * sizeof(float);
  float* v1    = (float*)w;         w += NN * sizeof(float);
  float* v2    = (float*)w;         w += NN * sizeof(float);
  float* W23   = (float*)w;         w += DM * DM * sizeof(float);
  float* W123  = (float*)w;         w += DM * DM * sizeof(float);
  float* c1    = (float*)w;         w += DM * sizeof(float);
  float* c2    = (float*)w;         w += DM * sizeof(float);
  u16* featb  = (u16*)w;            w += (size_t)NN * DM * sizeof(u16);   // bf16 in_feat
  u16* g1b    = (u16*)w;            w += (size_t)NN * DM * sizeof(u16);   // bf16 M h
  u16* g2b    = (u16*)w;            w += (size_t)NN * DM * sizeof(u16);   // bf16 M^2 h
  float* bufA  = (float*)w;         w += (size_t)NN * DM * sizeof(float); // f32 M^3 h

  // pcur aliases hcop's src half (blocks 0..127), consumed by k_scan_part
  // before k_pcur writes it. hcop's dst half (blocks 128..255) stays live.
  int* pcur = hcop;
  const int* hcop_dst = hcop + (size_t)128 * CHN;

  // graph preprocessing (no global atomics anywhere)
  k_hist<<<256, 256, 0, stream>>>(src, dst, hcop);
  k_scan_part<<<NB, 256, 0, stream>>>(hcop, co, ci, bsum);
  k_scan_mid<<<1, 256, 0, stream>>>(bsum, boff, rowptr);
  k_scan_out<<<NB, 256, 0, stream>>>(ci, co, boff, rowptr, onorm, inorm);
  k_pcur<<<NB, 256, 0, stream>>>(hcop_dst, rowptr, pcur);
  // LDS-cursor CSR fill + (in_feat -> bf16) rider
  k_fill2<<<128 + NFB, 256, 0, stream>>>(src, dst, pcur, col, in_feat, featb);

  // g3 = M^3 h; v1 = M·1 rides gather1, v2 = M·v1 rides gather2;
  // W23 = W2 W3 rides gather1; W123 = W1 W23, c1 = b1 W23, c2 = b2 W3 ride gather2.
  k_gather_t<1, 1, 1><<<NGB + 64, 256, 0, stream>>>(featb, rowptr, col, onorm, inorm,
                                                    nullptr, g1b, nullptr, v1,
                                                    W2, W3, W23,
                                                    nullptr, nullptr, nullptr,
                                                    nullptr, nullptr, nullptr);
  k_gather_t<2, 2, 1><<<NGB + 65, 256, 0, stream>>>(g1b, rowptr, col, onorm, inorm,
                                                    v1, g2b, nullptr, v2,
                                                    W1, W23, W123,
                                                    b1, W23, c1, b2, W3, c2);
  k_gather_t<0, 0, 0><<<NGB, 256, 0, stream>>>(g2b, rowptr, col, onorm, inorm,
                                               nullptr, nullptr, bufA, nullptr,
                                               nullptr, nullptr, nullptr,
                                               nullptr, nullptr, nullptr,
                                               nullptr, nullptr, nullptr);

  // out = g3 @ W123 + v2 c1^T + v1 c2^T + 1 b3^T
  k_gemm_f<<<1564, 256, 0, stream>>>(bufA, W123, c1, c2, b3, v1, v2, out);
}

// Round 16
// 203.955 us; speedup vs baseline: 8.6854x; 1.1198x over previous
//
#include <hip/hip_runtime.h>

// GCN: 3 layers GraphConv (norm='both'), N=50000, E=800000, D=128.
// Round 16: (a) GEMM -> MFMA bf16 on g2b (out = M·(g2·W123), W123 stored
// bf16-transposed by gather2's rider; t stored bf16; rank-1 terms fused
// into final gather's epilogue); (b) gather unroll-4 retest (regime now
// latency-ish: 35% HBM / 35% VALU); (c) scan_mid+scan_out+pcur merged.
//   out = M·(M^2 h · W123) + v2 c1^T + v1 c2^T + 1 b3^T,  v1=M·1, v2=M·v1.

#define NN 50000
#define NE 800000
#define DM 128
#define NB 196     // ceil(NN/256) scan blocks
#define NGB 12500  // gather blocks (NN*64/256)
#define CHN 12500  // nodes per histogram chunk (50KB LDS)
#define NCOP 32    // edge-slice copies per (array, chunk)
#define NFB 782    // bf16-conversion rider blocks

typedef unsigned short u16;
typedef __attribute__((ext_vector_type(8))) short bf16x8;
typedef __attribute__((ext_vector_type(4))) float f32x4;

#define FMA4(av, sv, wv) \
  av.x += (sv) * (wv).x; av.y += (sv) * (wv).y; av.z += (sv) * (wv).z; av.w += (sv) * (wv).w;

__device__ __forceinline__ float bf2f(u16 u) {
  return __uint_as_float((unsigned)u << 16);
}
__device__ __forceinline__ u16 f2bf(float f) {
  unsigned x = __float_as_uint(f);
  return (u16)((x + 0x7fffu + ((x >> 16) & 1u)) >> 16);  // RNE, finite inputs
}
__device__ __forceinline__ float4 bf4(ushort4 u) {
  return make_float4(bf2f(u.x), bf2f(u.y), bf2f(u.z), bf2f(u.w));
}

// grid 256: b = arr*128 + chunk*32 + copy. LDS histogram of its node chunk
// over its edge slice; non-atomic flush to hcop[b*CHN ..].
__global__ void k_hist(const int* __restrict__ src, const int* __restrict__ dst,
                       int* __restrict__ hcop) {
  __shared__ int h[CHN];
  int b = blockIdx.x;
  int arr   = b >> 7;
  int chunk = (b >> 5) & 3;
  int copy  = b & 31;
  const int* idx = arr ? dst : src;
  int lo = chunk * CHN;
  for (int i = threadIdx.x; i < CHN; i += 256) h[i] = 0;
  __syncthreads();
  const int4* e4 = reinterpret_cast<const int4*>(idx) + copy * (NE / 4 / NCOP);
  for (int i = threadIdx.x; i < NE / 4 / NCOP; i += 256) {
    int4 v = e4[i];
    unsigned a;
    a = (unsigned)(v.x - lo); if (a < (unsigned)CHN) atomicAdd(&h[a], 1);
    a = (unsigned)(v.y - lo); if (a < (unsigned)CHN) atomicAdd(&h[a], 1);
    a = (unsigned)(v.z - lo); if (a < (unsigned)CHN) atomicAdd(&h[a], 1);
    a = (unsigned)(v.w - lo); if (a < (unsigned)CHN) atomicAdd(&h[a], 1);
  }
  __syncthreads();
  int* o = hcop + (size_t)b * CHN;
  for (int i = threadIdx.x; i < CHN; i += 256) o[i] = h[i];
}

// ---- scan stage 1: reduce 32 copies -> co/ci, block sums of ci ----
__global__ void k_scan_part(const int* __restrict__ hcop, int* __restrict__ co,
                            int* __restrict__ ci, int* __restrict__ bsum) {
  __shared__ int s[256];
  int i = blockIdx.x * 256 + threadIdx.x;
  int sco = 0, sci = 0;
  if (i < NN) {
    int ch = i / CHN;
    int loc = i - ch * CHN;
    const int* pco = hcop + (size_t)(ch * 32) * CHN + loc;
    const int* pci = hcop + (size_t)(128 + ch * 32) * CHN + loc;
#pragma unroll
    for (int p = 0; p < NCOP; ++p) {
      sco += pco[(size_t)p * CHN];
      sci += pci[(size_t)p * CHN];
    }
    co[i] = sco;
    ci[i] = sci;
  }
  s[threadIdx.x] = sci;
  __syncthreads();
  for (int off = 128; off > 0; off >>= 1) {
    if (threadIdx.x < off) s[threadIdx.x] += s[threadIdx.x + off];
    __syncthreads();
  }
  if (threadIdx.x == 0) bsum[blockIdx.x] = s[0];
}

// ---- merged: scan bsum in-block, per-node scan -> rowptr/norms, pcur fill ----
__global__ void k_scan_out2(const int* __restrict__ ci, const int* __restrict__ co,
                            const int* __restrict__ bsum, int* __restrict__ rowptr,
                            float* __restrict__ onorm, float* __restrict__ inorm,
                            const int* __restrict__ hcop_dst, int* __restrict__ pcur) {
  __shared__ int s[256];
  int t = threadIdx.x;
  int bv = (t < NB) ? bsum[t] : 0;
  s[t] = bv;
  __syncthreads();
  for (int off = 1; off < 256; off <<= 1) {
    int u = (t >= off) ? s[t - off] : 0;
    __syncthreads();
    s[t] += u;
    __syncthreads();
  }
  int boff_blk = s[blockIdx.x] - bsum[blockIdx.x];  // exclusive prefix of our block
  __syncthreads();

  int i = blockIdx.x * 256 + t;
  int v = (i < NN) ? ci[i] : 0;
  s[t] = v;
  __syncthreads();
  for (int off = 1; off < 256; off <<= 1) {
    int u = (t >= off) ? s[t - off] : 0;
    __syncthreads();
    s[t] += u;
    __syncthreads();
  }
  if (i < NN) {
    int ex = boff_blk + s[t] - v;
    rowptr[i] = ex;
    onorm[i] = rsqrtf(fmaxf((float)co[i], 1.0f));
    inorm[i] = rsqrtf(fmaxf((float)v, 1.0f));
    int ch = i / CHN;
    int loc = i - ch * CHN;
    const int* hb = hcop_dst + (size_t)(ch * 32) * CHN + loc;
    int* pb = pcur + (size_t)(ch * 32) * CHN + loc;
    int run = ex;
#pragma unroll
    for (int p = 0; p < NCOP; ++p) {
      pb[(size_t)p * CHN] = run;
      run += hb[(size_t)p * CHN];
    }
  }
  if (blockIdx.x == 0 && t == 0) rowptr[NN] = NE;
}

// blocks <128: (chunk,slice) CSR fill via LDS cursors, no global atomics.
// blocks >=128: in_feat f32 -> bf16 conversion rider.
__global__ void k_fill2(const int* __restrict__ src, const int* __restrict__ dst,
                        const int* __restrict__ pcur, int* __restrict__ col,
                        const float* __restrict__ feat, u16* __restrict__ featb) {
  __shared__ int cur[CHN];
  int b = blockIdx.x;
  if (b >= 128) {
    size_t base = ((size_t)(b - 128) * 256 + threadIdx.x) * 8;
    const size_t stride = (size_t)NFB * 256 * 8;
#pragma unroll
    for (int it = 0; it < 4; ++it, base += stride) {
      if (base < (size_t)NN * DM) {
        float4 f0 = *reinterpret_cast<const float4*>(feat + base);
        float4 f1 = *reinterpret_cast<const float4*>(feat + base + 4);
        ushort4 u0 = make_ushort4(f2bf(f0.x), f2bf(f0.y), f2bf(f0.z), f2bf(f0.w));
        ushort4 u1 = make_ushort4(f2bf(f1.x), f2bf(f1.y), f2bf(f1.z), f2bf(f1.w));
        *reinterpret_cast<ushort4*>(featb + base) = u0;
        *reinterpret_cast<ushort4*>(featb + base + 4) = u1;
      }
    }
    return;
  }
  int chunk = b >> 5;
  int copy  = b & 31;
  int lo = chunk * CHN;
  const int* pc = pcur + (size_t)b * CHN;
  for (int i = threadIdx.x; i < CHN; i += 256) cur[i] = pc[i];
  __syncthreads();
  const int4* s4 = reinterpret_cast<const int4*>(src) + copy * (NE / 4 / NCOP);
  const int4* d4 = reinterpret_cast<const int4*>(dst) + copy * (NE / 4 / NCOP);
  for (int i = threadIdx.x; i < NE / 4 / NCOP; i += 256) {
    int4 s = s4[i];
    int4 d = d4[i];
    unsigned a;
    int p;
    a = (unsigned)(d.x - lo); if (a < (unsigned)CHN) { p = atomicAdd(&cur[a], 1); col[p] = s.x; }
    a = (unsigned)(d.y - lo); if (a < (unsigned)CHN) { p = atomicAdd(&cur[a], 1); col[p] = s.y; }
    a = (unsigned)(d.z - lo); if (a < (unsigned)CHN) { p = atomicAdd(&cur[a], 1); col[p] = s.z; }
    a = (unsigned)(d.w - lo); if (a < (unsigned)CHN) { p = atomicAdd(&cur[a], 1); col[p] = s.w; }
  }
}

// ---- feature gather: Y = M X with bf16 X. One wave per node; halves take
// even/odd edges; unroll 4/half (8 rows in flight); f32 accumulate;
// shfl-xor(32) reduce.
// VMODE 0: features only. 1: also vout = M·1. 2: also vout = M·vin.
// EXTRA==1: 64 extra blocks compute mCf = mA @ mB (f32, 2 rows each).
// EXTRA==2: 64 extra blocks compute mCt = bf16-transposed(mA @ mB);
//           block NGB+64 computes vc1 = vb1@vB1, vc2 = vb2@vB2.
// OUTMODE 0: write bf16 aggb. 1: final -> f32 outf with fused rank-1 terms.
template <int VMODE, int EXTRA, int OUTMODE>
__global__ void k_gather_t(const u16* __restrict__ h, const int* __restrict__ rowptr,
                           const int* __restrict__ col, const float* __restrict__ onorm,
                           const float* __restrict__ inorm, const float* __restrict__ vin,
                           u16* __restrict__ aggb, float* __restrict__ outf,
                           float* __restrict__ vout,
                           const float* __restrict__ mA, const float* __restrict__ mB,
                           float* __restrict__ mCf, u16* __restrict__ mCt,
                           const float* __restrict__ vb1, const float* __restrict__ vB1,
                           float* __restrict__ vc1,
                           const float* __restrict__ vb2, const float* __restrict__ vB2,
                           float* __restrict__ vc2,
                           const float* __restrict__ pv1, const float* __restrict__ pv2,
                           const float* __restrict__ pc1, const float* __restrict__ pc2,
                           const float* __restrict__ pb3) {
  if (EXTRA) {
    int eb = (int)blockIdx.x - NGB;
    if (eb >= 0) {
      if (eb < 64) {            // mA @ mB, rows 2eb, 2eb+1
        int i0 = eb * 2 + (threadIdx.x >> 7);
        int j = threadIdx.x & 127;
        float acc = 0.f;
        for (int k = 0; k < DM; ++k) acc += mA[i0 * DM + k] * mB[k * DM + j];
        if (EXTRA == 1) mCf[i0 * DM + j] = acc;
        else            mCt[j * DM + i0] = f2bf(acc);  // bf16, transposed [n][k]
      } else if (EXTRA == 2) {  // vc1 = vb1@vB1 (tid<128), vc2 = vb2@vB2
        int t = threadIdx.x;
        if (t < DM) {
          float acc = 0.f;
          for (int k = 0; k < DM; ++k) acc += vb1[k] * vB1[k * DM + t];
          vc1[t] = acc;
        } else {
          int j = t - DM;
          float acc = 0.f;
          for (int k = 0; k < DM; ++k) acc += vb2[k] * vB2[k * DM + j];
          vc2[j] = acc;
        }
      }
      return;
    }
  }
  int tid = blockIdx.x * blockDim.x + threadIdx.x;
  int n = tid >> 6;
  if (n >= NN) return;
  int half = (threadIdx.x >> 5) & 1;
  int l32 = threadIdx.x & 31;
  int beg = rowptr[n], end = rowptr[n + 1];
  const ushort4* h4 = reinterpret_cast<const ushort4*>(h);
  float4 a0 = make_float4(0.f, 0.f, 0.f, 0.f);
  float4 a1 = make_float4(0.f, 0.f, 0.f, 0.f);
  float4 a2 = make_float4(0.f, 0.f, 0.f, 0.f);
  float4 a3 = make_float4(0.f, 0.f, 0.f, 0.f);
  float av = 0.f;
  int e = beg + half;
  for (; e + 6 < end; e += 8) {
    int s0 = col[e], s1 = col[e + 2], s2 = col[e + 4], s3 = col[e + 6];
    float n0 = onorm[s0], n1 = onorm[s1], n2 = onorm[s2], n3 = onorm[s3];
    float4 v0 = bf4(h4[(size_t)s0 * 32 + l32]);
    float4 v1 = bf4(h4[(size_t)s1 * 32 + l32]);
    float4 v2 = bf4(h4[(size_t)s2 * 32 + l32]);
    float4 v3 = bf4(h4[(size_t)s3 * 32 + l32]);
    if (VMODE == 1) av += n0 + n1 + n2 + n3;
    if (VMODE == 2) av += n0 * vin[s0] + n1 * vin[s1] + n2 * vin[s2] + n3 * vin[s3];
    FMA4(a0, n0, v0)
    FMA4(a1, n1, v1)
    FMA4(a2, n2, v2)
    FMA4(a3, n3, v3)
  }
  for (; e < end; e += 2) {
    int s0 = col[e];
    float n0 = onorm[s0];
    float4 v0 = bf4(h4[(size_t)s0 * 32 + l32]);
    if (VMODE == 1) av += n0;
    if (VMODE == 2) av += n0 * vin[s0];
    FMA4(a0, n0, v0)
  }
  a0.x += a1.x + a2.x + a3.x;
  a0.y += a1.y + a2.y + a3.y;
  a0.z += a1.z + a2.z + a3.z;
  a0.w += a1.w + a2.w + a3.w;
  a0.x += __shfl_xor(a0.x, 32);
  a0.y += __shfl_xor(a0.y, 32);
  a0.z += __shfl_xor(a0.z, 32);
  a0.w += __shfl_xor(a0.w, 32);
  if (VMODE) av += __shfl_xor(av, 32);
  if (half == 0) {
    float sc = inorm[n];
    float4 o = make_float4(a0.x * sc, a0.y * sc, a0.z * sc, a0.w * sc);
    if (OUTMODE == 0) {
      reinterpret_cast<ushort4*>(aggb)[(size_t)n * 32 + l32] =
          make_ushort4(f2bf(o.x), f2bf(o.y), f2bf(o.z), f2bf(o.w));
    } else {
      int jc = l32 * 4;
      float4 e1 = *reinterpret_cast<const float4*>(pc1 + jc);
      float4 e2 = *reinterpret_cast<const float4*>(pc2 + jc);
      float4 e3 = *reinterpret_cast<const float4*>(pb3 + jc);
      float q1 = pv1[n], q2 = pv2[n];
      o.x += q2 * e1.x + q1 * e2.x + e3.x;
      o.y += q2 * e1.y + q1 * e2.y + e3.y;
      o.z += q2 * e1.z + q1 * e2.z + e3.z;
      o.w += q2 * e1.w + q1 * e2.w + e3.w;
      reinterpret_cast<float4*>(outf)[(size_t)n * 32 + l32] = o;
    }
    if (VMODE && l32 == 0) vout[n] = av * sc;
  }
}

// ---- MFMA GEMM: T[50000x128] = A[50000x128] @ B, both bf16.
// Bt is B stored transposed-bf16: Bt[n][k] = W123[k][n].
// Block 256 = 4 waves: wave w covers rows rbase+16*(w&1), cols 64*(w>>1)..+64
// (4 col-tiles of 16). Per wave: A frags loaded once (16 VGPR), reused.
// mfma_f32_16x16x32_bf16: A lane l -> row l&15, k=(l>>4)*8+r;
// B lane l -> col l&15, k=(l>>4)*8+r; C/D lane l -> col l&15, row=(l>>4)*4+reg.
__launch_bounds__(256, 4)
__global__ void k_gemm_mfma(const u16* __restrict__ A, const u16* __restrict__ Bt,
                            u16* __restrict__ T) {
  int w = threadIdx.x >> 6;
  int l = threadIdx.x & 63;
  int rbase = blockIdx.x * 32 + 16 * (w & 1);
  int jb0   = 64 * (w >> 1);
  int row = rbase + (l & 15);
  int rr = row < NN ? row : NN - 1;
  int kg = (l >> 4) * 8;
  const short* As = reinterpret_cast<const short*>(A);
  const short* Bs = reinterpret_cast<const short*>(Bt);
  bf16x8 fa0 = *reinterpret_cast<const bf16x8*>(As + (size_t)rr * DM + 0 * 32 + kg);
  bf16x8 fa1 = *reinterpret_cast<const bf16x8*>(As + (size_t)rr * DM + 1 * 32 + kg);
  bf16x8 fa2 = *reinterpret_cast<const bf16x8*>(As + (size_t)rr * DM + 2 * 32 + kg);
  bf16x8 fa3 = *reinterpret_cast<const bf16x8*>(As + (size_t)rr * DM + 3 * 32 + kg);
#pragma unroll
  for (int ct = 0; ct < 4; ++ct) {
    int jb = jb0 + ct * 16;
    const short* bp = Bs + (size_t)(jb + (l & 15)) * DM + kg;
    bf16x8 fb0 = *reinterpret_cast<const bf16x8*>(bp + 0 * 32);
    bf16x8 fb1 = *reinterpret_cast<const bf16x8*>(bp + 1 * 32);
    bf16x8 fb2 = *reinterpret_cast<const bf16x8*>(bp + 2 * 32);
    bf16x8 fb3 = *reinterpret_cast<const bf16x8*>(bp + 3 * 32);
    f32x4 c = {0.f, 0.f, 0.f, 0.f};
    c = __builtin_amdgcn_mfma_f32_16x16x32_bf16(fa0, fb0, c, 0, 0, 0);
    c = __builtin_amdgcn_mfma_f32_16x16x32_bf16(fa1, fb1, c, 0, 0, 0);
    c = __builtin_amdgcn_mfma_f32_16x16x32_bf16(fa2, fb2, c, 0, 0, 0);
    c = __builtin_amdgcn_mfma_f32_16x16x32_bf16(fa3, fb3, c, 0, 0, 0);
    int orow = rbase + (l >> 4) * 4;
    int ocol = jb + (l & 15);
#pragma unroll
    for (int r = 0; r < 4; ++r) {
      if (orow + r < NN) T[(size_t)(orow + r) * DM + ocol] = f2bf(c[r]);
    }
  }
}

extern "C" void kernel_launch(void* const* d_in, const int* in_sizes, int n_in,
                              void* d_out, int out_size, void* d_ws, size_t ws_size,
                              hipStream_t stream) {
  const float* in_feat = (const float*)d_in[0];
  const int*   ei      = (const int*)d_in[1];
  const float* Ws      = (const float*)d_in[2];
  const float* bs      = (const float*)d_in[3];
  float* out = (float*)d_out;

  const int* src = ei;
  const int* dst = ei + NE;
  const float* W1 = Ws;
  const float* W2 = Ws + DM * DM;
  const float* W3 = Ws + 2 * DM * DM;
  const float* b1 = bs;
  const float* b2 = bs + DM;
  const float* b3 = bs + 2 * DM;

  char* w = (char*)d_ws;
  int* hcop   = (int*)w;            w += (size_t)256 * CHN * sizeof(int);  // 12.8MB
  int* co     = (int*)w;            w += NN * sizeof(int);
  int* ci     = (int*)w;            w += NN * sizeof(int);
  int* rowptr = (int*)w;            w += (NN + 1) * sizeof(int);
  int* bsum   = (int*)w;            w += NB * sizeof(int);
  int* col    = (int*)w;            w += NE * sizeof(int);
  float* onorm = (float*)w;         w += NN * sizeof(float);
  float* inorm = (float*)w;         w += NN * sizeof(float);
  float* v1    = (float*)w;         w += NN * sizeof(float);
  float* v2    = (float*)w;         w += NN * sizeof(float);
  float* W23   = (float*)w;         w += DM * DM * sizeof(float);
  u16*   W123t = (u16*)w;           w += DM * DM * sizeof(u16);   // bf16 [n][k]
  float* c1    = (float*)w;         w += DM * sizeof(float);
  float* c2    = (float*)w;         w += DM * sizeof(float);
  u16* featb  = (u16*)w;            w += (size_t)NN * DM * sizeof(u16);   // bf16 in_feat
  u16* g1b    = (u16*)w;            w += (size_t)NN * DM * sizeof(u16);   // bf16 M h
  u16* g2b    = (u16*)w;            w += (size_t)NN * DM * sizeof(u16);   // bf16 M^2 h
  u16* tb     = (u16*)w;            w += (size_t)NN * DM * sizeof(u16);   // bf16 g2 W123

  // pcur aliases hcop's src half (blocks 0..127), consumed by k_scan_part
  // before k_scan_out2 writes it. hcop's dst half stays live for k_scan_out2.
  int* pcur = hcop;
  const int* hcop_dst = hcop + (size_t)128 * CHN;

  // graph preprocessing (no global atomics anywhere)
  k_hist<<<256, 256, 0, stream>>>(src, dst, hcop);
  k_scan_part<<<NB, 256, 0, stream>>>(hcop, co, ci, bsum);
  k_scan_out2<<<NB, 256, 0, stream>>>(ci, co, bsum, rowptr, onorm, inorm, hcop_dst, pcur);
  k_fill2<<<128 + NFB, 256, 0, stream>>>(src, dst, pcur, col, in_feat, featb);

  // g1 = M h (+v1, +W23 rider); g2 = M g1 (+v2, +W123t/c1/c2 riders)
  k_gather_t<1, 1, 0><<<NGB + 64, 256, 0, stream>>>(featb, rowptr, col, onorm, inorm,
                                                    nullptr, g1b, nullptr, v1,
                                                    W2, W3, W23, nullptr,
                                                    nullptr, nullptr, nullptr,
                                                    nullptr, nullptr, nullptr,
                                                    nullptr, nullptr, nullptr, nullptr, nullptr);
  k_gather_t<2, 2, 0><<<NGB + 65, 256, 0, stream>>>(g1b, rowptr, col, onorm, inorm,
                                                    v1, g2b, nullptr, v2,
                                                    W1, W23, nullptr, W123t,
                                                    b1, W23, c1, b2, W3, c2,
                                                    nullptr, nullptr, nullptr, nullptr, nullptr);
  // t = g2 @ W123 (bf16 MFMA)
  k_gemm_mfma<<<(NN + 31) / 32, 256, 0, stream>>>(g2b, W123t, tb);
  // out = M t + v2 c1^T + v1 c2^T + 1 b3^T (fused epilogue)
  k_gather_t<0, 0, 1><<<NGB, 256, 0, stream>>>(tb, rowptr, col, onorm, inorm,
                                               nullptr, nullptr, out, nullptr,
                                               nullptr, nullptr, nullptr, nullptr,
                                               nullptr, nullptr, nullptr,
                                               nullptr, nullptr, nullptr,
                                               v1, v2, c1, c2, b3);
}

// Round 17
// 185.984 us; speedup vs baseline: 9.5246x; 1.0966x over previous
//
#include <hip/hip_runtime.h>

// GCN: 3 layers GraphConv (norm='both'), N=50000, E=800000, D=128.
// Round 17: gather loads reshaped to 16B/lane (4 edge-groups x 16 col-lanes,
// one int4 = 8 bf16 per lane; a 16-lane group reads a whole 256B row per
// instruction — the shape the f32 gather sustained 3.8TB/s with). bf16-conv
// rider moved to k_scan_part; workspace reordered for 16B alignment.
//   out = M·(M^2 h · W123) + v2 c1^T + v1 c2^T + 1 b3^T,  v1=M·1, v2=M·v1.

#define NN 50000
#define NE 800000
#define DM 128
#define NB 196     // ceil(NN/256) scan blocks
#define NGB 12500  // gather blocks (NN*64/256)
#define CHN 12500  // nodes per histogram chunk (50KB LDS)
#define NCOP 32    // edge-slice copies per (array, chunk)
#define NFB 782    // bf16-conversion rider blocks

typedef unsigned short u16;
typedef __attribute__((ext_vector_type(8))) short bf16x8;
typedef __attribute__((ext_vector_type(4))) float f32x4;

__device__ __forceinline__ float bf2f(u16 u) {
  return __uint_as_float((unsigned)u << 16);
}
__device__ __forceinline__ u16 f2bf(float f) {
  unsigned x = __float_as_uint(f);
  return (u16)((x + 0x7fffu + ((x >> 16) & 1u)) >> 16);  // RNE, finite inputs
}
__device__ __forceinline__ float bflo(int u) { return __int_as_float(u << 16); }
__device__ __forceinline__ float bfhi(int u) { return __int_as_float(u & 0xffff0000); }

// grid 256: b = arr*128 + chunk*32 + copy. LDS histogram of its node chunk
// over its edge slice; non-atomic flush to hcop[b*CHN ..].
__global__ void k_hist(const int* __restrict__ src, const int* __restrict__ dst,
                       int* __restrict__ hcop) {
  __shared__ int h[CHN];
  int b = blockIdx.x;
  int arr   = b >> 7;
  int chunk = (b >> 5) & 3;
  int copy  = b & 31;
  const int* idx = arr ? dst : src;
  int lo = chunk * CHN;
  for (int i = threadIdx.x; i < CHN; i += 256) h[i] = 0;
  __syncthreads();
  const int4* e4 = reinterpret_cast<const int4*>(idx) + copy * (NE / 4 / NCOP);
  for (int i = threadIdx.x; i < NE / 4 / NCOP; i += 256) {
    int4 v = e4[i];
    unsigned a;
    a = (unsigned)(v.x - lo); if (a < (unsigned)CHN) atomicAdd(&h[a], 1);
    a = (unsigned)(v.y - lo); if (a < (unsigned)CHN) atomicAdd(&h[a], 1);
    a = (unsigned)(v.z - lo); if (a < (unsigned)CHN) atomicAdd(&h[a], 1);
    a = (unsigned)(v.w - lo); if (a < (unsigned)CHN) atomicAdd(&h[a], 1);
  }
  __syncthreads();
  int* o = hcop + (size_t)b * CHN;
  for (int i = threadIdx.x; i < CHN; i += 256) o[i] = h[i];
}

// ---- scan stage 1 (+bf16 conversion rider on blocks >= NB) ----
__global__ void k_scan_part(const int* __restrict__ hcop, int* __restrict__ co,
                            int* __restrict__ ci, int* __restrict__ bsum,
                            const float* __restrict__ feat, u16* __restrict__ featb) {
  __shared__ int s[256];
  int b = blockIdx.x;
  if (b >= NB) {
    size_t base = ((size_t)(b - NB) * 256 + threadIdx.x) * 8;
    const size_t stride = (size_t)NFB * 256 * 8;
#pragma unroll
    for (int it = 0; it < 4; ++it, base += stride) {
      if (base < (size_t)NN * DM) {
        float4 f0 = *reinterpret_cast<const float4*>(feat + base);
        float4 f1 = *reinterpret_cast<const float4*>(feat + base + 4);
        ushort4 u0 = make_ushort4(f2bf(f0.x), f2bf(f0.y), f2bf(f0.z), f2bf(f0.w));
        ushort4 u1 = make_ushort4(f2bf(f1.x), f2bf(f1.y), f2bf(f1.z), f2bf(f1.w));
        *reinterpret_cast<ushort4*>(featb + base) = u0;
        *reinterpret_cast<ushort4*>(featb + base + 4) = u1;
      }
    }
    return;
  }
  int i = b * 256 + threadIdx.x;
  int sco = 0, sci = 0;
  if (i < NN) {
    int ch = i / CHN;
    int loc = i - ch * CHN;
    const int* pco = hcop + (size_t)(ch * 32) * CHN + loc;
    const int* pci = hcop + (size_t)(128 + ch * 32) * CHN + loc;
#pragma unroll
    for (int p = 0; p < NCOP; ++p) {
      sco += pco[(size_t)p * CHN];
      sci += pci[(size_t)p * CHN];
    }
    co[i] = sco;
    ci[i] = sci;
  }
  s[threadIdx.x] = sci;
  __syncthreads();
  for (int off = 128; off > 0; off >>= 1) {
    if (threadIdx.x < off) s[threadIdx.x] += s[threadIdx.x + off];
    __syncthreads();
  }
  if (threadIdx.x == 0) bsum[b] = s[0];
}

// ---- merged: scan bsum in-block, per-node scan -> rowptr/norms, pcur fill ----
__global__ void k_scan_out2(const int* __restrict__ ci, const int* __restrict__ co,
                            const int* __restrict__ bsum, int* __restrict__ rowptr,
                            float* __restrict__ onorm, float* __restrict__ inorm,
                            const int* __restrict__ hcop_dst, int* __restrict__ pcur) {
  __shared__ int s[256];
  int t = threadIdx.x;
  int bv = (t < NB) ? bsum[t] : 0;
  s[t] = bv;
  __syncthreads();
  for (int off = 1; off < 256; off <<= 1) {
    int u = (t >= off) ? s[t - off] : 0;
    __syncthreads();
    s[t] += u;
    __syncthreads();
  }
  int boff_blk = s[blockIdx.x] - bsum[blockIdx.x];
  __syncthreads();

  int i = blockIdx.x * 256 + t;
  int v = (i < NN) ? ci[i] : 0;
  s[t] = v;
  __syncthreads();
  for (int off = 1; off < 256; off <<= 1) {
    int u = (t >= off) ? s[t - off] : 0;
    __syncthreads();
    s[t] += u;
    __syncthreads();
  }
  if (i < NN) {
    int ex = boff_blk + s[t] - v;
    rowptr[i] = ex;
    onorm[i] = rsqrtf(fmaxf((float)co[i], 1.0f));
    inorm[i] = rsqrtf(fmaxf((float)v, 1.0f));
    int ch = i / CHN;
    int loc = i - ch * CHN;
    const int* hb = hcop_dst + (size_t)(ch * 32) * CHN + loc;
    int* pb = pcur + (size_t)(ch * 32) * CHN + loc;
    int run = ex;
#pragma unroll
    for (int p = 0; p < NCOP; ++p) {
      pb[(size_t)p * CHN] = run;
      run += hb[(size_t)p * CHN];
    }
  }
  if (blockIdx.x == 0 && t == 0) rowptr[NN] = NE;
}

// (chunk,slice) CSR fill via LDS cursors, no global atomics.
__global__ void k_fill2(const int* __restrict__ src, const int* __restrict__ dst,
                        const int* __restrict__ pcur, int* __restrict__ col) {
  __shared__ int cur[CHN];
  int b = blockIdx.x;
  int copy  = b & 31;
  int lo = (b >> 5) * CHN;
  const int* pc = pcur + (size_t)b * CHN;
  for (int i = threadIdx.x; i < CHN; i += 256) cur[i] = pc[i];
  __syncthreads();
  const int4* s4 = reinterpret_cast<const int4*>(src) + copy * (NE / 4 / NCOP);
  const int4* d4 = reinterpret_cast<const int4*>(dst) + copy * (NE / 4 / NCOP);
  for (int i = threadIdx.x; i < NE / 4 / NCOP; i += 256) {
    int4 s = s4[i];
    int4 d = d4[i];
    unsigned a;
    int p;
    a = (unsigned)(d.x - lo); if (a < (unsigned)CHN) { p = atomicAdd(&cur[a], 1); col[p] = s.x; }
    a = (unsigned)(d.y - lo); if (a < (unsigned)CHN) { p = atomicAdd(&cur[a], 1); col[p] = s.y; }
    a = (unsigned)(d.z - lo); if (a < (unsigned)CHN) { p = atomicAdd(&cur[a], 1); col[p] = s.z; }
    a = (unsigned)(d.w - lo); if (a < (unsigned)CHN) { p = atomicAdd(&cur[a], 1); col[p] = s.w; }
  }
}

#define ACC8(uu, nn)                     \
  aa.x += (nn) * bflo((uu).x); ab.x += (nn) * bfhi((uu).x); \
  aa.y += (nn) * bflo((uu).y); ab.y += (nn) * bfhi((uu).y); \
  aa.z += (nn) * bflo((uu).z); ab.z += (nn) * bfhi((uu).z); \
  aa.w += (nn) * bflo((uu).w); ab.w += (nn) * bfhi((uu).w);

// ---- feature gather: Y = M X with bf16 X, 16B/lane loads.
// Wave = 4 edge-groups x 16 col-lanes; lane loads int4 (8 bf16) of one row.
// Unroll 2 per group (8 rows in flight/wave, one instr per row per group).
// VMODE 0: none. 1: vout = M·1. 2: vout = M·vin.
// EXTRA==1: riders compute mCf = mA@mB (f32). EXTRA==2: mCt = bf16-T(mA@mB),
// +1 block for vc1/vc2. OUTMODE 0: bf16 aggb. 1: f32 outf + fused rank-1.
template <int VMODE, int EXTRA, int OUTMODE>
__global__ void k_gather_t(const u16* __restrict__ h, const int* __restrict__ rowptr,
                           const int* __restrict__ col, const float* __restrict__ onorm,
                           const float* __restrict__ inorm, const float* __restrict__ vin,
                           u16* __restrict__ aggb, float* __restrict__ outf,
                           float* __restrict__ vout,
                           const float* __restrict__ mA, const float* __restrict__ mB,
                           float* __restrict__ mCf, u16* __restrict__ mCt,
                           const float* __restrict__ vb1, const float* __restrict__ vB1,
                           float* __restrict__ vc1,
                           const float* __restrict__ vb2, const float* __restrict__ vB2,
                           float* __restrict__ vc2,
                           const float* __restrict__ pv1, const float* __restrict__ pv2,
                           const float* __restrict__ pc1, const float* __restrict__ pc2,
                           const float* __restrict__ pb3) {
  if (EXTRA) {
    int eb = (int)blockIdx.x - NGB;
    if (eb >= 0) {
      if (eb < 64) {            // mA @ mB, rows 2eb, 2eb+1
        int i0 = eb * 2 + (threadIdx.x >> 7);
        int j = threadIdx.x & 127;
        float acc = 0.f;
        for (int k = 0; k < DM; ++k) acc += mA[i0 * DM + k] * mB[k * DM + j];
        if (EXTRA == 1) mCf[i0 * DM + j] = acc;
        else            mCt[j * DM + i0] = f2bf(acc);  // bf16, transposed [n][k]
      } else if (EXTRA == 2) {
        int t = threadIdx.x;
        if (t < DM) {
          float acc = 0.f;
          for (int k = 0; k < DM; ++k) acc += vb1[k] * vB1[k * DM + t];
          vc1[t] = acc;
        } else {
          int j = t - DM;
          float acc = 0.f;
          for (int k = 0; k < DM; ++k) acc += vb2[k] * vB2[k * DM + j];
          vc2[j] = acc;
        }
      }
      return;
    }
  }
  int tid = blockIdx.x * blockDim.x + threadIdx.x;
  int n = tid >> 6;
  if (n >= NN) return;
  int g   = (threadIdx.x >> 4) & 3;   // edge group within wave
  int l16 = threadIdx.x & 15;         // 16B column slot (8 bf16)
  int beg = rowptr[n], end = rowptr[n + 1];
  const int4* h16 = reinterpret_cast<const int4*>(h);  // row = 16 int4
  float4 aa = make_float4(0.f, 0.f, 0.f, 0.f);  // even cols
  float4 ab = make_float4(0.f, 0.f, 0.f, 0.f);  // odd cols
  float av = 0.f;
  int e = beg + g;
  for (; e + 4 < end; e += 8) {
    int s0 = col[e], s1 = col[e + 4];
    float n0 = onorm[s0], n1 = onorm[s1];
    int4 u0 = h16[(size_t)s0 * 16 + l16];
    int4 u1 = h16[(size_t)s1 * 16 + l16];
    if (VMODE == 1) av += n0 + n1;
    if (VMODE == 2) av += n0 * vin[s0] + n1 * vin[s1];
    ACC8(u0, n0)
    ACC8(u1, n1)
  }
  for (; e < end; e += 4) {
    int s0 = col[e];
    float n0 = onorm[s0];
    int4 u0 = h16[(size_t)s0 * 16 + l16];
    if (VMODE == 1) av += n0;
    if (VMODE == 2) av += n0 * vin[s0];
    ACC8(u0, n0)
  }
  // reduce across the 4 edge-groups
  aa.x += __shfl_xor(aa.x, 16); aa.y += __shfl_xor(aa.y, 16);
  aa.z += __shfl_xor(aa.z, 16); aa.w += __shfl_xor(aa.w, 16);
  ab.x += __shfl_xor(ab.x, 16); ab.y += __shfl_xor(ab.y, 16);
  ab.z += __shfl_xor(ab.z, 16); ab.w += __shfl_xor(ab.w, 16);
  aa.x += __shfl_xor(aa.x, 32); aa.y += __shfl_xor(aa.y, 32);
  aa.z += __shfl_xor(aa.z, 32); aa.w += __shfl_xor(aa.w, 32);
  ab.x += __shfl_xor(ab.x, 32); ab.y += __shfl_xor(ab.y, 32);
  ab.z += __shfl_xor(ab.z, 32); ab.w += __shfl_xor(ab.w, 32);
  if (VMODE) { av += __shfl_xor(av, 16); av += __shfl_xor(av, 32); }
  if (g == 0) {
    float sc = inorm[n];
    aa.x *= sc; aa.y *= sc; aa.z *= sc; aa.w *= sc;
    ab.x *= sc; ab.y *= sc; ab.z *= sc; ab.w *= sc;
    if (OUTMODE == 0) {
      int4 o;
      o.x = ((int)f2bf(ab.x) << 16) | f2bf(aa.x);
      o.y = ((int)f2bf(ab.y) << 16) | f2bf(aa.y);
      o.z = ((int)f2bf(ab.z) << 16) | f2bf(aa.z);
      o.w = ((int)f2bf(ab.w) << 16) | f2bf(aa.w);
      reinterpret_cast<int4*>(aggb)[(size_t)n * 16 + l16] = o;
    } else {
      int jc = l16 * 8;
      float4 e1a = *reinterpret_cast<const float4*>(pc1 + jc);
      float4 e1b = *reinterpret_cast<const float4*>(pc1 + jc + 4);
      float4 e2a = *reinterpret_cast<const float4*>(pc2 + jc);
      float4 e2b = *reinterpret_cast<const float4*>(pc2 + jc + 4);
      float4 e3a = *reinterpret_cast<const float4*>(pb3 + jc);
      float4 e3b = *reinterpret_cast<const float4*>(pb3 + jc + 4);
      float q1 = pv1[n], q2 = pv2[n];
      float4 o0, o1;
      o0.x = aa.x + q2 * e1a.x + q1 * e2a.x + e3a.x;
      o0.y = ab.x + q2 * e1a.y + q1 * e2a.y + e3a.y;
      o0.z = aa.y + q2 * e1a.z + q1 * e2a.z + e3a.z;
      o0.w = ab.y + q2 * e1a.w + q1 * e2a.w + e3a.w;
      o1.x = aa.z + q2 * e1b.x + q1 * e2b.x + e3b.x;
      o1.y = ab.z + q2 * e1b.y + q1 * e2b.y + e3b.y;
      o1.z = aa.w + q2 * e1b.z + q1 * e2b.z + e3b.z;
      o1.w = ab.w + q2 * e1b.w + q1 * e2b.w + e3b.w;
      *reinterpret_cast<float4*>(outf + (size_t)n * DM + jc) = o0;
      *reinterpret_cast<float4*>(outf + (size_t)n * DM + jc + 4) = o1;
    }
    if (VMODE && l16 == 0) vout[n] = av * sc;
  }
}

// ---- MFMA GEMM: T[50000x128] = A @ W123, bf16 in/out (Bt = W123^T bf16).
__launch_bounds__(256, 4)
__global__ void k_gemm_mfma(const u16* __restrict__ A, const u16* __restrict__ Bt,
                            u16* __restrict__ T) {
  int w = threadIdx.x >> 6;
  int l = threadIdx.x & 63;
  int rbase = blockIdx.x * 32 + 16 * (w & 1);
  int jb0   = 64 * (w >> 1);
  int row = rbase + (l & 15);
  int rr = row < NN ? row : NN - 1;
  int kg = (l >> 4) * 8;
  const short* As = reinterpret_cast<const short*>(A);
  const short* Bs = reinterpret_cast<const short*>(Bt);
  bf16x8 fa0 = *reinterpret_cast<const bf16x8*>(As + (size_t)rr * DM + 0 * 32 + kg);
  bf16x8 fa1 = *reinterpret_cast<const bf16x8*>(As + (size_t)rr * DM + 1 * 32 + kg);
  bf16x8 fa2 = *reinterpret_cast<const bf16x8*>(As + (size_t)rr * DM + 2 * 32 + kg);
  bf16x8 fa3 = *reinterpret_cast<const bf16x8*>(As + (size_t)rr * DM + 3 * 32 + kg);
#pragma unroll
  for (int ct = 0; ct < 4; ++ct) {
    int jb = jb0 + ct * 16;
    const short* bp = Bs + (size_t)(jb + (l & 15)) * DM + kg;
    bf16x8 fb0 = *reinterpret_cast<const bf16x8*>(bp + 0 * 32);
    bf16x8 fb1 = *reinterpret_cast<const bf16x8*>(bp + 1 * 32);
    bf16x8 fb2 = *reinterpret_cast<const bf16x8*>(bp + 2 * 32);
    bf16x8 fb3 = *reinterpret_cast<const bf16x8*>(bp + 3 * 32);
    f32x4 c = {0.f, 0.f, 0.f, 0.f};
    c = __builtin_amdgcn_mfma_f32_16x16x32_bf16(fa0, fb0, c, 0, 0, 0);
    c = __builtin_amdgcn_mfma_f32_16x16x32_bf16(fa1, fb1, c, 0, 0, 0);
    c = __builtin_amdgcn_mfma_f32_16x16x32_bf16(fa2, fb2, c, 0, 0, 0);
    c = __builtin_amdgcn_mfma_f32_16x16x32_bf16(fa3, fb3, c, 0, 0, 0);
    int orow = rbase + (l >> 4) * 4;
    int ocol = jb + (l & 15);
#pragma unroll
    for (int r = 0; r < 4; ++r) {
      if (orow + r < NN) T[(size_t)(orow + r) * DM + ocol] = f2bf(c[r]);
    }
  }
}

extern "C" void kernel_launch(void* const* d_in, const int* in_sizes, int n_in,
                              void* d_out, int out_size, void* d_ws, size_t ws_size,
                              hipStream_t stream) {
  const float* in_feat = (const float*)d_in[0];
  const int*   ei      = (const int*)d_in[1];
  const float* Ws      = (const float*)d_in[2];
  const float* bs      = (const float*)d_in[3];
  float* out = (float*)d_out;

  const int* src = ei;
  const int* dst = ei + NE;
  const float* W1 = Ws;
  const float* W2 = Ws + DM * DM;
  const float* W3 = Ws + 2 * DM * DM;
  const float* b1 = bs;
  const float* b2 = bs + DM;
  const float* b3 = bs + 2 * DM;

  // 16B-aligned-first workspace layout (bf16 matrices accessed as int4)
  char* w = (char*)d_ws;
  int* hcop   = (int*)w;            w += (size_t)256 * CHN * sizeof(int);   // 12.8MB
  u16* featb  = (u16*)w;            w += (size_t)NN * DM * sizeof(u16);     // bf16 in_feat
  u16* g1b    = (u16*)w;            w += (size_t)NN * DM * sizeof(u16);     // bf16 M h
  u16* g2b    = (u16*)w;            w += (size_t)NN * DM * sizeof(u16);     // bf16 M^2 h
  u16* tb     = (u16*)w;            w += (size_t)NN * DM * sizeof(u16);     // bf16 g2 W123
  u16* W123t  = (u16*)w;            w += DM * DM * sizeof(u16);             // bf16 [n][k]
  float* W23  = (float*)w;          w += DM * DM * sizeof(float);
  int* co     = (int*)w;            w += NN * sizeof(int);
  int* ci     = (int*)w;            w += NN * sizeof(int);
  int* rowptr = (int*)w;            w += (NN + 1) * sizeof(int);
  int* bsum   = (int*)w;            w += NB * sizeof(int);
  int* col    = (int*)w;            w += NE * sizeof(int);
  float* onorm = (float*)w;         w += NN * sizeof(float);
  float* inorm = (float*)w;         w += NN * sizeof(float);
  float* v1    = (float*)w;         w += NN * sizeof(float);
  float* v2    = (float*)w;         w += NN * sizeof(float);
  float* c1    = (float*)w;         w += DM * sizeof(float);
  float* c2    = (float*)w;         w += DM * sizeof(float);

  int* pcur = hcop;                                // aliases consumed src half
  const int* hcop_dst = hcop + (size_t)128 * CHN;

  // graph preprocessing (no global atomics anywhere)
  k_hist<<<256, 256, 0, stream>>>(src, dst, hcop);
  k_scan_part<<<NB + NFB, 256, 0, stream>>>(hcop, co, ci, bsum, in_feat, featb);
  k_scan_out2<<<NB, 256, 0, stream>>>(ci, co, bsum, rowptr, onorm, inorm, hcop_dst, pcur);
  k_fill2<<<128, 256, 0, stream>>>(src, dst, pcur, col);

  // g1 = M h (+v1, +W23 rider); g2 = M g1 (+v2, +W123t/c1/c2 riders)
  k_gather_t<1, 1, 0><<<NGB + 64, 256, 0, stream>>>(featb, rowptr, col, onorm, inorm,
                                                    nullptr, g1b, nullptr, v1,
                                                    W2, W3, W23, nullptr,
                                                    nullptr, nullptr, nullptr,
                                                    nullptr, nullptr, nullptr,
                                                    nullptr, nullptr, nullptr, nullptr, nullptr);
  k_gather_t<2, 2, 0><<<NGB + 65, 256, 0, stream>>>(g1b, rowptr, col, onorm, inorm,
                                                    v1, g2b, nullptr, v2,
                                                    W1, W23, nullptr, W123t,
                                                    b1, W23, c1, b2, W3, c2,
                                                    nullptr, nullptr, nullptr, nullptr, nullptr);
  // t = g2 @ W123 (bf16 MFMA)
  k_gemm_mfma<<<(NN + 31) / 32, 256, 0, stream>>>(g2b, W123t, tb);
  // out = M t + rank-1 terms (fused epilogue)
  k_gather_t<0, 0, 1><<<NGB, 256, 0, stream>>>(tb, rowptr, col, onorm, inorm,
                                               nullptr, nullptr, out, nullptr,
                                               nullptr, nullptr, nullptr, nullptr,
                                               nullptr, nullptr, nullptr,
                                               nullptr, nullptr, nullptr,
                                               v1, v2, c1, c2, b3);
}